// Round 1
// baseline (4509.292 us; speedup 1.0000x reference)
//
#include <hip/hip_runtime.h>
#include <math.h>

#define NC 8
#define NDIM 32
#define LDSD 33            // padded LDS row stride: conflict-free rows AND cols
#define MAT (NDIM * LDSD)  // 1056 floats per LDS matrix
#define EV_EPS 1e-10f
#define BMAX 2048

// ---------- round-robin tournament pairing: 16 disjoint pairs x 31 rounds ----------
__device__ inline void rr_pair(int r, int k, int& p, int& q) {
    int a, b;
    if (k == 0) { a = 31; b = r; }
    else { a = (r + k) % 31; b = (r - k + 62) % 31; }
    p = a < b ? a : b;
    q = a < b ? b : a;
}

// ---------- 32x32 LDS helpers (64-thread wave) ----------
__device__ inline void g2l(const float* g, float* l, int tid) {
    for (int it = 0; it < 16; ++it) {
        int idx = tid + (it << 6);
        l[(idx >> 5) * LDSD + (idx & 31)] = g[idx];
    }
}
__device__ inline void l2g(const float* l, float* g, int tid) {
    for (int it = 0; it < 16; ++it) {
        int idx = tid + (it << 6);
        g[idx] = l[(idx >> 5) * LDSD + (idx & 31)];
    }
}
__device__ inline void mm_nn(const float* A, const float* B, float* C, int tid) {
    for (int it = 0; it < 16; ++it) {
        int idx = tid + (it << 6);
        int i = idx >> 5, j = idx & 31;
        float acc = 0.f;
#pragma unroll
        for (int k = 0; k < 32; ++k) acc += A[i * LDSD + k] * B[k * LDSD + j];
        C[i * LDSD + j] = acc;
    }
}
__device__ inline void mm_nt(const float* A, const float* B, float* C, int tid) { // C = A * B^T
    for (int it = 0; it < 16; ++it) {
        int idx = tid + (it << 6);
        int i = idx >> 5, j = idx & 31;
        float acc = 0.f;
#pragma unroll
        for (int k = 0; k < 32; ++k) acc += A[i * LDSD + k] * B[j * LDSD + k];
        C[i * LDSD + j] = acc;
    }
}
__device__ inline void mm_tn(const float* A, const float* B, float* C, int tid) { // C = A^T * B
    for (int it = 0; it < 16; ++it) {
        int idx = tid + (it << 6);
        int i = idx >> 5, j = idx & 31;
        float acc = 0.f;
#pragma unroll
        for (int k = 0; k < 32; ++k) acc += A[k * LDSD + i] * B[k * LDSD + j];
        C[i * LDSD + j] = acc;
    }
}

// ---------- parallel Jacobi eigensolver, 32x32 symmetric, one wave ----------
template <bool WANT_V>
__device__ void jacobi32(float* A, float* V, float* csn, int tid, int max_sweeps) {
    if (WANT_V) {
        for (int it = 0; it < 16; ++it) {
            int idx = tid + (it << 6);
            int i = idx >> 5, j = idx & 31;
            V[i * LDSD + j] = (i == j) ? 1.f : 0.f;
        }
    }
    __syncthreads();
    float loc = 0.f;
    for (int it = 0; it < 16; ++it) {
        int idx = tid + (it << 6);
        float v = A[(idx >> 5) * LDSD + (idx & 31)];
        loc += v * v;
    }
#pragma unroll
    for (int off = 32; off > 0; off >>= 1) loc += __shfl_down(loc, off);
    float fro2 = __shfl(loc, 0);
    float tol2 = fro2 * 1e-12f + 1e-30f;

    for (int sweep = 0; sweep < max_sweeps; ++sweep) {
        for (int r = 0; r < 31; ++r) {
            if (tid < 16) {
                int p, q; rr_pair(r, tid, p, q);
                float apq = A[p * LDSD + q];
                float c = 1.f, s = 0.f;
                if (fabsf(apq) > 1e-36f) {
                    float app = A[p * LDSD + p], aqq = A[q * LDSD + q];
                    float tau = (aqq - app) / (2.f * apq);
                    float t = (tau >= 0.f ? 1.f : -1.f) / (fabsf(tau) + sqrtf(1.f + tau * tau));
                    c = 1.f / sqrtf(1.f + t * t);
                    s = t * c;
                }
                csn[tid] = c; csn[16 + tid] = s;
            }
            __syncthreads();
            // row rotations (disjoint row pairs)
            for (int it = 0; it < 8; ++it) {
                int item = tid + (it << 6);
                int k = item >> 5, j = item & 31;
                int p, q; rr_pair(r, k, p, q);
                float c = csn[k], s = csn[16 + k];
                float ap = A[p * LDSD + j], aq = A[q * LDSD + j];
                A[p * LDSD + j] = c * ap - s * aq;
                A[q * LDSD + j] = s * ap + c * aq;
            }
            __syncthreads();
            // column rotations (disjoint column pairs) + eigenvector accumulation
            for (int it = 0; it < 8; ++it) {
                int item = tid + (it << 6);
                int k = item >> 5, i = item & 31;
                int p, q; rr_pair(r, k, p, q);
                float c = csn[k], s = csn[16 + k];
                float ap = A[i * LDSD + p], aq = A[i * LDSD + q];
                A[i * LDSD + p] = c * ap - s * aq;
                A[i * LDSD + q] = s * ap + c * aq;
                if (WANT_V) {
                    float vp = V[i * LDSD + p], vq = V[i * LDSD + q];
                    V[i * LDSD + p] = c * vp - s * vq;
                    V[i * LDSD + q] = s * vp + c * vq;
                }
            }
            __syncthreads();
        }
        float l2 = 0.f;
        for (int it = 0; it < 16; ++it) {
            int idx = tid + (it << 6);
            int i = idx >> 5, j = idx & 31;
            if (i != j) { float v = A[i * LDSD + j]; l2 += v * v; }
        }
#pragma unroll
        for (int off = 32; off > 0; off >>= 1) l2 += __shfl_down(l2, off);
        l2 = __shfl(l2, 0);
        if (l2 <= tol2) break;
    }
    __syncthreads();
}

// ---------- kernels ----------
__global__ void k_count(const int* labels, int B, int* counts) {
    int tid = threadIdx.x;
    if (tid < NC) {
        int cnt = 0;
        for (int b = 0; b < B; ++b) cnt += (labels[b] == tid);
        counts[tid] = cnt;
    }
}

__global__ void k_bary0(const float* X, const int* labels, const int* counts, int B, float* bary0) {
    __shared__ int lab[BMAX];
    int c = blockIdx.x, tid = threadIdx.x;
    for (int b = tid; b < B; b += 256) lab[b] = labels[b];
    __syncthreads();
    float acc[4] = {0.f, 0.f, 0.f, 0.f};
    for (int b = 0; b < B; ++b) {
        if (lab[b] == c) {
#pragma unroll
            for (int e = 0; e < 4; ++e) acc[e] += X[b * 1024 + tid + 256 * e];
        }
    }
    float inv = 1.f / (float)counts[c];
#pragma unroll
    for (int e = 0; e < 4; ++e) bary0[c * 1024 + tid + 256 * e] = acc[e] * inv;
}

__global__ void k_eig_bary0(const float* bary0, float* sqrtm, float* invsqrtm) {
    __shared__ float A[MAT], V[MAT], T1[MAT], T2[MAT], csn[32];
    int c = blockIdx.x, tid = threadIdx.x;
    g2l(bary0 + c * 1024, A, tid);
    __syncthreads();
    jacobi32<true>(A, V, csn, tid, 10);
    for (int it = 0; it < 16; ++it) {
        int idx = tid + (it << 6);
        int i = idx >> 5, j = idx & 31;
        T1[i * LDSD + j] = V[i * LDSD + j] * sqrtf(fmaxf(A[j * LDSD + j], 0.f));
    }
    __syncthreads();
    mm_nt(T1, V, T2, tid);
    __syncthreads();
    l2g(T2, sqrtm + c * 1024, tid);
    for (int it = 0; it < 16; ++it) {
        int idx = tid + (it << 6);
        int i = idx >> 5, j = idx & 31;
        T1[i * LDSD + j] = V[i * LDSD + j] / sqrtf(fmaxf(A[j * LDSD + j], 1e-30f));
    }
    __syncthreads();
    mm_nt(T1, V, T2, tid);
    __syncthreads();
    l2g(T2, invsqrtm + c * 1024, tid);
}

__global__ void k_tangent(const float* X, const int* labels, const float* sqrtm,
                          const float* invsqrtm, float* Tbuf) {
    __shared__ float A[MAT], V[MAT], T1[MAT], S1[MAT], X1[MAT], csn[32];
    int b = blockIdx.x, tid = threadIdx.x;
    int lb = labels[b];
    g2l(X + b * 1024, X1, tid);
    g2l(invsqrtm + lb * 1024, S1, tid);
    __syncthreads();
    mm_nn(S1, X1, T1, tid); __syncthreads();
    mm_nn(T1, S1, A, tid);  __syncthreads();
    jacobi32<true>(A, V, csn, tid, 10);
    for (int it = 0; it < 16; ++it) {
        int idx = tid + (it << 6);
        int i = idx >> 5, j = idx & 31;
        T1[i * LDSD + j] = V[i * LDSD + j] * logf(fmaxf(A[j * LDSD + j], EV_EPS));
    }
    __syncthreads();
    mm_nt(T1, V, X1, tid);            // X1 = logM
    g2l(sqrtm + lb * 1024, S1, tid);  // overwrite invsqrtm with sqrtm
    __syncthreads();
    mm_nn(S1, X1, T1, tid); __syncthreads();
    for (int it = 0; it < 16; ++it) {  // T = T1 * S1 -> global
        int idx = tid + (it << 6);
        int i = idx >> 5, j = idx & 31;
        float acc = 0.f;
#pragma unroll
        for (int k = 0; k < 32; ++k) acc += T1[i * LDSD + k] * S1[k * LDSD + j];
        Tbuf[b * 1024 + idx] = acc;
    }
}

__global__ void k_meanT(const float* Tbuf, const int* labels, const int* counts, int B, float* meanT) {
    __shared__ int lab[BMAX];
    int c = blockIdx.x, tid = threadIdx.x;
    for (int b = tid; b < B; b += 256) lab[b] = labels[b];
    __syncthreads();
    float acc[4] = {0.f, 0.f, 0.f, 0.f};
    for (int b = 0; b < B; ++b) {
        if (lab[b] == c) {
#pragma unroll
            for (int e = 0; e < 4; ++e) acc[e] += Tbuf[b * 1024 + tid + 256 * e];
        }
    }
    float inv = 1.f / (float)counts[c];
#pragma unroll
    for (int e = 0; e < 4; ++e) meanT[c * 1024 + tid + 256 * e] = acc[e] * inv;
}

__global__ void k_update(const float* meanT, const float* sqrtm, const float* invsqrtm,
                         const float* bary0, float* bary) {
    __shared__ float A[MAT], V[MAT], T1[MAT], S1[MAT], X1[MAT], csn[32];
    int c = blockIdx.x, tid = threadIdx.x;
    g2l(meanT + c * 1024, X1, tid);
    g2l(invsqrtm + c * 1024, S1, tid);
    __syncthreads();
    mm_nn(S1, X1, T1, tid); __syncthreads();
    mm_nn(T1, S1, A, tid);  __syncthreads();
    jacobi32<true>(A, V, csn, tid, 10);
    for (int it = 0; it < 16; ++it) {
        int idx = tid + (it << 6);
        int i = idx >> 5, j = idx & 31;
        // faithful quirk: clamp eigenvalues to >= 1e-10 BEFORE exp
        T1[i * LDSD + j] = V[i * LDSD + j] * expf(fmaxf(A[j * LDSD + j], EV_EPS));
    }
    __syncthreads();
    mm_nt(T1, V, X1, tid);           // X1 = expN
    g2l(sqrtm + c * 1024, S1, tid);
    __syncthreads();
    mm_nn(S1, X1, T1, tid); __syncthreads();
    mm_nn(T1, S1, V, tid);  __syncthreads();  // V = new barycenter
    float loc = 0.f;
    for (int it = 0; it < 16; ++it) {
        int idx = tid + (it << 6);
        int i = idx >> 5, j = idx & 31;
        float d = V[i * LDSD + j] - bary0[c * 1024 + idx];
        loc += d * d;
    }
#pragma unroll
    for (int off = 32; off > 0; off >>= 1) loc += __shfl_down(loc, off);
    float err2 = __shfl(loc, 0);
    bool keep0 = (err2 < 1e-8f);  // CONV_TOL^2
    for (int it = 0; it < 16; ++it) {
        int idx = tid + (it << 6);
        int i = idx >> 5, j = idx & 31;
        bary[c * 1024 + idx] = keep0 ? bary0[c * 1024 + idx] : V[i * LDSD + j];
    }
}

__global__ void k_cholinv(const float* X, float* Wbuf) {
    __shared__ float A[MAT], W[MAT];
    int b = blockIdx.x, tid = threadIdx.x;
    g2l(X + b * 1024, A, tid);
    __syncthreads();
    if (tid < 32) A[tid * LDSD + tid] += 1e-3f;  // CHOL_EPS
    __syncthreads();
    // right-looking Cholesky (lower triangle)
    for (int k = 0; k < 32; ++k) {
        if (tid == 0) A[k * LDSD + k] = sqrtf(A[k * LDSD + k]);
        __syncthreads();
        float invd = 1.f / A[k * LDSD + k];
        if (tid > k && tid < 32) A[tid * LDSD + k] *= invd;
        __syncthreads();
        for (int it = 0; it < 16; ++it) {
            int idx = tid + (it << 6);
            int i = idx >> 5, j = idx & 31;
            if (i > k && j > k && j <= i) A[i * LDSD + j] -= A[i * LDSD + k] * A[j * LDSD + k];
        }
        __syncthreads();
    }
    // W = L^{-1}: thread j forward-substitutes column j
    if (tid < 32) {
        int j = tid;
        W[j * LDSD + j] = 1.f / A[j * LDSD + j];
        for (int i = j + 1; i < 32; ++i) {
            float acc = 0.f;
            for (int k2 = j; k2 < i; ++k2) acc += A[i * LDSD + k2] * W[k2 * LDSD + j];
            W[i * LDSD + j] = -acc / A[i * LDSD + i];
        }
        for (int i = 0; i < j; ++i) W[i * LDSD + j] = 0.f;  // zero upper
    }
    __syncthreads();
    l2g(W, Wbuf + b * 1024, tid);
}

__global__ void k_pairdist(const float* Wbuf, const float* bary, float* D) {
    __shared__ float Wl[MAT], Bc[MAT], T1[MAT], A[MAT], csn[32];
    int b = blockIdx.x >> 3, c = blockIdx.x & 7, tid = threadIdx.x;
    g2l(Wbuf + b * 1024, Wl, tid);
    g2l(bary + c * 1024, Bc, tid);
    __syncthreads();
    // faithful quirk: M = L^{-T} bary L^{-T}; with A_mat = W^T (W = L^{-1}):
    // T1[q][s] = sum_r Bc[q][r] * W[s][r];  M[p][s] = sum_q W[q][p] * T1[q][s]
    mm_nt(Bc, Wl, T1, tid); __syncthreads();
    mm_tn(Wl, T1, A, tid);  __syncthreads();
    // eigvalsh(UPLO='L'): mirror lower triangle into upper
    for (int it = 0; it < 16; ++it) {
        int idx = tid + (it << 6);
        int i = idx >> 5, j = idx & 31;
        if (i < j) A[i * LDSD + j] = A[j * LDSD + i];
    }
    __syncthreads();
    jacobi32<false>(A, nullptr, csn, tid, 10);
    float loc = 0.f;
    if (tid < 32) {
        float l = logf(fmaxf(A[tid * LDSD + tid], EV_EPS));
        loc = l * l;
    }
#pragma unroll
    for (int off = 32; off > 0; off >>= 1) loc += __shfl_down(loc, off);
    if (tid == 0) D[b * NC + c] = sqrtf(loc);
}

__global__ void k_loss(const float* out, const int* labels, const float* D, int B, float* res) {
    __shared__ float sI[256], sD[256], sC[256];
    int tid = threadIdx.x;
    float aI = 0.f, aD = 0.f, aC = 0.f;
    for (int b = tid; b < B; b += 256) {
        int lb = labels[b];
        const float* ob = out + b * NC;
        float m = ob[0];
#pragma unroll
        for (int j = 1; j < NC; ++j) m = fmaxf(m, ob[j]);
        float se = 0.f;
#pragma unroll
        for (int j = 0; j < NC; ++j) se += expf(ob[j] - m);
        aC += m + logf(se) - ob[lb];
        const float* db = D + b * NC;
        float s = 0.f;
#pragma unroll
        for (int j = 0; j < NC; ++j) s += db[j];
        aI += db[lb];
        aD += s - db[lb];
    }
    sI[tid] = aI; sD[tid] = aD; sC[tid] = aC;
    __syncthreads();
    for (int off = 128; off > 0; off >>= 1) {
        if (tid < off) { sI[tid] += sI[tid + off]; sD[tid] += sD[tid + off]; sC[tid] += sC[tid + off]; }
        __syncthreads();
    }
    if (tid == 0) {
        float intra = 0.001f * sI[0] / (float)B;
        float disp = sD[0] / (float)(B * (NC - 1));
        float ce = sC[0] / (float)B;
        res[0] = intra - 0.001f * disp + ce;
    }
}

extern "C" void kernel_launch(void* const* d_in, const int* in_sizes, int n_in,
                              void* d_out, int out_size, void* d_ws, size_t ws_size,
                              hipStream_t stream) {
    const float* X = (const float*)d_in[0];
    const float* out = (const float*)d_in[1];
    const int* labels = (const int*)d_in[2];
    int B = in_sizes[2];

    float* ws = (float*)d_ws;
    float* bary0    = ws;                 // 8192
    float* sqrtm    = ws + 8192;          // 8192
    float* invsqrtm = ws + 16384;         // 8192
    float* meanT    = ws + 24576;         // 8192
    float* bary     = ws + 32768;         // 8192
    float* D        = ws + 40960;         // B*8 = 16384
    int*   counts   = (int*)(ws + 57344); // 8
    float* big      = ws + 65536;         // B*1024 = 2M floats (T, then W=L^-1)

    k_count<<<1, 64, 0, stream>>>(labels, B, counts);
    k_bary0<<<NC, 256, 0, stream>>>(X, labels, counts, B, bary0);
    k_eig_bary0<<<NC, 64, 0, stream>>>(bary0, sqrtm, invsqrtm);
    k_tangent<<<B, 64, 0, stream>>>(X, labels, sqrtm, invsqrtm, big);
    k_meanT<<<NC, 256, 0, stream>>>(big, labels, counts, B, meanT);
    k_update<<<NC, 64, 0, stream>>>(meanT, sqrtm, invsqrtm, bary0, bary);
    k_cholinv<<<B, 64, 0, stream>>>(X, big);
    k_pairdist<<<B * NC, 64, 0, stream>>>(big, bary, D);
    k_loss<<<1, 256, 0, stream>>>(out, labels, D, B, (float*)d_out);
}

// Round 2
// 3326.636 us; speedup vs baseline: 1.3555x; 1.3555x over previous
//
#include <hip/hip_runtime.h>
#include <math.h>

#define NC 8
#define NDIM 32
#define LDSD 34            // stride 34: rows 8B-aligned (float2), col access = 2-way bank alias (free on CDNA4)
#define MAT (NDIM * LDSD)  // 1088 floats per LDS matrix
#define EV_EPS 1e-10f
#define BMAX 2048

// ---------- round-robin tournament pairing: 16 disjoint pairs x 31 rounds ----------
__device__ inline void rr_pair(int r, int k, int& p, int& q) {
    int a, b;
    if (k == 0) { a = 31; b = r; }
    else { a = (r + k) % 31; b = (r - k + 62) % 31; }
    p = a < b ? a : b;
    q = a < b ? b : a;
}

template <int NT>
__device__ inline void build_pq(ushort* pq, int tid) {
    for (int e = tid; e < 496; e += NT) {
        int r = e >> 4, kk = e & 15;
        int p, q; rr_pair(r, kk, p, q);
        pq[e] = (ushort)(p | (q << 8));
    }
}

// block-wide sum (NT = 64 or 128); scratch needs 2 floats for NT=128
template <int NT>
__device__ inline float bsum(float v, float* scratch, int tid) {
#pragma unroll
    for (int off = 32; off > 0; off >>= 1) v += __shfl_down(v, off);
    if constexpr (NT == 64) {
        return __shfl(v, 0);
    } else {
        if ((tid & 63) == 0) scratch[tid >> 6] = v;
        __syncthreads();
        float r = scratch[0] + scratch[1];
        __syncthreads();
        return r;
    }
}

// ---------- 32x32 LDS helpers ----------
template <int NT>
__device__ inline void g2l(const float* g, float* l, int tid) {
    for (int idx2 = tid; idx2 < 512; idx2 += NT) {
        int i = idx2 >> 4, jp = idx2 & 15;
        *(float2*)&l[i * LDSD + 2 * jp] = *(const float2*)&g[i * 32 + 2 * jp];
    }
}
template <int NT>
__device__ inline void l2g(const float* l, float* g, int tid) {
    for (int idx2 = tid; idx2 < 512; idx2 += NT) {
        int i = idx2 >> 4, jp = idx2 & 15;
        *(float2*)&g[i * 32 + 2 * jp] = *(const float2*)&l[i * LDSD + 2 * jp];
    }
}
// C = A * B (all LDS, stride LDSD)
template <int NT>
__device__ inline void mm_nn(const float* A, const float* B, float* C, int tid) {
    for (int idx2 = tid; idx2 < 512; idx2 += NT) {
        int i = idx2 >> 4, jp = idx2 & 15;
        const float* Ar = A + i * LDSD;
        const float* Bp = B + 2 * jp;
        float2 acc; acc.x = 0.f; acc.y = 0.f;
#pragma unroll
        for (int k = 0; k < 32; ++k) {
            float a = Ar[k];
            float2 b = *(const float2*)(Bp + k * LDSD);
            acc.x = fmaf(a, b.x, acc.x); acc.y = fmaf(a, b.y, acc.y);
        }
        *(float2*)&C[i * LDSD + 2 * jp] = acc;
    }
}
// C(global, stride 32) = A * B
template <int NT>
__device__ inline void mm_nn_g(const float* A, const float* B, float* gC, int tid) {
    for (int idx2 = tid; idx2 < 512; idx2 += NT) {
        int i = idx2 >> 4, jp = idx2 & 15;
        const float* Ar = A + i * LDSD;
        const float* Bp = B + 2 * jp;
        float2 acc; acc.x = 0.f; acc.y = 0.f;
#pragma unroll
        for (int k = 0; k < 32; ++k) {
            float a = Ar[k];
            float2 b = *(const float2*)(Bp + k * LDSD);
            acc.x = fmaf(a, b.x, acc.x); acc.y = fmaf(a, b.y, acc.y);
        }
        *(float2*)&gC[i * 32 + 2 * jp] = acc;
    }
}
// C = A^T * B  (C[i][j] = sum_k A[k][i] * B[k][j])
template <int NT>
__device__ inline void mm_tn(const float* A, const float* B, float* C, int tid) {
    for (int idx2 = tid; idx2 < 512; idx2 += NT) {
        int i = idx2 >> 4, jp = idx2 & 15;
        float2 acc; acc.x = 0.f; acc.y = 0.f;
#pragma unroll
        for (int k = 0; k < 32; ++k) {
            float a = A[k * LDSD + i];
            float2 b = *(const float2*)&B[k * LDSD + 2 * jp];
            acc.x = fmaf(a, b.x, acc.x); acc.y = fmaf(a, b.y, acc.y);
        }
        *(float2*)&C[i * LDSD + 2 * jp] = acc;
    }
}
// C(global) = A^T * B
template <int NT>
__device__ inline void mm_tn_g(const float* A, const float* B, float* gC, int tid) {
    for (int idx2 = tid; idx2 < 512; idx2 += NT) {
        int i = idx2 >> 4, jp = idx2 & 15;
        float2 acc; acc.x = 0.f; acc.y = 0.f;
#pragma unroll
        for (int k = 0; k < 32; ++k) {
            float a = A[k * LDSD + i];
            float2 b = *(const float2*)&B[k * LDSD + 2 * jp];
            acc.x = fmaf(a, b.x, acc.x); acc.y = fmaf(a, b.y, acc.y);
        }
        *(float2*)&gC[i * 32 + 2 * jp] = acc;
    }
}

// ---------- parallel Jacobi eigensolver, 32x32 symmetric ----------
// A in LDS (stride LDSD). If WANT_V, Vt accumulates TRANSPOSED eigenvectors:
// V[i][k] = Vt[k][i]. csn: [0..15]=c, [16..31]=s, [32..33]=reduce scratch.
template <int NT, bool WANT_V>
__device__ void jacobi32(float* A, float* Vt, float* csn, const ushort* pq, int tid, int max_sweeps) {
    if (WANT_V) {
        for (int idx = tid; idx < 1024; idx += NT) {
            int i = idx >> 5, j = idx & 31;
            Vt[i * LDSD + j] = (i == j) ? 1.f : 0.f;
        }
    }
    float loc = 0.f;
    for (int idx2 = tid; idx2 < 512; idx2 += NT) {
        int i = idx2 >> 4, jp = idx2 & 15;
        float2 v = *(const float2*)&A[i * LDSD + 2 * jp];
        loc += v.x * v.x + v.y * v.y;
    }
    float fro2 = bsum<NT>(loc, csn + 32, tid);
    float tol2 = fro2 * 1e-12f + 1e-30f;
    __syncthreads();

    for (int sweep = 0; sweep < max_sweeps; ++sweep) {
        for (int r = 0; r < 31; ++r) {
            const ushort* pqr = pq + (r << 4);
            if (tid < 16) {
                int e = pqr[tid], p = e & 31, q = e >> 8;
                float apq = A[p * LDSD + q];
                float c = 1.f, s = 0.f;
                if (fabsf(apq) > 1e-36f) {
                    float app = A[p * LDSD + p], aqq = A[q * LDSD + q];
                    float tau = (aqq - app) / (2.f * apq);
                    float t = (tau >= 0.f ? 1.f : -1.f) / (fabsf(tau) + sqrtf(1.f + tau * tau));
                    c = 1.f / sqrtf(1.f + t * t);
                    s = t * c;
                }
                csn[tid] = c; csn[16 + tid] = s;
            }
            __syncthreads();
            // row rotations on A: 16 pairs x 16 col-pairs (float2)
            for (int item = tid; item < 256; item += NT) {
                int k = item >> 4, g = item & 15;
                int e = pqr[k], p = e & 31, q = e >> 8;
                float c = csn[k], s = csn[16 + k];
                float2 ap = *(float2*)&A[p * LDSD + 2 * g];
                float2 aq = *(float2*)&A[q * LDSD + 2 * g];
                float2 np, nq;
                np.x = c * ap.x - s * aq.x; np.y = c * ap.y - s * aq.y;
                nq.x = s * ap.x + c * aq.x; nq.y = s * ap.y + c * aq.y;
                *(float2*)&A[p * LDSD + 2 * g] = np;
                *(float2*)&A[q * LDSD + 2 * g] = nq;
            }
            __syncthreads();
            // col rotations on A (b32, stride-34 = 2-way alias, free)
            for (int item = tid; item < 512; item += NT) {
                int k = item >> 5, i = item & 31;
                int e = pqr[k], p = e & 31, q = e >> 8;
                float c = csn[k], s = csn[16 + k];
                float ap = A[i * LDSD + p], aq = A[i * LDSD + q];
                A[i * LDSD + p] = c * ap - s * aq;
                A[i * LDSD + q] = s * ap + c * aq;
            }
            // Vt row rotations (= V col rotations), float2
            if (WANT_V) {
                for (int item = tid; item < 256; item += NT) {
                    int k = item >> 4, g = item & 15;
                    int e = pqr[k], p = e & 31, q = e >> 8;
                    float c = csn[k], s = csn[16 + k];
                    float2 vp = *(float2*)&Vt[p * LDSD + 2 * g];
                    float2 vq = *(float2*)&Vt[q * LDSD + 2 * g];
                    float2 np, nq;
                    np.x = c * vp.x - s * vq.x; np.y = c * vp.y - s * vq.y;
                    nq.x = s * vp.x + c * vq.x; nq.y = s * vp.y + c * vq.y;
                    *(float2*)&Vt[p * LDSD + 2 * g] = np;
                    *(float2*)&Vt[q * LDSD + 2 * g] = nq;
                }
            }
            __syncthreads();
        }
        // off-diagonal norm for early exit
        float l2 = 0.f;
        for (int idx2 = tid; idx2 < 512; idx2 += NT) {
            int i = idx2 >> 4, jp = idx2 & 15;
            float2 v = *(const float2*)&A[i * LDSD + 2 * jp];
            if ((i >> 1) == jp) { if (i & 1) v.y = 0.f; else v.x = 0.f; }
            l2 += v.x * v.x + v.y * v.y;
        }
        l2 = bsum<NT>(l2, csn + 32, tid);
        if (l2 <= tol2) break;
    }
    __syncthreads();
}

// ---------- kernels ----------
__global__ void k_count(const int* labels, int B, int* counts) {
    int tid = threadIdx.x;
    if (tid < NC) {
        int cnt = 0;
        for (int b = 0; b < B; ++b) cnt += (labels[b] == tid);
        counts[tid] = cnt;
    }
}

__global__ void k_bary0(const float* X, const int* labels, const int* counts, int B, float* bary0) {
    __shared__ int lab[BMAX];
    int c = blockIdx.x, tid = threadIdx.x;
    for (int b = tid; b < B; b += 256) lab[b] = labels[b];
    __syncthreads();
    float acc[4] = {0.f, 0.f, 0.f, 0.f};
    for (int b = 0; b < B; ++b) {
        if (lab[b] == c) {
#pragma unroll
            for (int e = 0; e < 4; ++e) acc[e] += X[b * 1024 + tid + 256 * e];
        }
    }
    float inv = 1.f / (float)counts[c];
#pragma unroll
    for (int e = 0; e < 4; ++e) bary0[c * 1024 + tid + 256 * e] = acc[e] * inv;
}

__global__ void __launch_bounds__(64) k_eig_bary0(const float* bary0, float* sqrtm, float* invsqrtm) {
    __shared__ __align__(16) float A[MAT], Vt[MAT], T1[MAT];
    __shared__ float csn[36], evs[32];
    __shared__ ushort pq[496];
    int c = blockIdx.x, tid = threadIdx.x;
    build_pq<64>(pq, tid);
    g2l<64>(bary0 + c * 1024, A, tid);
    __syncthreads();
    jacobi32<64, true>(A, Vt, csn, pq, tid, 10);
    if (tid < 32) evs[tid] = sqrtf(fmaxf(A[tid * LDSD + tid], 0.f));
    __syncthreads();
    for (int idx2 = tid; idx2 < 512; idx2 += 64) {     // T1 = diag(evs) * Vt
        int i = idx2 >> 4, jp = idx2 & 15;
        float2 v = *(const float2*)&Vt[i * LDSD + 2 * jp];
        float e = evs[i];
        float2 w; w.x = e * v.x; w.y = e * v.y;
        *(float2*)&T1[i * LDSD + 2 * jp] = w;
    }
    __syncthreads();
    mm_tn_g<64>(Vt, T1, sqrtm + c * 1024, tid);        // sqrtm = Vt^T diag Vt
    if (tid < 32) evs[tid] = 1.f / sqrtf(fmaxf(A[tid * LDSD + tid], 1e-30f));
    __syncthreads();
    for (int idx2 = tid; idx2 < 512; idx2 += 64) {
        int i = idx2 >> 4, jp = idx2 & 15;
        float2 v = *(const float2*)&Vt[i * LDSD + 2 * jp];
        float e = evs[i];
        float2 w; w.x = e * v.x; w.y = e * v.y;
        *(float2*)&T1[i * LDSD + 2 * jp] = w;
    }
    __syncthreads();
    mm_tn_g<64>(Vt, T1, invsqrtm + c * 1024, tid);
}

__global__ void __launch_bounds__(128) k_tangent(const float* X, const int* labels, const float* sqrtm,
                                                 const float* invsqrtm, float* Tbuf) {
    __shared__ __align__(16) float X1[MAT], S1[MAT], T1[MAT], Vt[MAT];
    __shared__ float csn[36], evs[32];
    __shared__ ushort pq[496];
    int b = blockIdx.x, tid = threadIdx.x;
    int lb = labels[b];
    build_pq<128>(pq, tid);
    g2l<128>(X + b * 1024, X1, tid);
    g2l<128>(invsqrtm + lb * 1024, S1, tid);
    __syncthreads();
    mm_nn<128>(S1, X1, T1, tid); __syncthreads();
    mm_nn<128>(T1, S1, X1, tid); __syncthreads();       // A = S X S -> X1
    jacobi32<128, true>(X1, Vt, csn, pq, tid, 10);
    if (tid < 32) evs[tid] = logf(fmaxf(X1[tid * LDSD + tid], EV_EPS));
    __syncthreads();
    for (int idx2 = tid; idx2 < 512; idx2 += 128) {     // T1 = diag(log ev) * Vt
        int i = idx2 >> 4, jp = idx2 & 15;
        float2 v = *(const float2*)&Vt[i * LDSD + 2 * jp];
        float e = evs[i];
        float2 w; w.x = e * v.x; w.y = e * v.y;
        *(float2*)&T1[i * LDSD + 2 * jp] = w;
    }
    __syncthreads();
    mm_tn<128>(Vt, T1, X1, tid);                        // logM -> X1
    g2l<128>(sqrtm + lb * 1024, S1, tid);               // S1 = sqrtm
    __syncthreads();
    mm_nn<128>(S1, X1, T1, tid); __syncthreads();
    mm_nn_g<128>(T1, S1, Tbuf + b * 1024, tid);         // T = sqrtm logM sqrtm
}

__global__ void k_meanT(const float* Tbuf, const int* labels, const int* counts, int B, float* meanT) {
    __shared__ int lab[BMAX];
    int c = blockIdx.x, tid = threadIdx.x;
    for (int b = tid; b < B; b += 256) lab[b] = labels[b];
    __syncthreads();
    float acc[4] = {0.f, 0.f, 0.f, 0.f};
    for (int b = 0; b < B; ++b) {
        if (lab[b] == c) {
#pragma unroll
            for (int e = 0; e < 4; ++e) acc[e] += Tbuf[b * 1024 + tid + 256 * e];
        }
    }
    float inv = 1.f / (float)counts[c];
#pragma unroll
    for (int e = 0; e < 4; ++e) meanT[c * 1024 + tid + 256 * e] = acc[e] * inv;
}

__global__ void __launch_bounds__(64) k_update(const float* meanT, const float* sqrtm, const float* invsqrtm,
                                               const float* bary0, float* bary) {
    __shared__ __align__(16) float X1[MAT], S1[MAT], T1[MAT], Vt[MAT];
    __shared__ float csn[36], evs[32];
    __shared__ ushort pq[496];
    int c = blockIdx.x, tid = threadIdx.x;
    build_pq<64>(pq, tid);
    g2l<64>(meanT + c * 1024, X1, tid);
    g2l<64>(invsqrtm + c * 1024, S1, tid);
    __syncthreads();
    mm_nn<64>(S1, X1, T1, tid); __syncthreads();
    mm_nn<64>(T1, S1, X1, tid); __syncthreads();        // N -> X1
    jacobi32<64, true>(X1, Vt, csn, pq, tid, 10);
    // faithful quirk: clamp eigenvalues to >= 1e-10 BEFORE exp
    if (tid < 32) evs[tid] = expf(fmaxf(X1[tid * LDSD + tid], EV_EPS));
    __syncthreads();
    for (int idx2 = tid; idx2 < 512; idx2 += 64) {
        int i = idx2 >> 4, jp = idx2 & 15;
        float2 v = *(const float2*)&Vt[i * LDSD + 2 * jp];
        float e = evs[i];
        float2 w; w.x = e * v.x; w.y = e * v.y;
        *(float2*)&T1[i * LDSD + 2 * jp] = w;
    }
    __syncthreads();
    mm_tn<64>(Vt, T1, S1, tid);                         // expN -> S1
    __syncthreads();
    g2l<64>(sqrtm + c * 1024, Vt, tid);                 // Vt = sqrtm
    __syncthreads();
    mm_nn<64>(Vt, S1, T1, tid); __syncthreads();
    mm_nn<64>(T1, Vt, X1, tid); __syncthreads();        // new barycenter -> X1
    float loc = 0.f;
    for (int idx = tid; idx < 1024; idx += 64) {
        int i = idx >> 5, j = idx & 31;
        float d = X1[i * LDSD + j] - bary0[c * 1024 + idx];
        loc += d * d;
    }
#pragma unroll
    for (int off = 32; off > 0; off >>= 1) loc += __shfl_down(loc, off);
    float err2 = __shfl(loc, 0);
    bool keep0 = (err2 < 1e-8f);  // CONV_TOL^2
    for (int idx = tid; idx < 1024; idx += 64) {
        int i = idx >> 5, j = idx & 31;
        bary[c * 1024 + idx] = keep0 ? bary0[c * 1024 + idx] : X1[i * LDSD + j];
    }
}

__global__ void __launch_bounds__(64) k_cholinv(const float* X, float* WtBuf) {
    __shared__ __align__(16) float A[MAT], W[MAT];
    int b = blockIdx.x, tid = threadIdx.x;
    g2l<64>(X + b * 1024, A, tid);
    __syncthreads();
    if (tid < 32) A[tid * LDSD + tid] += 1e-3f;  // CHOL_EPS
    __syncthreads();
    // right-looking Cholesky (lower triangle)
    for (int k = 0; k < 32; ++k) {
        if (tid == 0) A[k * LDSD + k] = sqrtf(A[k * LDSD + k]);
        __syncthreads();
        float invd = 1.f / A[k * LDSD + k];
        if (tid > k && tid < 32) A[tid * LDSD + k] *= invd;
        __syncthreads();
        for (int idx = tid; idx < 1024; idx += 64) {
            int i = idx >> 5, j = idx & 31;
            if (i > k && j > k && j <= i) A[i * LDSD + j] -= A[i * LDSD + k] * A[j * LDSD + k];
        }
        __syncthreads();
    }
    // W = L^{-1}: thread j forward-substitutes column j
    if (tid < 32) {
        int j = tid;
        W[j * LDSD + j] = 1.f / A[j * LDSD + j];
        for (int i = j + 1; i < 32; ++i) {
            float acc = 0.f;
            for (int k2 = j; k2 < i; ++k2) acc += A[i * LDSD + k2] * W[k2 * LDSD + j];
            W[i * LDSD + j] = -acc / A[i * LDSD + i];
        }
        for (int i = 0; i < j; ++i) W[i * LDSD + j] = 0.f;  // zero upper
    }
    __syncthreads();
    // store Wt = W^T = L^{-T} (row-major, stride 32)
    for (int idx = tid; idx < 1024; idx += 64) {
        int i = idx >> 5, j = idx & 31;
        WtBuf[b * 1024 + idx] = W[j * LDSD + i];
    }
}

__global__ void __launch_bounds__(64) k_pairdist(const float* WtBuf, const float* bary, float* D) {
    __shared__ __align__(16) float Wl[MAT], Bc[MAT], T1[MAT];
    __shared__ float csn[36];
    __shared__ ushort pq[496];
    int b = blockIdx.x >> 3, c = blockIdx.x & 7, tid = threadIdx.x;
    build_pq<64>(pq, tid);
    g2l<64>(WtBuf + b * 1024, Wl, tid);   // Wl = L^{-T}
    g2l<64>(bary + c * 1024, Bc, tid);
    __syncthreads();
    // faithful quirk: M = L^{-T} bary L^{-T} (both sides un-transposed)
    mm_nn<64>(Wl, Bc, T1, tid); __syncthreads();
    mm_nn<64>(T1, Wl, Bc, tid); __syncthreads();  // M -> Bc
    // eigvalsh(UPLO='L'): mirror lower triangle into upper
    for (int idx = tid; idx < 1024; idx += 64) {
        int i = idx >> 5, j = idx & 31;
        if (i < j) Bc[i * LDSD + j] = Bc[j * LDSD + i];
    }
    __syncthreads();
    jacobi32<64, false>(Bc, nullptr, csn, pq, tid, 10);
    float loc = 0.f;
    if (tid < 32) {
        float l = logf(fmaxf(Bc[tid * LDSD + tid], EV_EPS));
        loc = l * l;
    }
#pragma unroll
    for (int off = 32; off > 0; off >>= 1) loc += __shfl_down(loc, off);
    if (tid == 0) D[b * NC + c] = sqrtf(loc);
}

__global__ void k_loss(const float* out, const int* labels, const float* D, int B, float* res) {
    __shared__ float sI[256], sD[256], sC[256];
    int tid = threadIdx.x;
    float aI = 0.f, aD = 0.f, aC = 0.f;
    for (int b = tid; b < B; b += 256) {
        int lb = labels[b];
        const float* ob = out + b * NC;
        float m = ob[0];
#pragma unroll
        for (int j = 1; j < NC; ++j) m = fmaxf(m, ob[j]);
        float se = 0.f;
#pragma unroll
        for (int j = 0; j < NC; ++j) se += expf(ob[j] - m);
        aC += m + logf(se) - ob[lb];
        const float* db = D + b * NC;
        float s = 0.f;
#pragma unroll
        for (int j = 0; j < NC; ++j) s += db[j];
        aI += db[lb];
        aD += s - db[lb];
    }
    sI[tid] = aI; sD[tid] = aD; sC[tid] = aC;
    __syncthreads();
    for (int off = 128; off > 0; off >>= 1) {
        if (tid < off) { sI[tid] += sI[tid + off]; sD[tid] += sD[tid + off]; sC[tid] += sC[tid + off]; }
        __syncthreads();
    }
    if (tid == 0) {
        float intra = 0.001f * sI[0] / (float)B;
        float disp = sD[0] / (float)(B * (NC - 1));
        float ce = sC[0] / (float)B;
        res[0] = intra - 0.001f * disp + ce;
    }
}

extern "C" void kernel_launch(void* const* d_in, const int* in_sizes, int n_in,
                              void* d_out, int out_size, void* d_ws, size_t ws_size,
                              hipStream_t stream) {
    const float* X = (const float*)d_in[0];
    const float* out = (const float*)d_in[1];
    const int* labels = (const int*)d_in[2];
    int B = in_sizes[2];

    float* ws = (float*)d_ws;
    float* bary0    = ws;                 // 8192
    float* sqrtm    = ws + 8192;          // 8192
    float* invsqrtm = ws + 16384;         // 8192
    float* meanT    = ws + 24576;         // 8192
    float* bary     = ws + 32768;         // 8192
    float* D        = ws + 40960;         // B*8 = 16384
    int*   counts   = (int*)(ws + 57344); // 8
    float* big      = ws + 65536;         // B*1024 = 2M floats (T, then Wt = L^-T)

    k_count<<<1, 64, 0, stream>>>(labels, B, counts);
    k_bary0<<<NC, 256, 0, stream>>>(X, labels, counts, B, bary0);
    k_eig_bary0<<<NC, 64, 0, stream>>>(bary0, sqrtm, invsqrtm);
    k_tangent<<<B, 128, 0, stream>>>(X, labels, sqrtm, invsqrtm, big);
    k_meanT<<<NC, 256, 0, stream>>>(big, labels, counts, B, meanT);
    k_update<<<NC, 64, 0, stream>>>(meanT, sqrtm, invsqrtm, bary0, bary);
    k_cholinv<<<B, 64, 0, stream>>>(X, big);
    k_pairdist<<<B * NC, 64, 0, stream>>>(big, bary, D);
    k_loss<<<1, 256, 0, stream>>>(out, labels, D, B, (float*)d_out);
}

// Round 3
// 2496.636 us; speedup vs baseline: 1.8061x; 1.3324x over previous
//
#include <hip/hip_runtime.h>
#include <math.h>

#define NC 8
#define NDIM 32
#define LDSD 34            // stride 34: rows 8B-aligned (float2)
#define MAT (NDIM * LDSD)  // 1088 floats per LDS matrix
#define EV_EPS 1e-10f
#define BMAX 2048

#if __has_builtin(__builtin_amdgcn_rcpf)
__device__ inline float fast_rcp(float x) { return __builtin_amdgcn_rcpf(x); }
#else
__device__ inline float fast_rcp(float x) { return 1.f / x; }
#endif
#if __has_builtin(__builtin_amdgcn_rsqf)
__device__ inline float fast_rsq(float x) { return __builtin_amdgcn_rsqf(x); }
#else
__device__ inline float fast_rsq(float x) { return 1.f / sqrtf(x); }
#endif

// ---------- round-robin tournament pairing: 16 disjoint pairs x 31 rounds ----------
__device__ inline void rr_pair(int r, int k, int& p, int& q) {
    int a, b;
    if (k == 0) { a = 31; b = r; }
    else { a = (r + k) % 31; b = (r - k + 62) % 31; }
    p = a < b ? a : b;
    q = a < b ? b : a;
}

template <int NT>
__device__ inline void build_pq(ushort* pq, int tid) {
    for (int e = tid; e < 496; e += NT) {
        int r = e >> 4, kk = e & 15;
        int p, q; rr_pair(r, kk, p, q);
        pq[e] = (ushort)(p | (q << 8));
    }
}

// block-wide sum (NT = 64 or 128); scratch needs 2 floats for NT=128
template <int NT>
__device__ inline float bsum(float v, float* scratch, int tid) {
#pragma unroll
    for (int off = 32; off > 0; off >>= 1) v += __shfl_down(v, off);
    if constexpr (NT == 64) {
        return __shfl(v, 0);
    } else {
        if ((tid & 63) == 0) scratch[tid >> 6] = v;
        __syncthreads();
        float r = scratch[0] + scratch[1];
        __syncthreads();
        return r;
    }
}

// ---------- 32x32 LDS helpers ----------
template <int NT>
__device__ inline void g2l(const float* g, float* l, int tid) {
    for (int idx2 = tid; idx2 < 512; idx2 += NT) {
        int i = idx2 >> 4, jp = idx2 & 15;
        *(float2*)&l[i * LDSD + 2 * jp] = *(const float2*)&g[i * 32 + 2 * jp];
    }
}
// C = A * B (all LDS, stride LDSD)
template <int NT>
__device__ inline void mm_nn(const float* A, const float* B, float* C, int tid) {
    for (int idx2 = tid; idx2 < 512; idx2 += NT) {
        int i = idx2 >> 4, jp = idx2 & 15;
        const float* Ar = A + i * LDSD;
        const float* Bp = B + 2 * jp;
        float2 acc; acc.x = 0.f; acc.y = 0.f;
#pragma unroll
        for (int k = 0; k < 32; ++k) {
            float a = Ar[k];
            float2 b = *(const float2*)(Bp + k * LDSD);
            acc.x = fmaf(a, b.x, acc.x); acc.y = fmaf(a, b.y, acc.y);
        }
        *(float2*)&C[i * LDSD + 2 * jp] = acc;
    }
}
// C(global, stride 32) = A * B
template <int NT>
__device__ inline void mm_nn_g(const float* A, const float* B, float* gC, int tid) {
    for (int idx2 = tid; idx2 < 512; idx2 += NT) {
        int i = idx2 >> 4, jp = idx2 & 15;
        const float* Ar = A + i * LDSD;
        const float* Bp = B + 2 * jp;
        float2 acc; acc.x = 0.f; acc.y = 0.f;
#pragma unroll
        for (int k = 0; k < 32; ++k) {
            float a = Ar[k];
            float2 b = *(const float2*)(Bp + k * LDSD);
            acc.x = fmaf(a, b.x, acc.x); acc.y = fmaf(a, b.y, acc.y);
        }
        *(float2*)&gC[i * 32 + 2 * jp] = acc;
    }
}
// C = A^T * B
template <int NT>
__device__ inline void mm_tn(const float* A, const float* B, float* C, int tid) {
    for (int idx2 = tid; idx2 < 512; idx2 += NT) {
        int i = idx2 >> 4, jp = idx2 & 15;
        float2 acc; acc.x = 0.f; acc.y = 0.f;
#pragma unroll
        for (int k = 0; k < 32; ++k) {
            float a = A[k * LDSD + i];
            float2 b = *(const float2*)&B[k * LDSD + 2 * jp];
            acc.x = fmaf(a, b.x, acc.x); acc.y = fmaf(a, b.y, acc.y);
        }
        *(float2*)&C[i * LDSD + 2 * jp] = acc;
    }
}
// C(global) = A^T * B
template <int NT>
__device__ inline void mm_tn_g(const float* A, const float* B, float* gC, int tid) {
    for (int idx2 = tid; idx2 < 512; idx2 += NT) {
        int i = idx2 >> 4, jp = idx2 & 15;
        float2 acc; acc.x = 0.f; acc.y = 0.f;
#pragma unroll
        for (int k = 0; k < 32; ++k) {
            float a = A[k * LDSD + i];
            float2 b = *(const float2*)&B[k * LDSD + 2 * jp];
            acc.x = fmaf(a, b.x, acc.x); acc.y = fmaf(a, b.y, acc.y);
        }
        *(float2*)&gC[i * 32 + 2 * jp] = acc;
    }
}

// ---------- LDS parallel Jacobi (used by the few-block kernels) ----------
template <int NT, bool WANT_V>
__device__ void jacobi32(float* A, float* Vt, float* csn, const ushort* pq, int tid, int max_sweeps) {
    if (WANT_V) {
        for (int idx = tid; idx < 1024; idx += NT) {
            int i = idx >> 5, j = idx & 31;
            Vt[i * LDSD + j] = (i == j) ? 1.f : 0.f;
        }
    }
    float loc = 0.f;
    for (int idx2 = tid; idx2 < 512; idx2 += NT) {
        int i = idx2 >> 4, jp = idx2 & 15;
        float2 v = *(const float2*)&A[i * LDSD + 2 * jp];
        loc += v.x * v.x + v.y * v.y;
    }
    float fro2 = bsum<NT>(loc, csn + 32, tid);
    float tol2 = fro2 * 1e-9f + 1e-30f;
    __syncthreads();

    for (int sweep = 0; sweep < max_sweeps; ++sweep) {
        for (int r = 0; r < 31; ++r) {
            const ushort* pqr = pq + (r << 4);
            if (tid < 16) {
                int e = pqr[tid], p = e & 31, q = e >> 8;
                float apq = A[p * LDSD + q];
                float c = 1.f, s = 0.f;
                if (fabsf(apq) > 1e-36f) {
                    float app = A[p * LDSD + p], aqq = A[q * LDSD + q];
                    float tau = (aqq - app) / (2.f * apq);
                    float t = (tau >= 0.f ? 1.f : -1.f) / (fabsf(tau) + sqrtf(1.f + tau * tau));
                    c = 1.f / sqrtf(1.f + t * t);
                    s = t * c;
                }
                csn[tid] = c; csn[16 + tid] = s;
            }
            __syncthreads();
            for (int item = tid; item < 256; item += NT) {
                int k = item >> 4, g = item & 15;
                int e = pqr[k], p = e & 31, q = e >> 8;
                float c = csn[k], s = csn[16 + k];
                float2 ap = *(float2*)&A[p * LDSD + 2 * g];
                float2 aq = *(float2*)&A[q * LDSD + 2 * g];
                float2 np, nq;
                np.x = c * ap.x - s * aq.x; np.y = c * ap.y - s * aq.y;
                nq.x = s * ap.x + c * aq.x; nq.y = s * ap.y + c * aq.y;
                *(float2*)&A[p * LDSD + 2 * g] = np;
                *(float2*)&A[q * LDSD + 2 * g] = nq;
            }
            __syncthreads();
            for (int item = tid; item < 512; item += NT) {
                int k = item >> 5, i = item & 31;
                int e = pqr[k], p = e & 31, q = e >> 8;
                float c = csn[k], s = csn[16 + k];
                float ap = A[i * LDSD + p], aq = A[i * LDSD + q];
                A[i * LDSD + p] = c * ap - s * aq;
                A[i * LDSD + q] = s * ap + c * aq;
            }
            if (WANT_V) {
                for (int item = tid; item < 256; item += NT) {
                    int k = item >> 4, g = item & 15;
                    int e = pqr[k], p = e & 31, q = e >> 8;
                    float c = csn[k], s = csn[16 + k];
                    float2 vp = *(float2*)&Vt[p * LDSD + 2 * g];
                    float2 vq = *(float2*)&Vt[q * LDSD + 2 * g];
                    float2 np, nq;
                    np.x = c * vp.x - s * vq.x; np.y = c * vp.y - s * vq.y;
                    nq.x = s * vp.x + c * vq.x; nq.y = s * vp.y + c * vq.y;
                    *(float2*)&Vt[p * LDSD + 2 * g] = np;
                    *(float2*)&Vt[q * LDSD + 2 * g] = nq;
                }
            }
            __syncthreads();
        }
        float l2 = 0.f;
        for (int idx2 = tid; idx2 < 512; idx2 += NT) {
            int i = idx2 >> 4, jp = idx2 & 15;
            float2 v = *(const float2*)&A[i * LDSD + 2 * jp];
            if ((i >> 1) == jp) { if (i & 1) v.y = 0.f; else v.x = 0.f; }
            l2 += v.x * v.x + v.y * v.y;
        }
        l2 = bsum<NT>(l2, csn + 32, tid);
        if (l2 <= tol2) break;
    }
    __syncthreads();
}

// ---------- kernels ----------
__global__ void k_count(const int* labels, int B, int* counts) {
    int tid = threadIdx.x;
    if (tid < NC) {
        int cnt = 0;
        for (int b = 0; b < B; ++b) cnt += (labels[b] == tid);
        counts[tid] = cnt;
    }
}

__global__ void k_bary0(const float* X, const int* labels, const int* counts, int B, float* bary0) {
    __shared__ int lab[BMAX];
    int c = blockIdx.x, tid = threadIdx.x;
    for (int b = tid; b < B; b += 256) lab[b] = labels[b];
    __syncthreads();
    float acc[4] = {0.f, 0.f, 0.f, 0.f};
    for (int b = 0; b < B; ++b) {
        if (lab[b] == c) {
#pragma unroll
            for (int e = 0; e < 4; ++e) acc[e] += X[b * 1024 + tid + 256 * e];
        }
    }
    float inv = 1.f / (float)counts[c];
#pragma unroll
    for (int e = 0; e < 4; ++e) bary0[c * 1024 + tid + 256 * e] = acc[e] * inv;
}

__global__ void __launch_bounds__(64) k_eig_bary0(const float* bary0, float* sqrtm, float* invsqrtm) {
    __shared__ __align__(16) float A[MAT], Vt[MAT], T1[MAT];
    __shared__ float csn[36], evs[32];
    __shared__ ushort pq[496];
    int c = blockIdx.x, tid = threadIdx.x;
    build_pq<64>(pq, tid);
    g2l<64>(bary0 + c * 1024, A, tid);
    __syncthreads();
    jacobi32<64, true>(A, Vt, csn, pq, tid, 8);
    if (tid < 32) evs[tid] = sqrtf(fmaxf(A[tid * LDSD + tid], 0.f));
    __syncthreads();
    for (int idx2 = tid; idx2 < 512; idx2 += 64) {
        int i = idx2 >> 4, jp = idx2 & 15;
        float2 v = *(const float2*)&Vt[i * LDSD + 2 * jp];
        float e = evs[i];
        float2 w; w.x = e * v.x; w.y = e * v.y;
        *(float2*)&T1[i * LDSD + 2 * jp] = w;
    }
    __syncthreads();
    mm_tn_g<64>(Vt, T1, sqrtm + c * 1024, tid);
    if (tid < 32) evs[tid] = 1.f / sqrtf(fmaxf(A[tid * LDSD + tid], 1e-30f));
    __syncthreads();
    for (int idx2 = tid; idx2 < 512; idx2 += 64) {
        int i = idx2 >> 4, jp = idx2 & 15;
        float2 v = *(const float2*)&Vt[i * LDSD + 2 * jp];
        float e = evs[i];
        float2 w; w.x = e * v.x; w.y = e * v.y;
        *(float2*)&T1[i * LDSD + 2 * jp] = w;
    }
    __syncthreads();
    mm_tn_g<64>(Vt, T1, invsqrtm + c * 1024, tid);
}

__global__ void __launch_bounds__(128) k_tangent(const float* X, const int* labels, const float* sqrtm,
                                                 const float* invsqrtm, float* Tbuf) {
    __shared__ __align__(16) float X1[MAT], S1[MAT], T1[MAT], Vt[MAT];
    __shared__ float csn[36], evs[32];
    __shared__ ushort pq[496];
    int b = blockIdx.x, tid = threadIdx.x;
    int lb = labels[b];
    build_pq<128>(pq, tid);
    g2l<128>(X + b * 1024, X1, tid);
    g2l<128>(invsqrtm + lb * 1024, S1, tid);
    __syncthreads();
    mm_nn<128>(S1, X1, T1, tid); __syncthreads();
    mm_nn<128>(T1, S1, X1, tid); __syncthreads();
    jacobi32<128, true>(X1, Vt, csn, pq, tid, 8);
    if (tid < 32) evs[tid] = logf(fmaxf(X1[tid * LDSD + tid], EV_EPS));
    __syncthreads();
    for (int idx2 = tid; idx2 < 512; idx2 += 128) {
        int i = idx2 >> 4, jp = idx2 & 15;
        float2 v = *(const float2*)&Vt[i * LDSD + 2 * jp];
        float e = evs[i];
        float2 w; w.x = e * v.x; w.y = e * v.y;
        *(float2*)&T1[i * LDSD + 2 * jp] = w;
    }
    __syncthreads();
    mm_tn<128>(Vt, T1, X1, tid);
    g2l<128>(sqrtm + lb * 1024, S1, tid);
    __syncthreads();
    mm_nn<128>(S1, X1, T1, tid); __syncthreads();
    mm_nn_g<128>(T1, S1, Tbuf + b * 1024, tid);
}

__global__ void k_meanT(const float* Tbuf, const int* labels, const int* counts, int B, float* meanT) {
    __shared__ int lab[BMAX];
    int c = blockIdx.x, tid = threadIdx.x;
    for (int b = tid; b < B; b += 256) lab[b] = labels[b];
    __syncthreads();
    float acc[4] = {0.f, 0.f, 0.f, 0.f};
    for (int b = 0; b < B; ++b) {
        if (lab[b] == c) {
#pragma unroll
            for (int e = 0; e < 4; ++e) acc[e] += Tbuf[b * 1024 + tid + 256 * e];
        }
    }
    float inv = 1.f / (float)counts[c];
#pragma unroll
    for (int e = 0; e < 4; ++e) meanT[c * 1024 + tid + 256 * e] = acc[e] * inv;
}

__global__ void __launch_bounds__(64) k_update(const float* meanT, const float* sqrtm, const float* invsqrtm,
                                               const float* bary0, float* bary) {
    __shared__ __align__(16) float X1[MAT], S1[MAT], T1[MAT], Vt[MAT];
    __shared__ float csn[36], evs[32];
    __shared__ ushort pq[496];
    int c = blockIdx.x, tid = threadIdx.x;
    build_pq<64>(pq, tid);
    g2l<64>(meanT + c * 1024, X1, tid);
    g2l<64>(invsqrtm + c * 1024, S1, tid);
    __syncthreads();
    mm_nn<64>(S1, X1, T1, tid); __syncthreads();
    mm_nn<64>(T1, S1, X1, tid); __syncthreads();
    jacobi32<64, true>(X1, Vt, csn, pq, tid, 8);
    // faithful quirk: clamp eigenvalues to >= 1e-10 BEFORE exp
    if (tid < 32) evs[tid] = expf(fmaxf(X1[tid * LDSD + tid], EV_EPS));
    __syncthreads();
    for (int idx2 = tid; idx2 < 512; idx2 += 64) {
        int i = idx2 >> 4, jp = idx2 & 15;
        float2 v = *(const float2*)&Vt[i * LDSD + 2 * jp];
        float e = evs[i];
        float2 w; w.x = e * v.x; w.y = e * v.y;
        *(float2*)&T1[i * LDSD + 2 * jp] = w;
    }
    __syncthreads();
    mm_tn<64>(Vt, T1, S1, tid);
    __syncthreads();
    g2l<64>(sqrtm + c * 1024, Vt, tid);
    __syncthreads();
    mm_nn<64>(Vt, S1, T1, tid); __syncthreads();
    mm_nn<64>(T1, Vt, X1, tid); __syncthreads();
    float loc = 0.f;
    for (int idx = tid; idx < 1024; idx += 64) {
        int i = idx >> 5, j = idx & 31;
        float d = X1[i * LDSD + j] - bary0[c * 1024 + idx];
        loc += d * d;
    }
#pragma unroll
    for (int off = 32; off > 0; off >>= 1) loc += __shfl_down(loc, off);
    float err2 = __shfl(loc, 0);
    bool keep0 = (err2 < 1e-8f);  // CONV_TOL^2
    for (int idx = tid; idx < 1024; idx += 64) {
        int i = idx >> 5, j = idx & 31;
        bary[c * 1024 + idx] = keep0 ? bary0[c * 1024 + idx] : X1[i * LDSD + j];
    }
}

__global__ void __launch_bounds__(64) k_cholinv(const float* X, float* WtBuf) {
    __shared__ __align__(16) float A[MAT], W[MAT];
    int b = blockIdx.x, tid = threadIdx.x;
    g2l<64>(X + b * 1024, A, tid);
    __syncthreads();
    if (tid < 32) A[tid * LDSD + tid] += 1e-3f;  // CHOL_EPS
    __syncthreads();
    for (int k = 0; k < 32; ++k) {
        if (tid == 0) A[k * LDSD + k] = sqrtf(A[k * LDSD + k]);
        __syncthreads();
        float invd = 1.f / A[k * LDSD + k];
        if (tid > k && tid < 32) A[tid * LDSD + k] *= invd;
        __syncthreads();
        for (int idx = tid; idx < 1024; idx += 64) {
            int i = idx >> 5, j = idx & 31;
            if (i > k && j > k && j <= i) A[i * LDSD + j] -= A[i * LDSD + k] * A[j * LDSD + k];
        }
        __syncthreads();
    }
    if (tid < 32) {
        int j = tid;
        W[j * LDSD + j] = 1.f / A[j * LDSD + j];
        for (int i = j + 1; i < 32; ++i) {
            float acc = 0.f;
            for (int k2 = j; k2 < i; ++k2) acc += A[i * LDSD + k2] * W[k2 * LDSD + j];
            W[i * LDSD + j] = -acc / A[i * LDSD + i];
        }
        for (int i = 0; i < j; ++i) W[i * LDSD + j] = 0.f;
    }
    __syncthreads();
    // store Wt = W^T = L^{-T} (row-major, stride 32)
    for (int idx = tid; idx < 1024; idx += 64) {
        int i = idx >> 5, j = idx & 31;
        WtBuf[b * 1024 + idx] = W[j * LDSD + i];
    }
}

// ---------- pairdist: register-resident XOR-ordered Jacobi ----------
// One wave per block; lanes 0-31 and 32-63 each solve one 32x32 eigenproblem.
// XOR-skew layout: lane lh holds column lh as m_[r] = M[r ^ lh][lh]:
//   diag at m_[0], off-diag for pair (l, l^mm) at m_[mm]  (compile-time indices).
__global__ void __launch_bounds__(64) k_pairdist(const float* WtBuf, const float* bary, float* D) {
    __shared__ __align__(16) float Wl[MAT], Bc[MAT], T1[MAT];
    int bid = blockIdx.x;
    int b = bid >> 2, cp = bid & 3;
    int tid = threadIdx.x, half = tid >> 5, lh = tid & 31;
    g2l<64>(WtBuf + b * 1024, Wl, tid);
    __syncthreads();
    float m_[32];
    for (int h = 0; h < 2; ++h) {
        g2l<64>(bary + (2 * cp + h) * 1024, Bc, tid);
        __syncthreads();
        // faithful quirk: M = L^{-T} bary L^{-T}
        mm_nn<64>(Wl, Bc, T1, tid); __syncthreads();
        mm_nn<64>(T1, Wl, Bc, tid); __syncthreads();   // M -> Bc
        if (half == h) {
#pragma unroll
            for (int r = 0; r < 32; ++r) {
                int i = r ^ lh;
                // eigvalsh(UPLO='L'): take the lower-triangle element
                int hi = i > lh ? i : lh, lo = i > lh ? lh : i;
                m_[r] = Bc[hi * LDSD + lo];
            }
        }
        __syncthreads();
    }
    float fro2 = 0.f;
#pragma unroll
    for (int r = 0; r < 32; ++r) fro2 += m_[r] * m_[r];
#pragma unroll
    for (int off = 16; off > 0; off >>= 1) fro2 += __shfl_xor(fro2, off, 32);
    float tol2 = fro2 * 1e-9f + 1e-30f;

    for (int sweep = 0; sweep < 8; ++sweep) {
#pragma unroll
        for (int mm = 1; mm < 32; ++mm) {
            float app = m_[0];
            float aqq = __shfl_xor(app, mm, 32);
            float apq = m_[mm];
            float apqc = __builtin_copysignf(fmaxf(fabsf(apq), 1e-36f), apq);
            float tau = (aqq - app) * 0.5f * fast_rcp(apqc);
            float den = fabsf(tau) + sqrtf(fmaf(tau, tau, 1.f));
            float t = __builtin_copysignf(fast_rcp(den), tau);
            float cc = fast_rsq(fmaf(t, t, 1.f));
            float ss = t * cc;
            bool rot = fabsf(apq) > 1e-36f;
            cc = rot ? cc : 1.f;
            ss = rot ? ss : 0.f;
            // row rotations: in-lane register pairs (r, r^mm); params of row i=r^lh
            // fetched from lane i (its s sign is exactly the one row i needs).
#pragma unroll
            for (int r = 0; r < 32; ++r) {
                if (r < (r ^ mm)) {
                    const int r2 = r ^ mm;
                    float ci = __shfl(cc, r ^ lh, 32);
                    float si = __shfl(ss, r ^ lh, 32);
                    float x = m_[r], y = m_[r2];
                    m_[r]  = ci * x - si * y;
                    m_[r2] = ci * y + si * x;
                }
            }
            // column rotations: exchange with partner column via shfl_xor; fetch
            // both values before writing (lockstep => no hazard within the pair).
#pragma unroll
            for (int r = 0; r < 32; ++r) {
                if (r < (r ^ mm)) {
                    const int r2 = r ^ mm;
                    float o1 = __shfl_xor(m_[r2], mm, 32);
                    float o2 = __shfl_xor(m_[r], mm, 32);
                    m_[r]  = cc * m_[r]  - ss * o1;
                    m_[r2] = cc * m_[r2] - ss * o2;
                }
            }
        }
        float off2 = 0.f;
#pragma unroll
        for (int r = 1; r < 32; ++r) off2 += m_[r] * m_[r];
#pragma unroll
        for (int off = 16; off > 0; off >>= 1) off2 += __shfl_xor(off2, off, 32);
        if (__all(off2 <= tol2)) break;
    }
    float lg = logf(fmaxf(m_[0], EV_EPS));
    float d2 = lg * lg;
#pragma unroll
    for (int off = 16; off > 0; off >>= 1) d2 += __shfl_xor(d2, off, 32);
    if (lh == 0) D[b * NC + 2 * cp + half] = sqrtf(d2);
}

__global__ void k_loss(const float* out, const int* labels, const float* D, int B, float* res) {
    __shared__ float sI[256], sD[256], sC[256];
    int tid = threadIdx.x;
    float aI = 0.f, aD = 0.f, aC = 0.f;
    for (int b = tid; b < B; b += 256) {
        int lb = labels[b];
        const float* ob = out + b * NC;
        float m = ob[0];
#pragma unroll
        for (int j = 1; j < NC; ++j) m = fmaxf(m, ob[j]);
        float se = 0.f;
#pragma unroll
        for (int j = 0; j < NC; ++j) se += expf(ob[j] - m);
        aC += m + logf(se) - ob[lb];
        const float* db = D + b * NC;
        float s = 0.f;
#pragma unroll
        for (int j = 0; j < NC; ++j) s += db[j];
        aI += db[lb];
        aD += s - db[lb];
    }
    sI[tid] = aI; sD[tid] = aD; sC[tid] = aC;
    __syncthreads();
    for (int off = 128; off > 0; off >>= 1) {
        if (tid < off) { sI[tid] += sI[tid + off]; sD[tid] += sD[tid + off]; sC[tid] += sC[tid + off]; }
        __syncthreads();
    }
    if (tid == 0) {
        float intra = 0.001f * sI[0] / (float)B;
        float disp = sD[0] / (float)(B * (NC - 1));
        float ce = sC[0] / (float)B;
        res[0] = intra - 0.001f * disp + ce;
    }
}

extern "C" void kernel_launch(void* const* d_in, const int* in_sizes, int n_in,
                              void* d_out, int out_size, void* d_ws, size_t ws_size,
                              hipStream_t stream) {
    const float* X = (const float*)d_in[0];
    const float* out = (const float*)d_in[1];
    const int* labels = (const int*)d_in[2];
    int B = in_sizes[2];

    float* ws = (float*)d_ws;
    float* bary0    = ws;                 // 8192
    float* sqrtm    = ws + 8192;          // 8192
    float* invsqrtm = ws + 16384;         // 8192
    float* meanT    = ws + 24576;         // 8192
    float* bary     = ws + 32768;         // 8192
    float* D        = ws + 40960;         // B*8 = 16384
    int*   counts   = (int*)(ws + 57344); // 8
    float* big      = ws + 65536;         // B*1024 = 2M floats (T, then Wt = L^-T)

    k_count<<<1, 64, 0, stream>>>(labels, B, counts);
    k_bary0<<<NC, 256, 0, stream>>>(X, labels, counts, B, bary0);
    k_eig_bary0<<<NC, 64, 0, stream>>>(bary0, sqrtm, invsqrtm);
    k_tangent<<<B, 128, 0, stream>>>(X, labels, sqrtm, invsqrtm, big);
    k_meanT<<<NC, 256, 0, stream>>>(big, labels, counts, B, meanT);
    k_update<<<NC, 64, 0, stream>>>(meanT, sqrtm, invsqrtm, bary0, bary);
    k_cholinv<<<B, 64, 0, stream>>>(X, big);
    k_pairdist<<<B * 4, 64, 0, stream>>>(big, bary, D);
    k_loss<<<1, 256, 0, stream>>>(out, labels, D, B, (float*)d_out);
}

// Round 4
// 2222.140 us; speedup vs baseline: 2.0293x; 1.1235x over previous
//
#include <hip/hip_runtime.h>
#include <math.h>

#define NC 8
#define NDIM 32
#define LDSD 34            // stride 34: rows 8B-aligned (float2)
#define MAT (NDIM * LDSD)  // 1088 floats per LDS matrix
#define EV_EPS 1e-10f
#define NPART 32

#if __has_builtin(__builtin_amdgcn_rcpf)
__device__ inline float fast_rcp(float x) { return __builtin_amdgcn_rcpf(x); }
#else
__device__ inline float fast_rcp(float x) { return 1.f / x; }
#endif
#if __has_builtin(__builtin_amdgcn_rsqf)
__device__ inline float fast_rsq(float x) { return __builtin_amdgcn_rsqf(x); }
#else
__device__ inline float fast_rsq(float x) { return 1.f / sqrtf(x); }
#endif

// ---------- round-robin tournament pairing (for the 8-block LDS-Jacobi kernels) ----------
__device__ inline void rr_pair(int r, int k, int& p, int& q) {
    int a, b;
    if (k == 0) { a = 31; b = r; }
    else { a = (r + k) % 31; b = (r - k + 62) % 31; }
    p = a < b ? a : b;
    q = a < b ? b : a;
}

template <int NT>
__device__ inline void build_pq(ushort* pq, int tid) {
    for (int e = tid; e < 496; e += NT) {
        int r = e >> 4, kk = e & 15;
        int p, q; rr_pair(r, kk, p, q);
        pq[e] = (ushort)(p | (q << 8));
    }
}

template <int NT>
__device__ inline float bsum(float v, float* scratch, int tid) {
#pragma unroll
    for (int off = 32; off > 0; off >>= 1) v += __shfl_down(v, off);
    if constexpr (NT == 64) {
        return __shfl(v, 0);
    } else {
        if ((tid & 63) == 0) scratch[tid >> 6] = v;
        __syncthreads();
        float r = scratch[0] + scratch[1];
        __syncthreads();
        return r;
    }
}

// ---------- 32x32 LDS helpers ----------
template <int NT>
__device__ inline void g2l(const float* g, float* l, int tid) {
    for (int idx2 = tid; idx2 < 512; idx2 += NT) {
        int i = idx2 >> 4, jp = idx2 & 15;
        *(float2*)&l[i * LDSD + 2 * jp] = *(const float2*)&g[i * 32 + 2 * jp];
    }
}
// C = A * B
template <int NT>
__device__ inline void mm_nn(const float* A, const float* B, float* C, int tid) {
    for (int idx2 = tid; idx2 < 512; idx2 += NT) {
        int i = idx2 >> 4, jp = idx2 & 15;
        const float* Ar = A + i * LDSD;
        const float* Bp = B + 2 * jp;
        float2 acc; acc.x = 0.f; acc.y = 0.f;
#pragma unroll
        for (int k = 0; k < 32; ++k) {
            float a = Ar[k];
            float2 b = *(const float2*)(Bp + k * LDSD);
            acc.x = fmaf(a, b.x, acc.x); acc.y = fmaf(a, b.y, acc.y);
        }
        *(float2*)&C[i * LDSD + 2 * jp] = acc;
    }
}
// C(global, stride 32) = A * B
template <int NT>
__device__ inline void mm_nn_g(const float* A, const float* B, float* gC, int tid) {
    for (int idx2 = tid; idx2 < 512; idx2 += NT) {
        int i = idx2 >> 4, jp = idx2 & 15;
        const float* Ar = A + i * LDSD;
        const float* Bp = B + 2 * jp;
        float2 acc; acc.x = 0.f; acc.y = 0.f;
#pragma unroll
        for (int k = 0; k < 32; ++k) {
            float a = Ar[k];
            float2 b = *(const float2*)(Bp + k * LDSD);
            acc.x = fmaf(a, b.x, acc.x); acc.y = fmaf(a, b.y, acc.y);
        }
        *(float2*)&gC[i * 32 + 2 * jp] = acc;
    }
}
// C = A^T * B
template <int NT>
__device__ inline void mm_tn(const float* A, const float* B, float* C, int tid) {
    for (int idx2 = tid; idx2 < 512; idx2 += NT) {
        int i = idx2 >> 4, jp = idx2 & 15;
        float2 acc; acc.x = 0.f; acc.y = 0.f;
#pragma unroll
        for (int k = 0; k < 32; ++k) {
            float a = A[k * LDSD + i];
            float2 b = *(const float2*)&B[k * LDSD + 2 * jp];
            acc.x = fmaf(a, b.x, acc.x); acc.y = fmaf(a, b.y, acc.y);
        }
        *(float2*)&C[i * LDSD + 2 * jp] = acc;
    }
}
// C(global) = A^T * B
template <int NT>
__device__ inline void mm_tn_g(const float* A, const float* B, float* gC, int tid) {
    for (int idx2 = tid; idx2 < 512; idx2 += NT) {
        int i = idx2 >> 4, jp = idx2 & 15;
        float2 acc; acc.x = 0.f; acc.y = 0.f;
#pragma unroll
        for (int k = 0; k < 32; ++k) {
            float a = A[k * LDSD + i];
            float2 b = *(const float2*)&B[k * LDSD + 2 * jp];
            acc.x = fmaf(a, b.x, acc.x); acc.y = fmaf(a, b.y, acc.y);
        }
        *(float2*)&gC[i * 32 + 2 * jp] = acc;
    }
}

// ---------- register-resident XOR-ordered Jacobi (one 32x32 problem per 32-lane half) ----------
// XOR-skew: lane lh holds column lh as m_[r] = M[r ^ lh][lh]; diag = m_[0],
// off-diag of pair (l, l^mm) = m_[mm]. All register indices compile-time.
// If WANT_V: v_ accumulates eigenvector columns in the same skew (V[i][l] = v_[i^l]).
template <bool WANT_V>
__device__ inline void rjacobi(float* m_, float* v_, int max_sweeps) {
    if (WANT_V) {
#pragma unroll
        for (int r = 0; r < 32; ++r) v_[r] = (r == 0) ? 1.f : 0.f;
    }
    float fro2 = 0.f;
#pragma unroll
    for (int r = 0; r < 32; ++r) fro2 += m_[r] * m_[r];
#pragma unroll
    for (int off = 16; off > 0; off >>= 1) fro2 += __shfl_xor(fro2, off, 32);
    float tol2 = fro2 * 1e-9f + 1e-30f;

    for (int sweep = 0; sweep < max_sweeps; ++sweep) {
#pragma unroll
        for (int mm = 1; mm < 32; ++mm) {
            float app = m_[0];
            float aqq = __shfl_xor(app, mm, 32);
            float apq = m_[mm];
            float apqc = __builtin_copysignf(fmaxf(fabsf(apq), 1e-36f), apq);
            float tau = (aqq - app) * 0.5f * fast_rcp(apqc);
            float den = fabsf(tau) + sqrtf(fmaf(tau, tau, 1.f));
            float t = __builtin_copysignf(fast_rcp(den), tau);
            float cc = fast_rsq(fmaf(t, t, 1.f));
            float ss = t * cc;
            bool rot = fabsf(apq) > 1e-36f;
            cc = rot ? cc : 1.f;
            ss = rot ? ss : 0.f;
            // row rotations: params of row i=r^lh live in lane lh^r -> constant-mask shfl_xor
#pragma unroll
            for (int r = 0; r < 32; ++r) {
                if (r < (r ^ mm)) {
                    const int r2 = r ^ mm;
                    float ci = __shfl_xor(cc, r, 32);
                    float si = __shfl_xor(ss, r, 32);
                    float x = m_[r], y = m_[r2];
                    m_[r]  = ci * x - si * y;
                    m_[r2] = ci * y + si * x;
                }
            }
            // column rotations: exchange with partner column (lockstep, no hazard)
#pragma unroll
            for (int r = 0; r < 32; ++r) {
                if (r < (r ^ mm)) {
                    const int r2 = r ^ mm;
                    float o1 = __shfl_xor(m_[r2], mm, 32);
                    float o2 = __shfl_xor(m_[r], mm, 32);
                    m_[r]  = cc * m_[r]  - ss * o1;
                    m_[r2] = cc * m_[r2] - ss * o2;
                }
            }
            if (WANT_V) {
#pragma unroll
                for (int r = 0; r < 32; ++r) {
                    if (r < (r ^ mm)) {
                        const int r2 = r ^ mm;
                        float o1 = __shfl_xor(v_[r2], mm, 32);
                        float o2 = __shfl_xor(v_[r], mm, 32);
                        v_[r]  = cc * v_[r]  - ss * o1;
                        v_[r2] = cc * v_[r2] - ss * o2;
                    }
                }
            }
        }
        float off2 = 0.f;
#pragma unroll
        for (int r = 1; r < 32; ++r) off2 += m_[r] * m_[r];
#pragma unroll
        for (int off = 16; off > 0; off >>= 1) off2 += __shfl_xor(off2, off, 32);
        if (__all(off2 <= tol2)) break;
    }
}

// ---------- LDS parallel Jacobi (8-block kernels only) ----------
template <int NT, bool WANT_V>
__device__ void jacobi32(float* A, float* Vt, float* csn, const ushort* pq, int tid, int max_sweeps) {
    if (WANT_V) {
        for (int idx = tid; idx < 1024; idx += NT) {
            int i = idx >> 5, j = idx & 31;
            Vt[i * LDSD + j] = (i == j) ? 1.f : 0.f;
        }
    }
    float loc = 0.f;
    for (int idx2 = tid; idx2 < 512; idx2 += NT) {
        int i = idx2 >> 4, jp = idx2 & 15;
        float2 v = *(const float2*)&A[i * LDSD + 2 * jp];
        loc += v.x * v.x + v.y * v.y;
    }
    float fro2 = bsum<NT>(loc, csn + 32, tid);
    float tol2 = fro2 * 1e-9f + 1e-30f;
    __syncthreads();

    for (int sweep = 0; sweep < max_sweeps; ++sweep) {
        for (int r = 0; r < 31; ++r) {
            const ushort* pqr = pq + (r << 4);
            if (tid < 16) {
                int e = pqr[tid], p = e & 31, q = e >> 8;
                float apq = A[p * LDSD + q];
                float c = 1.f, s = 0.f;
                if (fabsf(apq) > 1e-36f) {
                    float app = A[p * LDSD + p], aqq = A[q * LDSD + q];
                    float tau = (aqq - app) / (2.f * apq);
                    float t = (tau >= 0.f ? 1.f : -1.f) / (fabsf(tau) + sqrtf(1.f + tau * tau));
                    c = 1.f / sqrtf(1.f + t * t);
                    s = t * c;
                }
                csn[tid] = c; csn[16 + tid] = s;
            }
            __syncthreads();
            for (int item = tid; item < 256; item += NT) {
                int k = item >> 4, g = item & 15;
                int e = pqr[k], p = e & 31, q = e >> 8;
                float c = csn[k], s = csn[16 + k];
                float2 ap = *(float2*)&A[p * LDSD + 2 * g];
                float2 aq = *(float2*)&A[q * LDSD + 2 * g];
                float2 np, nq;
                np.x = c * ap.x - s * aq.x; np.y = c * ap.y - s * aq.y;
                nq.x = s * ap.x + c * aq.x; nq.y = s * ap.y + c * aq.y;
                *(float2*)&A[p * LDSD + 2 * g] = np;
                *(float2*)&A[q * LDSD + 2 * g] = nq;
            }
            __syncthreads();
            for (int item = tid; item < 512; item += NT) {
                int k = item >> 5, i = item & 31;
                int e = pqr[k], p = e & 31, q = e >> 8;
                float c = csn[k], s = csn[16 + k];
                float ap = A[i * LDSD + p], aq = A[i * LDSD + q];
                A[i * LDSD + p] = c * ap - s * aq;
                A[i * LDSD + q] = s * ap + c * aq;
            }
            if (WANT_V) {
                for (int item = tid; item < 256; item += NT) {
                    int k = item >> 4, g = item & 15;
                    int e = pqr[k], p = e & 31, q = e >> 8;
                    float c = csn[k], s = csn[16 + k];
                    float2 vp = *(float2*)&Vt[p * LDSD + 2 * g];
                    float2 vq = *(float2*)&Vt[q * LDSD + 2 * g];
                    float2 np, nq;
                    np.x = c * vp.x - s * vq.x; np.y = c * vp.y - s * vq.y;
                    nq.x = s * vp.x + c * vq.x; nq.y = s * vp.y + c * vq.y;
                    *(float2*)&Vt[p * LDSD + 2 * g] = np;
                    *(float2*)&Vt[q * LDSD + 2 * g] = nq;
                }
            }
            __syncthreads();
        }
        float l2 = 0.f;
        for (int idx2 = tid; idx2 < 512; idx2 += NT) {
            int i = idx2 >> 4, jp = idx2 & 15;
            float2 v = *(const float2*)&A[i * LDSD + 2 * jp];
            if ((i >> 1) == jp) { if (i & 1) v.y = 0.f; else v.x = 0.f; }
            l2 += v.x * v.x + v.y * v.y;
        }
        l2 = bsum<NT>(l2, csn + 32, tid);
        if (l2 <= tol2) break;
    }
    __syncthreads();
}

// ---------- kernels ----------
__global__ void k_count(const int* labels, int B, int* counts) {
    int tid = threadIdx.x;
    if (tid < NC) {
        int cnt = 0;
        for (int b = 0; b < B; ++b) cnt += (labels[b] == tid);
        counts[tid] = cnt;
    }
}

// stage 1: per-chunk per-class partial sums; labels are wave-uniform per sample
__global__ void __launch_bounds__(256) k_accum_part(const float* src, const int* labels, int B, float* part) {
    int blk = blockIdx.x, tid = threadIdx.x;
    int chunk = (B + NPART - 1) / NPART;
    int b0 = blk * chunk, b1 = b0 + chunk < B ? b0 + chunk : B;
    float acc[NC][4];
#pragma unroll
    for (int c = 0; c < NC; ++c)
#pragma unroll
        for (int e = 0; e < 4; ++e) acc[c][e] = 0.f;
    for (int b = b0; b < b1; ++b) {
        int lb = labels[b];  // uniform -> scalar branch
        float x[4];
#pragma unroll
        for (int e = 0; e < 4; ++e) x[e] = src[b * 1024 + tid + 256 * e];
#pragma unroll
        for (int c = 0; c < NC; ++c) {
            if (lb == c) {
#pragma unroll
                for (int e = 0; e < 4; ++e) acc[c][e] += x[e];
            }
        }
    }
#pragma unroll
    for (int c = 0; c < NC; ++c)
#pragma unroll
        for (int e = 0; e < 4; ++e) part[(blk * NC + c) * 1024 + tid + 256 * e] = acc[c][e];
}

// stage 2: reduce NPART partials, divide by count
__global__ void __launch_bounds__(256) k_accum_fin(const float* part, const int* counts, float* dst) {
    int c = blockIdx.x, tid = threadIdx.x;
    float acc[4] = {0.f, 0.f, 0.f, 0.f};
    for (int k = 0; k < NPART; ++k) {
#pragma unroll
        for (int e = 0; e < 4; ++e) acc[e] += part[(k * NC + c) * 1024 + tid + 256 * e];
    }
    float inv = 1.f / (float)counts[c];
#pragma unroll
    for (int e = 0; e < 4; ++e) dst[c * 1024 + tid + 256 * e] = acc[e] * inv;
}

__global__ void __launch_bounds__(64) k_eig_bary0(const float* bary0, float* sqrtm, float* invsqrtm) {
    __shared__ __align__(16) float A[MAT], Vt[MAT], T1[MAT];
    __shared__ float csn[36], evs[32];
    __shared__ ushort pq[496];
    int c = blockIdx.x, tid = threadIdx.x;
    build_pq<64>(pq, tid);
    g2l<64>(bary0 + c * 1024, A, tid);
    __syncthreads();
    jacobi32<64, true>(A, Vt, csn, pq, tid, 8);
    if (tid < 32) evs[tid] = sqrtf(fmaxf(A[tid * LDSD + tid], 0.f));
    __syncthreads();
    for (int idx2 = tid; idx2 < 512; idx2 += 64) {
        int i = idx2 >> 4, jp = idx2 & 15;
        float2 v = *(const float2*)&Vt[i * LDSD + 2 * jp];
        float e = evs[i];
        float2 w; w.x = e * v.x; w.y = e * v.y;
        *(float2*)&T1[i * LDSD + 2 * jp] = w;
    }
    __syncthreads();
    mm_tn_g<64>(Vt, T1, sqrtm + c * 1024, tid);
    if (tid < 32) evs[tid] = 1.f / sqrtf(fmaxf(A[tid * LDSD + tid], 1e-30f));
    __syncthreads();
    for (int idx2 = tid; idx2 < 512; idx2 += 64) {
        int i = idx2 >> 4, jp = idx2 & 15;
        float2 v = *(const float2*)&Vt[i * LDSD + 2 * jp];
        float e = evs[i];
        float2 w; w.x = e * v.x; w.y = e * v.y;
        *(float2*)&T1[i * LDSD + 2 * jp] = w;
    }
    __syncthreads();
    mm_tn_g<64>(Vt, T1, invsqrtm + c * 1024, tid);
}

// tangent vectors via register Jacobi (both halves duplicate the solve)
__global__ void __launch_bounds__(64) k_tangent(const float* X, const int* labels, const float* sqrtm,
                                                const float* invsqrtm, float* Tbuf) {
    __shared__ __align__(16) float P[MAT], Q[MAT], R[MAT];
    __shared__ float evs[32];
    int b = blockIdx.x, tid = threadIdx.x, lh = tid & 31;
    int lb = labels[b];
    g2l<64>(X + b * 1024, P, tid);
    g2l<64>(invsqrtm + lb * 1024, Q, tid);
    __syncthreads();
    mm_nn<64>(Q, P, R, tid); __syncthreads();   // R = S·X
    mm_nn<64>(R, Q, P, tid); __syncthreads();   // P = S·X·S = M
    // extract with symmetrization (eigh symmetrize_input): m_[r] = (M+M^T)/2 at (r^lh, lh)
    float m_[32], v_[32];
#pragma unroll
    for (int r = 0; r < 32; ++r) {
        int i = r ^ lh;
        m_[r] = 0.5f * (P[i * LDSD + lh] + P[lh * LDSD + i]);
    }
    rjacobi<true>(m_, v_, 8);
    // lane l: eigenvalue m_[0], eigenvector col l in v_ (V[i][l] = v_[i^l])
    if (tid < 32) {
        evs[lh] = logf(fmaxf(m_[0], EV_EPS));
#pragma unroll
        for (int r = 0; r < 32; ++r) R[(r ^ lh) * LDSD + lh] = v_[r];  // R = V (normal layout)
    }
    g2l<64>(sqrtm + lb * 1024, Q, tid);         // Q = sqrtm
    __syncthreads();
    mm_tn<64>(R, Q, P, tid); __syncthreads();   // P = Ut = V^T·sqrtm  (sqrtm symmetric)
    // R = diag(evs)·Ut  (row scale)
    for (int idx2 = tid; idx2 < 512; idx2 += 64) {
        int i = idx2 >> 4, jp = idx2 & 15;
        float2 u = *(const float2*)&P[i * LDSD + 2 * jp];
        float e = evs[i];
        float2 w; w.x = e * u.x; w.y = e * u.y;
        *(float2*)&R[i * LDSD + 2 * jp] = w;
    }
    __syncthreads();
    mm_tn_g<64>(R, P, Tbuf + b * 1024, tid);    // T = Ut^T·diag·Ut = sqrtm·logM·sqrtm
}

__global__ void __launch_bounds__(64) k_update(const float* meanT, const float* sqrtm, const float* invsqrtm,
                                               const float* bary0, float* bary) {
    __shared__ __align__(16) float X1[MAT], S1[MAT], T1[MAT], Vt[MAT];
    __shared__ float csn[36], evs[32];
    __shared__ ushort pq[496];
    int c = blockIdx.x, tid = threadIdx.x;
    build_pq<64>(pq, tid);
    g2l<64>(meanT + c * 1024, X1, tid);
    g2l<64>(invsqrtm + c * 1024, S1, tid);
    __syncthreads();
    mm_nn<64>(S1, X1, T1, tid); __syncthreads();
    mm_nn<64>(T1, S1, X1, tid); __syncthreads();
    jacobi32<64, true>(X1, Vt, csn, pq, tid, 8);
    // faithful quirk: clamp eigenvalues to >= 1e-10 BEFORE exp
    if (tid < 32) evs[tid] = expf(fmaxf(X1[tid * LDSD + tid], EV_EPS));
    __syncthreads();
    for (int idx2 = tid; idx2 < 512; idx2 += 64) {
        int i = idx2 >> 4, jp = idx2 & 15;
        float2 v = *(const float2*)&Vt[i * LDSD + 2 * jp];
        float e = evs[i];
        float2 w; w.x = e * v.x; w.y = e * v.y;
        *(float2*)&T1[i * LDSD + 2 * jp] = w;
    }
    __syncthreads();
    mm_tn<64>(Vt, T1, S1, tid);
    __syncthreads();
    g2l<64>(sqrtm + c * 1024, Vt, tid);
    __syncthreads();
    mm_nn<64>(Vt, S1, T1, tid); __syncthreads();
    mm_nn<64>(T1, Vt, X1, tid); __syncthreads();
    float loc = 0.f;
    for (int idx = tid; idx < 1024; idx += 64) {
        int i = idx >> 5, j = idx & 31;
        float d = X1[i * LDSD + j] - bary0[c * 1024 + idx];
        loc += d * d;
    }
#pragma unroll
    for (int off = 32; off > 0; off >>= 1) loc += __shfl_down(loc, off);
    float err2 = __shfl(loc, 0);
    bool keep0 = (err2 < 1e-8f);  // CONV_TOL^2
    for (int idx = tid; idx < 1024; idx += 64) {
        int i = idx >> 5, j = idx & 31;
        bary[c * 1024 + idx] = keep0 ? bary0[c * 1024 + idx] : X1[i * LDSD + j];
    }
}

__global__ void __launch_bounds__(64) k_cholinv(const float* X, float* WtBuf) {
    __shared__ __align__(16) float A[MAT], W[MAT];
    int b = blockIdx.x, tid = threadIdx.x;
    g2l<64>(X + b * 1024, A, tid);
    __syncthreads();
    if (tid < 32) A[tid * LDSD + tid] += 1e-3f;  // CHOL_EPS
    __syncthreads();
    for (int k = 0; k < 32; ++k) {
        if (tid == 0) A[k * LDSD + k] = sqrtf(A[k * LDSD + k]);
        __syncthreads();
        float invd = 1.f / A[k * LDSD + k];
        if (tid > k && tid < 32) A[tid * LDSD + k] *= invd;
        __syncthreads();
        for (int idx = tid; idx < 1024; idx += 64) {
            int i = idx >> 5, j = idx & 31;
            if (i > k && j > k && j <= i) A[i * LDSD + j] -= A[i * LDSD + k] * A[j * LDSD + k];
        }
        __syncthreads();
    }
    if (tid < 32) {
        int j = tid;
        W[j * LDSD + j] = 1.f / A[j * LDSD + j];
        for (int i = j + 1; i < 32; ++i) {
            float acc = 0.f;
            for (int k2 = j; k2 < i; ++k2) acc += A[i * LDSD + k2] * W[k2 * LDSD + j];
            W[i * LDSD + j] = -acc / A[i * LDSD + i];
        }
        for (int i = 0; i < j; ++i) W[i * LDSD + j] = 0.f;
    }
    __syncthreads();
    for (int idx = tid; idx < 1024; idx += 64) {
        int i = idx >> 5, j = idx & 31;
        WtBuf[b * 1024 + idx] = W[j * LDSD + i];  // store L^{-T}
    }
}

__global__ void __launch_bounds__(64) k_pairdist(const float* WtBuf, const float* bary, float* D) {
    __shared__ __align__(16) float Wl[MAT], Bc[MAT], T1[MAT];
    int bid = blockIdx.x;
    int b = bid >> 2, cp = bid & 3;
    int tid = threadIdx.x, half = tid >> 5, lh = tid & 31;
    g2l<64>(WtBuf + b * 1024, Wl, tid);
    __syncthreads();
    float m_[32];
    for (int h = 0; h < 2; ++h) {
        g2l<64>(bary + (2 * cp + h) * 1024, Bc, tid);
        __syncthreads();
        // faithful quirk: M = L^{-T} bary L^{-T}
        mm_nn<64>(Wl, Bc, T1, tid); __syncthreads();
        mm_nn<64>(T1, Wl, Bc, tid); __syncthreads();
        if (half == h) {
#pragma unroll
            for (int r = 0; r < 32; ++r) {
                int i = r ^ lh;
                // eigvalsh(UPLO='L'): lower-triangle element
                int hi = i > lh ? i : lh, lo = i > lh ? lh : i;
                m_[r] = Bc[hi * LDSD + lo];
            }
        }
        __syncthreads();
    }
    rjacobi<false>(m_, nullptr, 8);
    float lg = logf(fmaxf(m_[0], EV_EPS));
    float d2 = lg * lg;
#pragma unroll
    for (int off = 16; off > 0; off >>= 1) d2 += __shfl_xor(d2, off, 32);
    if (lh == 0) D[b * NC + 2 * cp + half] = sqrtf(d2);
}

__global__ void k_loss(const float* out, const int* labels, const float* D, int B, float* res) {
    __shared__ float sI[256], sD[256], sC[256];
    int tid = threadIdx.x;
    float aI = 0.f, aD = 0.f, aC = 0.f;
    for (int b = tid; b < B; b += 256) {
        int lb = labels[b];
        const float* ob = out + b * NC;
        float m = ob[0];
#pragma unroll
        for (int j = 1; j < NC; ++j) m = fmaxf(m, ob[j]);
        float se = 0.f;
#pragma unroll
        for (int j = 0; j < NC; ++j) se += expf(ob[j] - m);
        aC += m + logf(se) - ob[lb];
        const float* db = D + b * NC;
        float s = 0.f;
#pragma unroll
        for (int j = 0; j < NC; ++j) s += db[j];
        aI += db[lb];
        aD += s - db[lb];
    }
    sI[tid] = aI; sD[tid] = aD; sC[tid] = aC;
    __syncthreads();
    for (int off = 128; off > 0; off >>= 1) {
        if (tid < off) { sI[tid] += sI[tid + off]; sD[tid] += sD[tid + off]; sC[tid] += sC[tid + off]; }
        __syncthreads();
    }
    if (tid == 0) {
        float intra = 0.001f * sI[0] / (float)B;
        float disp = sD[0] / (float)(B * (NC - 1));
        float ce = sC[0] / (float)B;
        res[0] = intra - 0.001f * disp + ce;
    }
}

extern "C" void kernel_launch(void* const* d_in, const int* in_sizes, int n_in,
                              void* d_out, int out_size, void* d_ws, size_t ws_size,
                              hipStream_t stream) {
    const float* X = (const float*)d_in[0];
    const float* out = (const float*)d_in[1];
    const int* labels = (const int*)d_in[2];
    int B = in_sizes[2];

    float* ws = (float*)d_ws;
    float* bary0    = ws;                 // 8192
    float* sqrtm    = ws + 8192;          // 8192
    float* invsqrtm = ws + 16384;         // 8192
    float* meanT    = ws + 24576;         // 8192
    float* bary     = ws + 32768;         // 8192
    float* D        = ws + 40960;         // B*8 = 16384
    int*   counts   = (int*)(ws + 57344); // 8
    float* big      = ws + 65536;         // B*1024 = 2M floats (partialsA, then T, then Wt)
    float* part2    = ws + 65536 + (size_t)B * 1024;  // NPART*NC*1024 = 256K floats

    k_count<<<1, 64, 0, stream>>>(labels, B, counts);
    k_accum_part<<<NPART, 256, 0, stream>>>(X, labels, B, big);     // partials in big (free now)
    k_accum_fin<<<NC, 256, 0, stream>>>(big, counts, bary0);
    k_eig_bary0<<<NC, 64, 0, stream>>>(bary0, sqrtm, invsqrtm);
    k_tangent<<<B, 64, 0, stream>>>(X, labels, sqrtm, invsqrtm, big);
    k_accum_part<<<NPART, 256, 0, stream>>>(big, labels, B, part2);
    k_accum_fin<<<NC, 256, 0, stream>>>(part2, counts, meanT);
    k_update<<<NC, 64, 0, stream>>>(meanT, sqrtm, invsqrtm, bary0, bary);
    k_cholinv<<<B, 64, 0, stream>>>(X, big);
    k_pairdist<<<B * 4, 64, 0, stream>>>(big, bary, D);
    k_loss<<<1, 256, 0, stream>>>(out, labels, D, B, (float*)d_out);
}

// Round 5
// 1858.227 us; speedup vs baseline: 2.4267x; 1.1958x over previous
//
#include <hip/hip_runtime.h>
#include <math.h>

#define NC 8
#define NDIM 32
#define LDSD 34            // stride 34: rows 8B-aligned (float2)
#define MAT (NDIM * LDSD)  // 1088 floats per LDS matrix
#define EV_EPS 1e-10f
#define NPART 32

#if __has_builtin(__builtin_amdgcn_rcpf)
__device__ inline float fast_rcp(float x) { return __builtin_amdgcn_rcpf(x); }
#else
__device__ inline float fast_rcp(float x) { return 1.f / x; }
#endif
#if __has_builtin(__builtin_amdgcn_rsqf)
__device__ inline float fast_rsq(float x) { return __builtin_amdgcn_rsqf(x); }
#else
__device__ inline float fast_rsq(float x) { return 1.f / sqrtf(x); }
#endif

// ---------- round-robin tournament pairing (8-block LDS-Jacobi kernels only) ----------
__device__ inline void rr_pair(int r, int k, int& p, int& q) {
    int a, b;
    if (k == 0) { a = 31; b = r; }
    else { a = (r + k) % 31; b = (r - k + 62) % 31; }
    p = a < b ? a : b;
    q = a < b ? b : a;
}

template <int NT>
__device__ inline void build_pq(ushort* pq, int tid) {
    for (int e = tid; e < 496; e += NT) {
        int r = e >> 4, kk = e & 15;
        int p, q; rr_pair(r, kk, p, q);
        pq[e] = (ushort)(p | (q << 8));
    }
}

template <int NT>
__device__ inline float bsum(float v, float* scratch, int tid) {
#pragma unroll
    for (int off = 32; off > 0; off >>= 1) v += __shfl_down(v, off);
    if constexpr (NT == 64) {
        return __shfl(v, 0);
    } else {
        if ((tid & 63) == 0) scratch[tid >> 6] = v;
        __syncthreads();
        float r = scratch[0] + scratch[1];
        __syncthreads();
        return r;
    }
}

// ---------- 32x32 LDS helpers ----------
template <int NT>
__device__ inline void g2l(const float* g, float* l, int tid) {
    for (int idx2 = tid; idx2 < 512; idx2 += NT) {
        int i = idx2 >> 4, jp = idx2 & 15;
        *(float2*)&l[i * LDSD + 2 * jp] = *(const float2*)&g[i * 32 + 2 * jp];
    }
}

// ---------- register-tiled LDS matmuls (64 threads; 8-row x 2-col tile/thread) ----------
// C = A * B (all LDS)
__device__ inline void mmb_nn(const float* A, const float* B, float* C, int tid) {
    int j2 = (tid & 15) * 2;
    int i0 = (tid >> 4) * 8;
    float a0[2] = {0.f,0.f}, a1[2] = {0.f,0.f}, a2[2] = {0.f,0.f}, a3[2] = {0.f,0.f};
    float a4[2] = {0.f,0.f}, a5[2] = {0.f,0.f}, a6[2] = {0.f,0.f}, a7[2] = {0.f,0.f};
#pragma unroll
    for (int k = 0; k < 32; k += 2) {
        float2 b0 = *(const float2*)&B[k * LDSD + j2];
        float2 b1 = *(const float2*)&B[(k + 1) * LDSD + j2];
#define ROWNN(rr, ac) { float2 a = *(const float2*)&A[(i0 + rr) * LDSD + k]; \
        ac[0] = fmaf(a.x, b0.x, fmaf(a.y, b1.x, ac[0])); \
        ac[1] = fmaf(a.x, b0.y, fmaf(a.y, b1.y, ac[1])); }
        ROWNN(0, a0) ROWNN(1, a1) ROWNN(2, a2) ROWNN(3, a3)
        ROWNN(4, a4) ROWNN(5, a5) ROWNN(6, a6) ROWNN(7, a7)
#undef ROWNN
    }
#define STNN(rr, ac) { float2 w; w.x = ac[0]; w.y = ac[1]; *(float2*)&C[(i0 + rr) * LDSD + j2] = w; }
    STNN(0, a0) STNN(1, a1) STNN(2, a2) STNN(3, a3)
    STNN(4, a4) STNN(5, a5) STNN(6, a6) STNN(7, a7)
#undef STNN
}
// gC(global, stride 32) = A * B^T   (C[i][j] = sum_l A[i][l]*B[j][l])
__device__ inline void mmb_nt_g(const float* A, const float* B, float* gC, int tid) {
    int j2 = (tid & 15) * 2;
    int i0 = (tid >> 4) * 8;
    float a0[2] = {0.f,0.f}, a1[2] = {0.f,0.f}, a2[2] = {0.f,0.f}, a3[2] = {0.f,0.f};
    float a4[2] = {0.f,0.f}, a5[2] = {0.f,0.f}, a6[2] = {0.f,0.f}, a7[2] = {0.f,0.f};
#pragma unroll
    for (int l = 0; l < 32; l += 2) {
        float2 b0 = *(const float2*)&B[j2 * LDSD + l];
        float2 b1 = *(const float2*)&B[(j2 + 1) * LDSD + l];
#define ROWNT(rr, ac) { float2 a = *(const float2*)&A[(i0 + rr) * LDSD + l]; \
        ac[0] = fmaf(a.x, b0.x, fmaf(a.y, b0.y, ac[0])); \
        ac[1] = fmaf(a.x, b1.x, fmaf(a.y, b1.y, ac[1])); }
        ROWNT(0, a0) ROWNT(1, a1) ROWNT(2, a2) ROWNT(3, a3)
        ROWNT(4, a4) ROWNT(5, a5) ROWNT(6, a6) ROWNT(7, a7)
#undef ROWNT
    }
#define STNT(rr, ac) { float2 w; w.x = ac[0]; w.y = ac[1]; *(float2*)&gC[(i0 + rr) * 32 + j2] = w; }
    STNT(0, a0) STNT(1, a1) STNT(2, a2) STNT(3, a3)
    STNT(4, a4) STNT(5, a5) STNT(6, a6) STNT(7, a7)
#undef STNT
}

// ---------- register-resident XOR-ordered Jacobi, eigenvalues only ----------
// Lane lh of each 32-lane half holds column lh skewed: m_[r] = M[r^lh][lh].
__device__ inline void rjacobi_nv(float* m_, float tolmul, int max_sweeps) {
    float fro2 = 0.f;
#pragma unroll
    for (int r = 0; r < 32; ++r) fro2 += m_[r] * m_[r];
#pragma unroll
    for (int off = 16; off > 0; off >>= 1) fro2 += __shfl_xor(fro2, off, 32);
    float tol2 = fro2 * tolmul + 1e-30f;

    for (int sweep = 0; sweep < max_sweeps; ++sweep) {
#pragma unroll
        for (int mm = 1; mm < 32; ++mm) {
            float app = m_[0];
            float aqq = __shfl_xor(app, mm, 32);
            float apq = m_[mm];
            float apqc = __builtin_copysignf(fmaxf(fabsf(apq), 1e-36f), apq);
            float tau = (aqq - app) * 0.5f * fast_rcp(apqc);
            float den = fabsf(tau) + sqrtf(fmaf(tau, tau, 1.f));
            float t = __builtin_copysignf(fast_rcp(den), tau);
            t = (fabsf(apq) > 1e-36f) ? t : 0.f;
            float cc = fast_rsq(fmaf(t, t, 1.f));
            float ss = t * cc;
            // row rotations: refetch t (1 shfl), rebuild c,s on trans pipe
#pragma unroll
            for (int r = 0; r < 32; ++r) {
                if (r < (r ^ mm)) {
                    const int r2 = r ^ mm;
                    float ti = __shfl_xor(t, r, 32);
                    float ci = fast_rsq(fmaf(ti, ti, 1.f));
                    float si = ti * ci;
                    float x = m_[r], y = m_[r2];
                    m_[r]  = ci * x - si * y;
                    m_[r2] = ci * y + si * x;
                }
            }
            // column rotations: exchange partner values
#pragma unroll
            for (int r = 0; r < 32; ++r) {
                if (r < (r ^ mm)) {
                    const int r2 = r ^ mm;
                    float o1 = __shfl_xor(m_[r2], mm, 32);
                    float o2 = __shfl_xor(m_[r], mm, 32);
                    m_[r]  = cc * m_[r]  - ss * o1;
                    m_[r2] = cc * m_[r2] - ss * o2;
                }
            }
        }
        float off2 = 0.f;
#pragma unroll
        for (int r = 1; r < 32; ++r) off2 += m_[r] * m_[r];
#pragma unroll
        for (int off = 16; off > 0; off >>= 1) off2 += __shfl_xor(off2, off, 32);
        if (__all(off2 <= tol2)) break;
    }
}

// ---------- LDS parallel Jacobi (8-block kernels only) ----------
template <int NT, bool WANT_V>
__device__ void jacobi32(float* A, float* Vt, float* csn, const ushort* pq, int tid, int max_sweeps) {
    if (WANT_V) {
        for (int idx = tid; idx < 1024; idx += NT) {
            int i = idx >> 5, j = idx & 31;
            Vt[i * LDSD + j] = (i == j) ? 1.f : 0.f;
        }
    }
    float loc = 0.f;
    for (int idx2 = tid; idx2 < 512; idx2 += NT) {
        int i = idx2 >> 4, jp = idx2 & 15;
        float2 v = *(const float2*)&A[i * LDSD + 2 * jp];
        loc += v.x * v.x + v.y * v.y;
    }
    float fro2 = bsum<NT>(loc, csn + 32, tid);
    float tol2 = fro2 * 1e-9f + 1e-30f;
    __syncthreads();

    for (int sweep = 0; sweep < max_sweeps; ++sweep) {
        for (int r = 0; r < 31; ++r) {
            const ushort* pqr = pq + (r << 4);
            if (tid < 16) {
                int e = pqr[tid], p = e & 31, q = e >> 8;
                float apq = A[p * LDSD + q];
                float c = 1.f, s = 0.f;
                if (fabsf(apq) > 1e-36f) {
                    float app = A[p * LDSD + p], aqq = A[q * LDSD + q];
                    float tau = (aqq - app) / (2.f * apq);
                    float t = (tau >= 0.f ? 1.f : -1.f) / (fabsf(tau) + sqrtf(1.f + tau * tau));
                    c = 1.f / sqrtf(1.f + t * t);
                    s = t * c;
                }
                csn[tid] = c; csn[16 + tid] = s;
            }
            __syncthreads();
            for (int item = tid; item < 256; item += NT) {
                int k = item >> 4, g = item & 15;
                int e = pqr[k], p = e & 31, q = e >> 8;
                float c = csn[k], s = csn[16 + k];
                float2 ap = *(float2*)&A[p * LDSD + 2 * g];
                float2 aq = *(float2*)&A[q * LDSD + 2 * g];
                float2 np, nq;
                np.x = c * ap.x - s * aq.x; np.y = c * ap.y - s * aq.y;
                nq.x = s * ap.x + c * aq.x; nq.y = s * ap.y + c * aq.y;
                *(float2*)&A[p * LDSD + 2 * g] = np;
                *(float2*)&A[q * LDSD + 2 * g] = nq;
            }
            __syncthreads();
            for (int item = tid; item < 512; item += NT) {
                int k = item >> 5, i = item & 31;
                int e = pqr[k], p = e & 31, q = e >> 8;
                float c = csn[k], s = csn[16 + k];
                float ap = A[i * LDSD + p], aq = A[i * LDSD + q];
                A[i * LDSD + p] = c * ap - s * aq;
                A[i * LDSD + q] = s * ap + c * aq;
            }
            if (WANT_V) {
                for (int item = tid; item < 256; item += NT) {
                    int k = item >> 4, g = item & 15;
                    int e = pqr[k], p = e & 31, q = e >> 8;
                    float c = csn[k], s = csn[16 + k];
                    float2 vp = *(float2*)&Vt[p * LDSD + 2 * g];
                    float2 vq = *(float2*)&Vt[q * LDSD + 2 * g];
                    float2 np, nq;
                    np.x = c * vp.x - s * vq.x; np.y = c * vp.y - s * vq.y;
                    nq.x = s * vp.x + c * vq.x; nq.y = s * vp.y + c * vq.y;
                    *(float2*)&Vt[p * LDSD + 2 * g] = np;
                    *(float2*)&Vt[q * LDSD + 2 * g] = nq;
                }
            }
            __syncthreads();
        }
        float l2 = 0.f;
        for (int idx2 = tid; idx2 < 512; idx2 += NT) {
            int i = idx2 >> 4, jp = idx2 & 15;
            float2 v = *(const float2*)&A[i * LDSD + 2 * jp];
            if ((i >> 1) == jp) { if (i & 1) v.y = 0.f; else v.x = 0.f; }
            l2 += v.x * v.x + v.y * v.y;
        }
        l2 = bsum<NT>(l2, csn + 32, tid);
        if (l2 <= tol2) break;
    }
    __syncthreads();
}

// ---------- kernels ----------
__global__ void __launch_bounds__(256) k_count(const int* labels, int B, int* counts) {
    __shared__ int h[NC];
    int tid = threadIdx.x;
    if (tid < NC) h[tid] = 0;
    __syncthreads();
    int loc[NC] = {0, 0, 0, 0, 0, 0, 0, 0};
    for (int b = tid; b < B; b += 256) {
        int lb = labels[b];
#pragma unroll
        for (int c = 0; c < NC; ++c) loc[c] += (lb == c) ? 1 : 0;
    }
#pragma unroll
    for (int c = 0; c < NC; ++c) if (loc[c]) atomicAdd(&h[c], loc[c]);
    __syncthreads();
    if (tid < NC) counts[tid] = h[tid];
}

// stage 1: per-chunk per-class partial sums
__global__ void __launch_bounds__(256) k_accum_part(const float* src, const int* labels, int B, float* part) {
    int blk = blockIdx.x, tid = threadIdx.x;
    int chunk = (B + NPART - 1) / NPART;
    int b0 = blk * chunk, b1 = b0 + chunk < B ? b0 + chunk : B;
    float acc[NC][4];
#pragma unroll
    for (int c = 0; c < NC; ++c)
#pragma unroll
        for (int e = 0; e < 4; ++e) acc[c][e] = 0.f;
    for (int b = b0; b < b1; ++b) {
        int lb = labels[b];
        float x[4];
#pragma unroll
        for (int e = 0; e < 4; ++e) x[e] = src[b * 1024 + tid + 256 * e];
#pragma unroll
        for (int c = 0; c < NC; ++c) {
            if (lb == c) {
#pragma unroll
                for (int e = 0; e < 4; ++e) acc[c][e] += x[e];
            }
        }
    }
#pragma unroll
    for (int c = 0; c < NC; ++c)
#pragma unroll
        for (int e = 0; e < 4; ++e) part[(blk * NC + c) * 1024 + tid + 256 * e] = acc[c][e];
}

__global__ void __launch_bounds__(256) k_accum_fin(const float* part, const int* counts, float* dst) {
    int c = blockIdx.x, tid = threadIdx.x;
    float acc[4] = {0.f, 0.f, 0.f, 0.f};
    for (int k = 0; k < NPART; ++k) {
#pragma unroll
        for (int e = 0; e < 4; ++e) acc[e] += part[(k * NC + c) * 1024 + tid + 256 * e];
    }
    float inv = 1.f / (float)counts[c];
#pragma unroll
    for (int e = 0; e < 4; ++e) dst[c * 1024 + tid + 256 * e] = acc[e] * inv;
}

__global__ void __launch_bounds__(64) k_eig_bary0(const float* bary0, float* sqrtm, float* invsqrtm) {
    __shared__ __align__(16) float A[MAT], Vt[MAT], T1[MAT];
    __shared__ float csn[36], evs[32];
    __shared__ ushort pq[496];
    int c = blockIdx.x, tid = threadIdx.x;
    build_pq<64>(pq, tid);
    g2l<64>(bary0 + c * 1024, A, tid);
    __syncthreads();
    jacobi32<64, true>(A, Vt, csn, pq, tid, 8);
    if (tid < 32) evs[tid] = sqrtf(fmaxf(A[tid * LDSD + tid], 0.f));
    __syncthreads();
    for (int idx2 = tid; idx2 < 512; idx2 += 64) {
        int i = idx2 >> 4, jp = idx2 & 15;
        float2 v = *(const float2*)&Vt[i * LDSD + 2 * jp];
        float e = evs[i];
        float2 w; w.x = e * v.x; w.y = e * v.y;
        *(float2*)&T1[i * LDSD + 2 * jp] = w;
    }
    __syncthreads();
    // sqrtm = Vt^T·diag·Vt  via blocked NT on (T1^T? ) — keep simple TN form:
    {
        int j2 = (tid & 15) * 2, i0 = (tid >> 4) * 8;
        float ac[8][2];
#pragma unroll
        for (int r = 0; r < 8; ++r) { ac[r][0] = 0.f; ac[r][1] = 0.f; }
        for (int k = 0; k < 32; ++k) {
            float2 b = *(const float2*)&T1[k * LDSD + j2];
#pragma unroll
            for (int r = 0; r < 8; ++r) {
                float a = Vt[k * LDSD + i0 + r];
                ac[r][0] = fmaf(a, b.x, ac[r][0]);
                ac[r][1] = fmaf(a, b.y, ac[r][1]);
            }
        }
#pragma unroll
        for (int r = 0; r < 8; ++r) {
            float2 w; w.x = ac[r][0]; w.y = ac[r][1];
            *(float2*)&sqrtm[c * 1024 + (i0 + r) * 32 + j2] = w;
        }
    }
    if (tid < 32) evs[tid] = 1.f / sqrtf(fmaxf(A[tid * LDSD + tid], 1e-30f));
    __syncthreads();
    for (int idx2 = tid; idx2 < 512; idx2 += 64) {
        int i = idx2 >> 4, jp = idx2 & 15;
        float2 v = *(const float2*)&Vt[i * LDSD + 2 * jp];
        float e = evs[i];
        float2 w; w.x = e * v.x; w.y = e * v.y;
        *(float2*)&T1[i * LDSD + 2 * jp] = w;
    }
    __syncthreads();
    {
        int j2 = (tid & 15) * 2, i0 = (tid >> 4) * 8;
        float ac[8][2];
#pragma unroll
        for (int r = 0; r < 8; ++r) { ac[r][0] = 0.f; ac[r][1] = 0.f; }
        for (int k = 0; k < 32; ++k) {
            float2 b = *(const float2*)&T1[k * LDSD + j2];
#pragma unroll
            for (int r = 0; r < 8; ++r) {
                float a = Vt[k * LDSD + i0 + r];
                ac[r][0] = fmaf(a, b.x, ac[r][0]);
                ac[r][1] = fmaf(a, b.y, ac[r][1]);
            }
        }
#pragma unroll
        for (int r = 0; r < 8; ++r) {
            float2 w; w.x = ac[r][0]; w.y = ac[r][1];
            *(float2*)&invsqrtm[c * 1024 + (i0 + r) * 32 + j2] = w;
        }
    }
}

// tangent vectors: split-role wave. half 0: Jacobi on M; half 1: W = sqrtm·(rotations)
__global__ void __launch_bounds__(64) k_tangent(const float* X, const int* labels, const float* sqrtm,
                                                const float* invsqrtm, float* Tbuf) {
    __shared__ __align__(16) float P[MAT], Q[MAT], R[MAT];
    int b = blockIdx.x, tid = threadIdx.x, half = tid >> 5, lh = tid & 31;
    int lb = labels[b];
    g2l<64>(X + b * 1024, P, tid);
    g2l<64>(invsqrtm + lb * 1024, Q, tid);
    __syncthreads();
    mmb_nn(Q, P, R, tid); __syncthreads();      // R = S·X
    mmb_nn(R, Q, P, tid); __syncthreads();      // P = S·X·S = M
    g2l<64>(sqrtm + lb * 1024, R, tid);         // R = sqrtm
    __syncthreads();
    float z_[32];
    if (half == 0) {
#pragma unroll
        for (int r = 0; r < 32; ++r) {
            int i = r ^ lh;
            z_[r] = 0.5f * (P[i * LDSD + lh] + P[lh * LDSD + i]);   // symmetrized M
        }
    } else {
#pragma unroll
        for (int r = 0; r < 32; ++r) z_[r] = R[(r ^ lh) * LDSD + lh];  // W0 = sqrtm col lh (skew)
    }
    // Frobenius tol from half 0
    float fro2 = 0.f;
#pragma unroll
    for (int r = 0; r < 32; ++r) fro2 += z_[r] * z_[r];
#pragma unroll
    for (int off = 16; off > 0; off >>= 1) fro2 += __shfl_xor(fro2, off, 32);
    fro2 = __shfl(fro2, lh, 64);                 // broadcast half-0 value
    float tol2 = fro2 * 1e-9f + 1e-30f;

    for (int sweep = 0; sweep < 8; ++sweep) {
#pragma unroll
        for (int mm = 1; mm < 32; ++mm) {
            // rotation params from half 0's M
            float app = z_[0];
            float aqq = __shfl_xor(app, mm, 32);
            float apq = z_[mm];
            float apqc = __builtin_copysignf(fmaxf(fabsf(apq), 1e-36f), apq);
            float tau = (aqq - app) * 0.5f * fast_rcp(apqc);
            float den = fabsf(tau) + sqrtf(fmaf(tau, tau, 1.f));
            float t = __builtin_copysignf(fast_rcp(den), tau);
            t = (fabsf(apq) > 1e-36f) ? t : 0.f;
            t = __shfl(t, lh, 64);               // half 1 inherits half 0's t (per-lane sign kept)
            float cc = fast_rsq(fmaf(t, t, 1.f));
            float ss = t * cc;
            if (half == 0) {                     // row rotations on M only
#pragma unroll
                for (int r = 0; r < 32; ++r) {
                    if (r < (r ^ mm)) {
                        const int r2 = r ^ mm;
                        float ti = __shfl_xor(t, r, 32);
                        float ci = fast_rsq(fmaf(ti, ti, 1.f));
                        float si = ti * ci;
                        float x = z_[r], y = z_[r2];
                        z_[r]  = ci * x - si * y;
                        z_[r2] = ci * y + si * x;
                    }
                }
            }
            // column rotations: identical stream for M (half 0) and W (half 1)
#pragma unroll
            for (int r = 0; r < 32; ++r) {
                if (r < (r ^ mm)) {
                    const int r2 = r ^ mm;
                    float o1 = __shfl_xor(z_[r2], mm, 32);
                    float o2 = __shfl_xor(z_[r], mm, 32);
                    z_[r]  = cc * z_[r]  - ss * o1;
                    z_[r2] = cc * z_[r2] - ss * o2;
                }
            }
        }
        float off2 = 0.f;
#pragma unroll
        for (int r = 1; r < 32; ++r) off2 += z_[r] * z_[r];
#pragma unroll
        for (int off = 16; off > 0; off >>= 1) off2 += __shfl_xor(off2, off, 32);
        off2 = __shfl(off2, lh, 64);             // half-0's off-norm everywhere
        if (__all(off2 <= tol2)) break;
    }
    // eigenvalue of column lh from half 0; half 1 holds W[:,lh] = (sqrtm·V)[:,lh]
    float lam = __shfl(z_[0], lh, 64);
    float ev = logf(fmaxf(lam, EV_EPS));
    __syncthreads();
    if (half == 1) {
#pragma unroll
        for (int r = 0; r < 32; ++r) {
            float w = z_[r];
            int i = r ^ lh;
            Q[i * LDSD + lh] = w;                // Q = W
            P[i * LDSD + lh] = w * ev;           // P = W·diag(log λ)
        }
    }
    __syncthreads();
    mmb_nt_g(P, Q, Tbuf + b * 1024, tid);        // T = W·diag·W^T = sqrtm·logM·sqrtm
}

__global__ void __launch_bounds__(64) k_update(const float* meanT, const float* sqrtm, const float* invsqrtm,
                                               const float* bary0, float* bary) {
    __shared__ __align__(16) float X1[MAT], S1[MAT], T1[MAT], Vt[MAT];
    __shared__ float csn[36], evs[32];
    __shared__ ushort pq[496];
    int c = blockIdx.x, tid = threadIdx.x;
    build_pq<64>(pq, tid);
    g2l<64>(meanT + c * 1024, X1, tid);
    g2l<64>(invsqrtm + c * 1024, S1, tid);
    __syncthreads();
    mmb_nn(S1, X1, T1, tid); __syncthreads();
    mmb_nn(T1, S1, X1, tid); __syncthreads();
    jacobi32<64, true>(X1, Vt, csn, pq, tid, 8);
    // faithful quirk: clamp eigenvalues to >= 1e-10 BEFORE exp
    if (tid < 32) evs[tid] = expf(fmaxf(X1[tid * LDSD + tid], EV_EPS));
    __syncthreads();
    for (int idx2 = tid; idx2 < 512; idx2 += 64) {
        int i = idx2 >> 4, jp = idx2 & 15;
        float2 v = *(const float2*)&Vt[i * LDSD + 2 * jp];
        float e = evs[i];
        float2 w; w.x = e * v.x; w.y = e * v.y;
        *(float2*)&T1[i * LDSD + 2 * jp] = w;
    }
    __syncthreads();
    // S1 = Vt^T·T1 (expN)
    {
        int j2 = (tid & 15) * 2, i0 = (tid >> 4) * 8;
        float ac[8][2];
#pragma unroll
        for (int r = 0; r < 8; ++r) { ac[r][0] = 0.f; ac[r][1] = 0.f; }
        for (int k = 0; k < 32; ++k) {
            float2 b = *(const float2*)&T1[k * LDSD + j2];
#pragma unroll
            for (int r = 0; r < 8; ++r) {
                float a = Vt[k * LDSD + i0 + r];
                ac[r][0] = fmaf(a, b.x, ac[r][0]);
                ac[r][1] = fmaf(a, b.y, ac[r][1]);
            }
        }
        __syncthreads();
#pragma unroll
        for (int r = 0; r < 8; ++r) {
            float2 w; w.x = ac[r][0]; w.y = ac[r][1];
            *(float2*)&S1[(i0 + r) * LDSD + j2] = w;
        }
    }
    __syncthreads();
    g2l<64>(sqrtm + c * 1024, Vt, tid);
    __syncthreads();
    mmb_nn(Vt, S1, T1, tid); __syncthreads();
    mmb_nn(T1, Vt, X1, tid); __syncthreads();
    float loc = 0.f;
    for (int idx = tid; idx < 1024; idx += 64) {
        int i = idx >> 5, j = idx & 31;
        float d = X1[i * LDSD + j] - bary0[c * 1024 + idx];
        loc += d * d;
    }
#pragma unroll
    for (int off = 32; off > 0; off >>= 1) loc += __shfl_down(loc, off);
    float err2 = __shfl(loc, 0);
    bool keep0 = (err2 < 1e-8f);  // CONV_TOL^2
    for (int idx = tid; idx < 1024; idx += 64) {
        int i = idx >> 5, j = idx & 31;
        bary[c * 1024 + idx] = keep0 ? bary0[c * 1024 + idx] : X1[i * LDSD + j];
    }
}

__global__ void __launch_bounds__(64) k_cholinv(const float* X, float* WtBuf) {
    __shared__ __align__(16) float A[MAT], W[MAT];
    int b = blockIdx.x, tid = threadIdx.x;
    g2l<64>(X + b * 1024, A, tid);
    __syncthreads();
    if (tid < 32) A[tid * LDSD + tid] += 1e-3f;  // CHOL_EPS
    __syncthreads();
    for (int k = 0; k < 32; ++k) {
        if (tid == 0) A[k * LDSD + k] = sqrtf(A[k * LDSD + k]);
        __syncthreads();
        float invd = 1.f / A[k * LDSD + k];
        if (tid > k && tid < 32) A[tid * LDSD + k] *= invd;
        __syncthreads();
        for (int idx = tid; idx < 1024; idx += 64) {
            int i = idx >> 5, j = idx & 31;
            if (i > k && j > k && j <= i) A[i * LDSD + j] -= A[i * LDSD + k] * A[j * LDSD + k];
        }
        __syncthreads();
    }
    if (tid < 32) {
        int j = tid;
        W[j * LDSD + j] = 1.f / A[j * LDSD + j];
        for (int i = j + 1; i < 32; ++i) {
            float acc = 0.f;
            for (int k2 = j; k2 < i; ++k2) acc += A[i * LDSD + k2] * W[k2 * LDSD + j];
            W[i * LDSD + j] = -acc / A[i * LDSD + i];
        }
        for (int i = 0; i < j; ++i) W[i * LDSD + j] = 0.f;
    }
    __syncthreads();
    for (int idx = tid; idx < 1024; idx += 64) {
        int i = idx >> 5, j = idx & 31;
        WtBuf[b * 1024 + idx] = W[j * LDSD + i];  // store L^{-T}
    }
}

__global__ void __launch_bounds__(64) k_pairdist(const float* WtBuf, const float* bary, float* D) {
    __shared__ __align__(16) float Wl[MAT], Bc[MAT], T1[MAT];
    int bid = blockIdx.x;
    int b = bid >> 2, cp = bid & 3;
    int tid = threadIdx.x, half = tid >> 5, lh = tid & 31;
    g2l<64>(WtBuf + b * 1024, Wl, tid);
    __syncthreads();
    float m_[32];
    for (int h = 0; h < 2; ++h) {
        g2l<64>(bary + (2 * cp + h) * 1024, Bc, tid);
        __syncthreads();
        // faithful quirk: M = L^{-T} bary L^{-T}
        mmb_nn(Wl, Bc, T1, tid); __syncthreads();
        mmb_nn(T1, Wl, Bc, tid); __syncthreads();
        if (half == h) {
#pragma unroll
            for (int r = 0; r < 32; ++r) {
                int i = r ^ lh;
                int hi = i > lh ? i : lh, lo = i > lh ? lh : i;  // eigvalsh UPLO='L'
                m_[r] = Bc[hi * LDSD + lo];
            }
        }
        __syncthreads();
    }
    rjacobi_nv(m_, 1e-8f, 8);
    float lg = logf(fmaxf(m_[0], EV_EPS));
    float d2 = lg * lg;
#pragma unroll
    for (int off = 16; off > 0; off >>= 1) d2 += __shfl_xor(d2, off, 32);
    if (lh == 0) D[b * NC + 2 * cp + half] = sqrtf(d2);
}

__global__ void k_loss(const float* out, const int* labels, const float* D, int B, float* res) {
    __shared__ float sI[256], sD[256], sC[256];
    int tid = threadIdx.x;
    float aI = 0.f, aD = 0.f, aC = 0.f;
    for (int b = tid; b < B; b += 256) {
        int lb = labels[b];
        const float* ob = out + b * NC;
        float m = ob[0];
#pragma unroll
        for (int j = 1; j < NC; ++j) m = fmaxf(m, ob[j]);
        float se = 0.f;
#pragma unroll
        for (int j = 0; j < NC; ++j) se += expf(ob[j] - m);
        aC += m + logf(se) - ob[lb];
        const float* db = D + b * NC;
        float s = 0.f;
#pragma unroll
        for (int j = 0; j < NC; ++j) s += db[j];
        aI += db[lb];
        aD += s - db[lb];
    }
    sI[tid] = aI; sD[tid] = aD; sC[tid] = aC;
    __syncthreads();
    for (int off = 128; off > 0; off >>= 1) {
        if (tid < off) { sI[tid] += sI[tid + off]; sD[tid] += sD[tid + off]; sC[tid] += sC[tid + off]; }
        __syncthreads();
    }
    if (tid == 0) {
        float intra = 0.001f * sI[0] / (float)B;
        float disp = sD[0] / (float)(B * (NC - 1));
        float ce = sC[0] / (float)B;
        res[0] = intra - 0.001f * disp + ce;
    }
}

extern "C" void kernel_launch(void* const* d_in, const int* in_sizes, int n_in,
                              void* d_out, int out_size, void* d_ws, size_t ws_size,
                              hipStream_t stream) {
    const float* X = (const float*)d_in[0];
    const float* out = (const float*)d_in[1];
    const int* labels = (const int*)d_in[2];
    int B = in_sizes[2];

    float* ws = (float*)d_ws;
    float* bary0    = ws;                 // 8192
    float* sqrtm    = ws + 8192;          // 8192
    float* invsqrtm = ws + 16384;         // 8192
    float* meanT    = ws + 24576;         // 8192
    float* bary     = ws + 32768;         // 8192
    float* D        = ws + 40960;         // B*8 = 16384
    int*   counts   = (int*)(ws + 57344); // 8
    float* big      = ws + 65536;         // B*1024 floats (partials, then T, then Wt)
    float* part2    = ws + 65536 + (size_t)B * 1024;  // NPART*NC*1024 floats

    k_count<<<1, 256, 0, stream>>>(labels, B, counts);
    k_accum_part<<<NPART, 256, 0, stream>>>(X, labels, B, big);
    k_accum_fin<<<NC, 256, 0, stream>>>(big, counts, bary0);
    k_eig_bary0<<<NC, 64, 0, stream>>>(bary0, sqrtm, invsqrtm);
    k_tangent<<<B, 64, 0, stream>>>(X, labels, sqrtm, invsqrtm, big);
    k_accum_part<<<NPART, 256, 0, stream>>>(big, labels, B, part2);
    k_accum_fin<<<NC, 256, 0, stream>>>(part2, counts, meanT);
    k_update<<<NC, 64, 0, stream>>>(meanT, sqrtm, invsqrtm, bary0, bary);
    k_cholinv<<<B, 64, 0, stream>>>(X, big);
    k_pairdist<<<B * 4, 64, 0, stream>>>(big, bary, D);
    k_loss<<<1, 256, 0, stream>>>(out, labels, D, B, (float*)d_out);
}

// Round 6
// 1732.894 us; speedup vs baseline: 2.6022x; 1.0723x over previous
//
#include <hip/hip_runtime.h>
#include <math.h>

#define NC 8
#define NDIM 32
#define LDSD 34            // stride 34: rows 8B-aligned (float2); col access 2-way bank alias (free)
#define MAT (NDIM * LDSD)  // 1088 floats per LDS matrix
#define EV_EPS 1e-10f
#define NPART 32

#if __has_builtin(__builtin_amdgcn_rcpf)
__device__ inline float fast_rcp(float x) { return __builtin_amdgcn_rcpf(x); }
#else
__device__ inline float fast_rcp(float x) { return 1.f / x; }
#endif
#if __has_builtin(__builtin_amdgcn_rsqf)
__device__ inline float fast_rsq(float x) { return __builtin_amdgcn_rsqf(x); }
#else
__device__ inline float fast_rsq(float x) { return 1.f / sqrtf(x); }
#endif

// ---------- round-robin tournament pairing (8-block LDS-Jacobi kernels only) ----------
__device__ inline void rr_pair(int r, int k, int& p, int& q) {
    int a, b;
    if (k == 0) { a = 31; b = r; }
    else { a = (r + k) % 31; b = (r - k + 62) % 31; }
    p = a < b ? a : b;
    q = a < b ? b : a;
}

template <int NT>
__device__ inline void build_pq(ushort* pq, int tid) {
    for (int e = tid; e < 496; e += NT) {
        int r = e >> 4, kk = e & 15;
        int p, q; rr_pair(r, kk, p, q);
        pq[e] = (ushort)(p | (q << 8));
    }
}

template <int NT>
__device__ inline float bsum(float v, float* scratch, int tid) {
#pragma unroll
    for (int off = 32; off > 0; off >>= 1) v += __shfl_down(v, off);
    if constexpr (NT == 64) {
        return __shfl(v, 0);
    } else {
        if ((tid & 63) == 0) scratch[tid >> 6] = v;
        __syncthreads();
        float r = scratch[0] + scratch[1];
        __syncthreads();
        return r;
    }
}

// ---------- 32x32 LDS helpers ----------
template <int NT>
__device__ inline void g2l(const float* g, float* l, int tid) {
    for (int idx2 = tid; idx2 < 512; idx2 += NT) {
        int i = idx2 >> 4, jp = idx2 & 15;
        *(float2*)&l[i * LDSD + 2 * jp] = *(const float2*)&g[i * 32 + 2 * jp];
    }
}
template <int NT>
__device__ inline void l2g(const float* l, float* g, int tid) {
    for (int idx2 = tid; idx2 < 512; idx2 += NT) {
        int i = idx2 >> 4, jp = idx2 & 15;
        *(float2*)&g[i * 32 + 2 * jp] = *(const float2*)&l[i * LDSD + 2 * jp];
    }
}

// ---------- register-tiled LDS matmuls (64 threads; 8-row x 2-col tile/thread) ----------
// C = A * B.  SAFE with C == B (each thread reads only its own B columns and
// writes only those columns, all loads precede stores in program order).
__device__ inline void mmb_nn(const float* A, const float* B, float* C, int tid) {
    int j2 = (tid & 15) * 2;
    int i0 = (tid >> 4) * 8;
    float a0[2] = {0.f,0.f}, a1[2] = {0.f,0.f}, a2[2] = {0.f,0.f}, a3[2] = {0.f,0.f};
    float a4[2] = {0.f,0.f}, a5[2] = {0.f,0.f}, a6[2] = {0.f,0.f}, a7[2] = {0.f,0.f};
#pragma unroll
    for (int k = 0; k < 32; k += 2) {
        float2 b0 = *(const float2*)&B[k * LDSD + j2];
        float2 b1 = *(const float2*)&B[(k + 1) * LDSD + j2];
#define ROWNN(rr, ac) { float2 a = *(const float2*)&A[(i0 + rr) * LDSD + k]; \
        ac[0] = fmaf(a.x, b0.x, fmaf(a.y, b1.x, ac[0])); \
        ac[1] = fmaf(a.x, b0.y, fmaf(a.y, b1.y, ac[1])); }
        ROWNN(0, a0) ROWNN(1, a1) ROWNN(2, a2) ROWNN(3, a3)
        ROWNN(4, a4) ROWNN(5, a5) ROWNN(6, a6) ROWNN(7, a7)
#undef ROWNN
    }
#define STNN(rr, ac) { float2 w; w.x = ac[0]; w.y = ac[1]; *(float2*)&C[(i0 + rr) * LDSD + j2] = w; }
    STNN(0, a0) STNN(1, a1) STNN(2, a2) STNN(3, a3)
    STNN(4, a4) STNN(5, a5) STNN(6, a6) STNN(7, a7)
#undef STNN
}
// C = A * B with C aliasing A: accumulate, block-wide barrier, then store.
__device__ inline void mmb_nn_st(const float* A, const float* B, float* C, int tid) {
    int j2 = (tid & 15) * 2;
    int i0 = (tid >> 4) * 8;
    float a0[2] = {0.f,0.f}, a1[2] = {0.f,0.f}, a2[2] = {0.f,0.f}, a3[2] = {0.f,0.f};
    float a4[2] = {0.f,0.f}, a5[2] = {0.f,0.f}, a6[2] = {0.f,0.f}, a7[2] = {0.f,0.f};
#pragma unroll
    for (int k = 0; k < 32; k += 2) {
        float2 b0 = *(const float2*)&B[k * LDSD + j2];
        float2 b1 = *(const float2*)&B[(k + 1) * LDSD + j2];
#define ROWNN(rr, ac) { float2 a = *(const float2*)&A[(i0 + rr) * LDSD + k]; \
        ac[0] = fmaf(a.x, b0.x, fmaf(a.y, b1.x, ac[0])); \
        ac[1] = fmaf(a.x, b0.y, fmaf(a.y, b1.y, ac[1])); }
        ROWNN(0, a0) ROWNN(1, a1) ROWNN(2, a2) ROWNN(3, a3)
        ROWNN(4, a4) ROWNN(5, a5) ROWNN(6, a6) ROWNN(7, a7)
#undef ROWNN
    }
    __syncthreads();   // all threads done reading A and B
#define STNN(rr, ac) { float2 w; w.x = ac[0]; w.y = ac[1]; *(float2*)&C[(i0 + rr) * LDSD + j2] = w; }
    STNN(0, a0) STNN(1, a1) STNN(2, a2) STNN(3, a3)
    STNN(4, a4) STNN(5, a5) STNN(6, a6) STNN(7, a7)
#undef STNN
}
// gC(global, stride 32) = A * B^T
__device__ inline void mmb_nt_g(const float* A, const float* B, float* gC, int tid) {
    int j2 = (tid & 15) * 2;
    int i0 = (tid >> 4) * 8;
    float a0[2] = {0.f,0.f}, a1[2] = {0.f,0.f}, a2[2] = {0.f,0.f}, a3[2] = {0.f,0.f};
    float a4[2] = {0.f,0.f}, a5[2] = {0.f,0.f}, a6[2] = {0.f,0.f}, a7[2] = {0.f,0.f};
#pragma unroll
    for (int l = 0; l < 32; l += 2) {
        float2 b0 = *(const float2*)&B[j2 * LDSD + l];
        float2 b1 = *(const float2*)&B[(j2 + 1) * LDSD + l];
#define ROWNT(rr, ac) { float2 a = *(const float2*)&A[(i0 + rr) * LDSD + l]; \
        ac[0] = fmaf(a.x, b0.x, fmaf(a.y, b0.y, ac[0])); \
        ac[1] = fmaf(a.x, b1.x, fmaf(a.y, b1.y, ac[1])); }
        ROWNT(0, a0) ROWNT(1, a1) ROWNT(2, a2) ROWNT(3, a3)
        ROWNT(4, a4) ROWNT(5, a5) ROWNT(6, a6) ROWNT(7, a7)
#undef ROWNT
    }
#define STNT(rr, ac) { float2 w; w.x = ac[0]; w.y = ac[1]; *(float2*)&gC[(i0 + rr) * 32 + j2] = w; }
    STNT(0, a0) STNT(1, a1) STNT(2, a2) STNT(3, a3)
    STNT(4, a4) STNT(5, a5) STNT(6, a6) STNT(7, a7)
#undef STNT
}

// ---------- register-resident XOR-ordered Jacobi, eigenvalues only, fixed sweeps ----------
__device__ inline void rjacobi_fixed(float* m_, int nsweep) {
    for (int sweep = 0; sweep < nsweep; ++sweep) {
#pragma unroll
        for (int mm = 1; mm < 32; ++mm) {
            float app = m_[0];
            float aqq = __shfl_xor(app, mm, 32);
            float apq = m_[mm];
            float apqc = __builtin_copysignf(fmaxf(fabsf(apq), 1e-36f), apq);
            float tau = (aqq - app) * 0.5f * fast_rcp(apqc);
            float den = fabsf(tau) + sqrtf(fmaf(tau, tau, 1.f));
            float t = __builtin_copysignf(fast_rcp(den), tau);
            t = (fabsf(apq) > 1e-36f) ? t : 0.f;
            float cc = fast_rsq(fmaf(t, t, 1.f));
            float ss = t * cc;
#pragma unroll
            for (int r = 0; r < 32; ++r) {
                if (r < (r ^ mm)) {
                    const int r2 = r ^ mm;
                    float ti = __shfl_xor(t, r, 32);
                    float ci = fast_rsq(fmaf(ti, ti, 1.f));
                    float si = ti * ci;
                    float x = m_[r], y = m_[r2];
                    m_[r]  = ci * x - si * y;
                    m_[r2] = ci * y + si * x;
                }
            }
#pragma unroll
            for (int r = 0; r < 32; ++r) {
                if (r < (r ^ mm)) {
                    const int r2 = r ^ mm;
                    float o1 = __shfl_xor(m_[r2], mm, 32);
                    float o2 = __shfl_xor(m_[r], mm, 32);
                    m_[r]  = cc * m_[r]  - ss * o1;
                    m_[r2] = cc * m_[r2] - ss * o2;
                }
            }
        }
    }
}

// ---------- LDS parallel Jacobi (8-block kernels only) ----------
template <int NT, bool WANT_V>
__device__ void jacobi32(float* A, float* Vt, float* csn, const ushort* pq, int tid, int max_sweeps) {
    if (WANT_V) {
        for (int idx = tid; idx < 1024; idx += NT) {
            int i = idx >> 5, j = idx & 31;
            Vt[i * LDSD + j] = (i == j) ? 1.f : 0.f;
        }
    }
    float loc = 0.f;
    for (int idx2 = tid; idx2 < 512; idx2 += NT) {
        int i = idx2 >> 4, jp = idx2 & 15;
        float2 v = *(const float2*)&A[i * LDSD + 2 * jp];
        loc += v.x * v.x + v.y * v.y;
    }
    float fro2 = bsum<NT>(loc, csn + 32, tid);
    float tol2 = fro2 * 1e-9f + 1e-30f;
    __syncthreads();

    for (int sweep = 0; sweep < max_sweeps; ++sweep) {
        for (int r = 0; r < 31; ++r) {
            const ushort* pqr = pq + (r << 4);
            if (tid < 16) {
                int e = pqr[tid], p = e & 31, q = e >> 8;
                float apq = A[p * LDSD + q];
                float c = 1.f, s = 0.f;
                if (fabsf(apq) > 1e-36f) {
                    float app = A[p * LDSD + p], aqq = A[q * LDSD + q];
                    float tau = (aqq - app) / (2.f * apq);
                    float t = (tau >= 0.f ? 1.f : -1.f) / (fabsf(tau) + sqrtf(1.f + tau * tau));
                    c = 1.f / sqrtf(1.f + t * t);
                    s = t * c;
                }
                csn[tid] = c; csn[16 + tid] = s;
            }
            __syncthreads();
            for (int item = tid; item < 256; item += NT) {
                int k = item >> 4, g = item & 15;
                int e = pqr[k], p = e & 31, q = e >> 8;
                float c = csn[k], s = csn[16 + k];
                float2 ap = *(float2*)&A[p * LDSD + 2 * g];
                float2 aq = *(float2*)&A[q * LDSD + 2 * g];
                float2 np, nq;
                np.x = c * ap.x - s * aq.x; np.y = c * ap.y - s * aq.y;
                nq.x = s * ap.x + c * aq.x; nq.y = s * ap.y + c * aq.y;
                *(float2*)&A[p * LDSD + 2 * g] = np;
                *(float2*)&A[q * LDSD + 2 * g] = nq;
            }
            __syncthreads();
            for (int item = tid; item < 512; item += NT) {
                int k = item >> 5, i = item & 31;
                int e = pqr[k], p = e & 31, q = e >> 8;
                float c = csn[k], s = csn[16 + k];
                float ap = A[i * LDSD + p], aq = A[i * LDSD + q];
                A[i * LDSD + p] = c * ap - s * aq;
                A[i * LDSD + q] = s * ap + c * aq;
            }
            if (WANT_V) {
                for (int item = tid; item < 256; item += NT) {
                    int k = item >> 4, g = item & 15;
                    int e = pqr[k], p = e & 31, q = e >> 8;
                    float c = csn[k], s = csn[16 + k];
                    float2 vp = *(float2*)&Vt[p * LDSD + 2 * g];
                    float2 vq = *(float2*)&Vt[q * LDSD + 2 * g];
                    float2 np, nq;
                    np.x = c * vp.x - s * vq.x; np.y = c * vp.y - s * vq.y;
                    nq.x = s * vp.x + c * vq.x; nq.y = s * vp.y + c * vq.y;
                    *(float2*)&Vt[p * LDSD + 2 * g] = np;
                    *(float2*)&Vt[q * LDSD + 2 * g] = nq;
                }
            }
            __syncthreads();
        }
        float l2 = 0.f;
        for (int idx2 = tid; idx2 < 512; idx2 += NT) {
            int i = idx2 >> 4, jp = idx2 & 15;
            float2 v = *(const float2*)&A[i * LDSD + 2 * jp];
            if ((i >> 1) == jp) { if (i & 1) v.y = 0.f; else v.x = 0.f; }
            l2 += v.x * v.x + v.y * v.y;
        }
        l2 = bsum<NT>(l2, csn + 32, tid);
        if (l2 <= tol2) break;
    }
    __syncthreads();
}

// ---------- kernels ----------
__global__ void __launch_bounds__(256) k_count(const int* labels, int B, int* counts) {
    __shared__ int h[NC];
    int tid = threadIdx.x;
    if (tid < NC) h[tid] = 0;
    __syncthreads();
    int loc[NC] = {0, 0, 0, 0, 0, 0, 0, 0};
    for (int b = tid; b < B; b += 256) {
        int lb = labels[b];
#pragma unroll
        for (int c = 0; c < NC; ++c) loc[c] += (lb == c) ? 1 : 0;
    }
#pragma unroll
    for (int c = 0; c < NC; ++c) if (loc[c]) atomicAdd(&h[c], loc[c]);
    __syncthreads();
    if (tid < NC) counts[tid] = h[tid];
}

__global__ void __launch_bounds__(256) k_accum_part(const float* src, const int* labels, int B, float* part) {
    int blk = blockIdx.x, tid = threadIdx.x;
    int chunk = (B + NPART - 1) / NPART;
    int b0 = blk * chunk, b1 = b0 + chunk < B ? b0 + chunk : B;
    float acc[NC][4];
#pragma unroll
    for (int c = 0; c < NC; ++c)
#pragma unroll
        for (int e = 0; e < 4; ++e) acc[c][e] = 0.f;
    for (int b = b0; b < b1; ++b) {
        int lb = labels[b];
        float x[4];
#pragma unroll
        for (int e = 0; e < 4; ++e) x[e] = src[b * 1024 + tid + 256 * e];
#pragma unroll
        for (int c = 0; c < NC; ++c) {
            if (lb == c) {
#pragma unroll
                for (int e = 0; e < 4; ++e) acc[c][e] += x[e];
            }
        }
    }
#pragma unroll
    for (int c = 0; c < NC; ++c)
#pragma unroll
        for (int e = 0; e < 4; ++e) part[(blk * NC + c) * 1024 + tid + 256 * e] = acc[c][e];
}

__global__ void __launch_bounds__(256) k_accum_fin(const float* part, const int* counts, float* dst) {
    int c = blockIdx.x, tid = threadIdx.x;
    float acc[4] = {0.f, 0.f, 0.f, 0.f};
    for (int k = 0; k < NPART; ++k) {
#pragma unroll
        for (int e = 0; e < 4; ++e) acc[e] += part[(k * NC + c) * 1024 + tid + 256 * e];
    }
    float inv = 1.f / (float)counts[c];
#pragma unroll
    for (int e = 0; e < 4; ++e) dst[c * 1024 + tid + 256 * e] = acc[e] * inv;
}

__global__ void __launch_bounds__(64) k_eig_bary0(const float* bary0, float* sqrtm, float* invsqrtm) {
    __shared__ __align__(16) float A[MAT], Vt[MAT], T1[MAT];
    __shared__ float csn[36], evs[32];
    __shared__ ushort pq[496];
    int c = blockIdx.x, tid = threadIdx.x;
    build_pq<64>(pq, tid);
    g2l<64>(bary0 + c * 1024, A, tid);
    __syncthreads();
    jacobi32<64, true>(A, Vt, csn, pq, tid, 8);
    if (tid < 32) evs[tid] = sqrtf(fmaxf(A[tid * LDSD + tid], 0.f));
    __syncthreads();
    for (int idx2 = tid; idx2 < 512; idx2 += 64) {
        int i = idx2 >> 4, jp = idx2 & 15;
        float2 v = *(const float2*)&Vt[i * LDSD + 2 * jp];
        float e = evs[i];
        float2 w; w.x = e * v.x; w.y = e * v.y;
        *(float2*)&T1[i * LDSD + 2 * jp] = w;
    }
    __syncthreads();
    {
        int j2 = (tid & 15) * 2, i0 = (tid >> 4) * 8;
        float ac[8][2];
#pragma unroll
        for (int r = 0; r < 8; ++r) { ac[r][0] = 0.f; ac[r][1] = 0.f; }
        for (int k = 0; k < 32; ++k) {
            float2 b = *(const float2*)&T1[k * LDSD + j2];
#pragma unroll
            for (int r = 0; r < 8; ++r) {
                float a = Vt[k * LDSD + i0 + r];
                ac[r][0] = fmaf(a, b.x, ac[r][0]);
                ac[r][1] = fmaf(a, b.y, ac[r][1]);
            }
        }
#pragma unroll
        for (int r = 0; r < 8; ++r) {
            float2 w; w.x = ac[r][0]; w.y = ac[r][1];
            *(float2*)&sqrtm[c * 1024 + (i0 + r) * 32 + j2] = w;
        }
    }
    if (tid < 32) evs[tid] = 1.f / sqrtf(fmaxf(A[tid * LDSD + tid], 1e-30f));
    __syncthreads();
    for (int idx2 = tid; idx2 < 512; idx2 += 64) {
        int i = idx2 >> 4, jp = idx2 & 15;
        float2 v = *(const float2*)&Vt[i * LDSD + 2 * jp];
        float e = evs[i];
        float2 w; w.x = e * v.x; w.y = e * v.y;
        *(float2*)&T1[i * LDSD + 2 * jp] = w;
    }
    __syncthreads();
    {
        int j2 = (tid & 15) * 2, i0 = (tid >> 4) * 8;
        float ac[8][2];
#pragma unroll
        for (int r = 0; r < 8; ++r) { ac[r][0] = 0.f; ac[r][1] = 0.f; }
        for (int k = 0; k < 32; ++k) {
            float2 b = *(const float2*)&T1[k * LDSD + j2];
#pragma unroll
            for (int r = 0; r < 8; ++r) {
                float a = Vt[k * LDSD + i0 + r];
                ac[r][0] = fmaf(a, b.x, ac[r][0]);
                ac[r][1] = fmaf(a, b.y, ac[r][1]);
            }
        }
#pragma unroll
        for (int r = 0; r < 8; ++r) {
            float2 w; w.x = ac[r][0]; w.y = ac[r][1];
            *(float2*)&invsqrtm[c * 1024 + (i0 + r) * 32 + j2] = w;
        }
    }
}

// tangent: 2 LDS buffers; split-role wave; fixed 4 sweeps
__global__ void __launch_bounds__(64) k_tangent(const float* X, const int* labels, const float* sqrtm,
                                                const float* invsqrtm, float* Tbuf) {
    __shared__ __align__(16) float P[MAT], Q[MAT];
    int b = blockIdx.x, tid = threadIdx.x, half = tid >> 5, lh = tid & 31;
    int lb = labels[b];
    g2l<64>(X + b * 1024, P, tid);
    g2l<64>(invsqrtm + lb * 1024, Q, tid);
    __syncthreads();
    mmb_nn(Q, P, P, tid); __syncthreads();   // P = S·X          (in-place on B)
    mmb_nn(P, Q, Q, tid); __syncthreads();   // Q = (S·X)·S = M  (in-place on B)
    g2l<64>(sqrtm + lb * 1024, P, tid);      // P = sqrtm
    __syncthreads();
    float z_[32];
    if (half == 0) {
#pragma unroll
        for (int r = 0; r < 32; ++r) {
            int i = r ^ lh;
            z_[r] = 0.5f * (Q[i * LDSD + lh] + Q[lh * LDSD + i]);   // symmetrized M
        }
    } else {
#pragma unroll
        for (int r = 0; r < 32; ++r) z_[r] = P[(r ^ lh) * LDSD + lh];  // W0 = sqrtm col lh (skew)
    }
    for (int sweep = 0; sweep < 4; ++sweep) {
#pragma unroll
        for (int mm = 1; mm < 32; ++mm) {
            float app = z_[0];
            float aqq = __shfl_xor(app, mm, 32);
            float apq = z_[mm];
            float apqc = __builtin_copysignf(fmaxf(fabsf(apq), 1e-36f), apq);
            float tau = (aqq - app) * 0.5f * fast_rcp(apqc);
            float den = fabsf(tau) + sqrtf(fmaf(tau, tau, 1.f));
            float t = __builtin_copysignf(fast_rcp(den), tau);
            t = (fabsf(apq) > 1e-36f) ? t : 0.f;
            t = __shfl(t, lh, 64);               // half 1 inherits half 0's t
            float cc = fast_rsq(fmaf(t, t, 1.f));
            float ss = t * cc;
            if (half == 0) {                     // row rotations on M only
#pragma unroll
                for (int r = 0; r < 32; ++r) {
                    if (r < (r ^ mm)) {
                        const int r2 = r ^ mm;
                        float ti = __shfl_xor(t, r, 32);
                        float ci = fast_rsq(fmaf(ti, ti, 1.f));
                        float si = ti * ci;
                        float x = z_[r], y = z_[r2];
                        z_[r]  = ci * x - si * y;
                        z_[r2] = ci * y + si * x;
                    }
                }
            }
#pragma unroll
            for (int r = 0; r < 32; ++r) {       // col rotations: M (h0) and W (h1)
                if (r < (r ^ mm)) {
                    const int r2 = r ^ mm;
                    float o1 = __shfl_xor(z_[r2], mm, 32);
                    float o2 = __shfl_xor(z_[r], mm, 32);
                    z_[r]  = cc * z_[r]  - ss * o1;
                    z_[r2] = cc * z_[r2] - ss * o2;
                }
            }
        }
    }
    float lam = __shfl(z_[0], lh, 64);
    float ev = logf(fmaxf(lam, EV_EPS));
    __syncthreads();                             // extraction reads of P,Q done
    if (half == 1) {
#pragma unroll
        for (int r = 0; r < 32; ++r) {
            float w = z_[r];
            int i = r ^ lh;
            Q[i * LDSD + lh] = w;                // Q = W = sqrtm·V
            P[i * LDSD + lh] = w * ev;           // P = W·diag(log λ)
        }
    }
    __syncthreads();
    mmb_nt_g(P, Q, Tbuf + b * 1024, tid);        // T = W·diag·W^T
}

__global__ void __launch_bounds__(64) k_update(const float* meanT, const float* sqrtm, const float* invsqrtm,
                                               const float* bary0, float* bary) {
    __shared__ __align__(16) float X1[MAT], S1[MAT], T1[MAT], Vt[MAT];
    __shared__ float csn[36], evs[32];
    __shared__ ushort pq[496];
    int c = blockIdx.x, tid = threadIdx.x;
    build_pq<64>(pq, tid);
    g2l<64>(meanT + c * 1024, X1, tid);
    g2l<64>(invsqrtm + c * 1024, S1, tid);
    __syncthreads();
    mmb_nn(S1, X1, T1, tid); __syncthreads();
    mmb_nn(T1, S1, X1, tid); __syncthreads();
    jacobi32<64, true>(X1, Vt, csn, pq, tid, 8);
    // faithful quirk: clamp eigenvalues to >= 1e-10 BEFORE exp
    if (tid < 32) evs[tid] = expf(fmaxf(X1[tid * LDSD + tid], EV_EPS));
    __syncthreads();
    for (int idx2 = tid; idx2 < 512; idx2 += 64) {
        int i = idx2 >> 4, jp = idx2 & 15;
        float2 v = *(const float2*)&Vt[i * LDSD + 2 * jp];
        float e = evs[i];
        float2 w; w.x = e * v.x; w.y = e * v.y;
        *(float2*)&T1[i * LDSD + 2 * jp] = w;
    }
    __syncthreads();
    {
        int j2 = (tid & 15) * 2, i0 = (tid >> 4) * 8;
        float ac[8][2];
#pragma unroll
        for (int r = 0; r < 8; ++r) { ac[r][0] = 0.f; ac[r][1] = 0.f; }
        for (int k = 0; k < 32; ++k) {
            float2 b = *(const float2*)&T1[k * LDSD + j2];
#pragma unroll
            for (int r = 0; r < 8; ++r) {
                float a = Vt[k * LDSD + i0 + r];
                ac[r][0] = fmaf(a, b.x, ac[r][0]);
                ac[r][1] = fmaf(a, b.y, ac[r][1]);
            }
        }
        __syncthreads();
#pragma unroll
        for (int r = 0; r < 8; ++r) {
            float2 w; w.x = ac[r][0]; w.y = ac[r][1];
            *(float2*)&S1[(i0 + r) * LDSD + j2] = w;
        }
    }
    __syncthreads();
    g2l<64>(sqrtm + c * 1024, Vt, tid);
    __syncthreads();
    mmb_nn(Vt, S1, T1, tid); __syncthreads();
    mmb_nn(T1, Vt, X1, tid); __syncthreads();
    float loc = 0.f;
    for (int idx = tid; idx < 1024; idx += 64) {
        int i = idx >> 5, j = idx & 31;
        float d = X1[i * LDSD + j] - bary0[c * 1024 + idx];
        loc += d * d;
    }
#pragma unroll
    for (int off = 32; off > 0; off >>= 1) loc += __shfl_down(loc, off);
    float err2 = __shfl(loc, 0);
    bool keep0 = (err2 < 1e-8f);  // CONV_TOL^2
    for (int idx = tid; idx < 1024; idx += 64) {
        int i = idx >> 5, j = idx & 31;
        bary[c * 1024 + idx] = keep0 ? bary0[c * 1024 + idx] : X1[i * LDSD + j];
    }
}

__global__ void __launch_bounds__(64) k_cholinv(const float* X, float* WtBuf) {
    __shared__ __align__(16) float A[MAT], W[MAT];
    int b = blockIdx.x, tid = threadIdx.x;
    g2l<64>(X + b * 1024, A, tid);
    __syncthreads();
    if (tid < 32) A[tid * LDSD + tid] += 1e-3f;  // CHOL_EPS
    __syncthreads();
    for (int k = 0; k < 32; ++k) {
        if (tid == 0) A[k * LDSD + k] = sqrtf(A[k * LDSD + k]);
        __syncthreads();
        float invd = 1.f / A[k * LDSD + k];
        if (tid > k && tid < 32) A[tid * LDSD + k] *= invd;
        __syncthreads();
        for (int idx = tid; idx < 1024; idx += 64) {
            int i = idx >> 5, j = idx & 31;
            if (i > k && j > k && j <= i) A[i * LDSD + j] -= A[i * LDSD + k] * A[j * LDSD + k];
        }
        __syncthreads();
    }
    // register forward substitution: lane j computes column j of W = L^{-1}
    // fully static unroll: w[k]==0 for k<j makes masking implicit.
    if (tid < 32) {
        const int j = tid;
        float w[32];
#pragma unroll
        for (int i = 0; i < 32; ++i) {
            float acc = (i == j) ? 1.f : 0.f;
#pragma unroll
            for (int k = 0; k < 32; ++k) {
                if (k < i) acc = fmaf(-A[i * LDSD + k], w[k], acc);
            }
            float val = acc * fast_rcp(A[i * LDSD + i]);
            w[i] = (i < j) ? 0.f : val;
            // stage Wt = L^{-T}: Wt[i][j_col] = W[j_col][i]; lane j writes Wlds[j][i] = W[i][j]
            W[j * LDSD + i] = w[i];
        }
    }
    __syncthreads();
    l2g<64>(W, WtBuf + b * 1024, tid);   // WtBuf[r][cc] = W_lds[r][cc] = W[cc][r] = L^{-T}[r][cc]
}

// pairdist: 2 LDS buffers (in-place matmuls), register Jacobi fixed 4 sweeps
__global__ void __launch_bounds__(64) k_pairdist(const float* WtBuf, const float* bary, float* D) {
    __shared__ __align__(16) float Wl[MAT], Bc[MAT];
    int bid = blockIdx.x;
    int b = bid >> 2, cp = bid & 3;
    int tid = threadIdx.x, half = tid >> 5, lh = tid & 31;
    g2l<64>(WtBuf + b * 1024, Wl, tid);
    float m_[32];
    for (int h = 0; h < 2; ++h) {
        __syncthreads();                      // Wl ready / previous extraction done
        g2l<64>(bary + (2 * cp + h) * 1024, Bc, tid);
        __syncthreads();
        // faithful quirk: M = L^{-T} bary L^{-T}
        mmb_nn(Wl, Bc, Bc, tid);              // Y = Wl·bary  (in-place on B)
        __syncthreads();
        mmb_nn_st(Bc, Wl, Bc, tid);           // M = Y·Wl     (staged store into A-alias)
        __syncthreads();
        if (half == h) {
#pragma unroll
            for (int r = 0; r < 32; ++r) {
                int i = r ^ lh;
                int hi = i > lh ? i : lh, lo = i > lh ? lh : i;  // eigvalsh UPLO='L'
                m_[r] = Bc[hi * LDSD + lo];
            }
        }
    }
    rjacobi_fixed(m_, 4);
    float lg = logf(fmaxf(m_[0], EV_EPS));
    float d2 = lg * lg;
#pragma unroll
    for (int off = 16; off > 0; off >>= 1) d2 += __shfl_xor(d2, off, 32);
    if (lh == 0) D[b * NC + 2 * cp + half] = sqrtf(d2);
}

__global__ void k_loss(const float* out, const int* labels, const float* D, int B, float* res) {
    __shared__ float sI[256], sD[256], sC[256];
    int tid = threadIdx.x;
    float aI = 0.f, aD = 0.f, aC = 0.f;
    for (int b = tid; b < B; b += 256) {
        int lb = labels[b];
        const float* ob = out + b * NC;
        float m = ob[0];
#pragma unroll
        for (int j = 1; j < NC; ++j) m = fmaxf(m, ob[j]);
        float se = 0.f;
#pragma unroll
        for (int j = 0; j < NC; ++j) se += expf(ob[j] - m);
        aC += m + logf(se) - ob[lb];
        const float* db = D + b * NC;
        float s = 0.f;
#pragma unroll
        for (int j = 0; j < NC; ++j) s += db[j];
        aI += db[lb];
        aD += s - db[lb];
    }
    sI[tid] = aI; sD[tid] = aD; sC[tid] = aC;
    __syncthreads();
    for (int off = 128; off > 0; off >>= 1) {
        if (tid < off) { sI[tid] += sI[tid + off]; sD[tid] += sD[tid + off]; sC[tid] += sC[tid + off]; }
        __syncthreads();
    }
    if (tid == 0) {
        float intra = 0.001f * sI[0] / (float)B;
        float disp = sD[0] / (float)(B * (NC - 1));
        float ce = sC[0] / (float)B;
        res[0] = intra - 0.001f * disp + ce;
    }
}

extern "C" void kernel_launch(void* const* d_in, const int* in_sizes, int n_in,
                              void* d_out, int out_size, void* d_ws, size_t ws_size,
                              hipStream_t stream) {
    const float* X = (const float*)d_in[0];
    const float* out = (const float*)d_in[1];
    const int* labels = (const int*)d_in[2];
    int B = in_sizes[2];

    float* ws = (float*)d_ws;
    float* bary0    = ws;                 // 8192
    float* sqrtm    = ws + 8192;          // 8192
    float* invsqrtm = ws + 16384;         // 8192
    float* meanT    = ws + 24576;         // 8192
    float* bary     = ws + 32768;         // 8192
    float* D        = ws + 40960;         // B*8 = 16384
    int*   counts   = (int*)(ws + 57344); // 8
    float* big      = ws + 65536;         // B*1024 floats (partials, then T, then Wt)
    float* part2    = ws + 65536 + (size_t)B * 1024;  // NPART*NC*1024 floats

    k_count<<<1, 256, 0, stream>>>(labels, B, counts);
    k_accum_part<<<NPART, 256, 0, stream>>>(X, labels, B, big);
    k_accum_fin<<<NC, 256, 0, stream>>>(big, counts, bary0);
    k_eig_bary0<<<NC, 64, 0, stream>>>(bary0, sqrtm, invsqrtm);
    k_tangent<<<B, 64, 0, stream>>>(X, labels, sqrtm, invsqrtm, big);
    k_accum_part<<<NPART, 256, 0, stream>>>(big, labels, B, part2);
    k_accum_fin<<<NC, 256, 0, stream>>>(part2, counts, meanT);
    k_update<<<NC, 64, 0, stream>>>(meanT, sqrtm, invsqrtm, bary0, bary);
    k_cholinv<<<B, 64, 0, stream>>>(X, big);
    k_pairdist<<<B * 4, 64, 0, stream>>>(big, bary, D);
    k_loss<<<1, 256, 0, stream>>>(out, labels, D, B, (float*)d_out);
}

// Round 7
// 1626.351 us; speedup vs baseline: 2.7726x; 1.0655x over previous
//
#include <hip/hip_runtime.h>
#include <math.h>

#define NC 8
#define NDIM 32
#define LDSD 34            // stride 34: rows 8B-aligned (float2); col access 2-way bank alias (free)
#define MAT (NDIM * LDSD)  // 1088 floats per LDS matrix
#define EV_EPS 1e-10f
#define NPART 32

#if __has_builtin(__builtin_amdgcn_rcpf)
__device__ inline float fast_rcp(float x) { return __builtin_amdgcn_rcpf(x); }
#else
__device__ inline float fast_rcp(float x) { return 1.f / x; }
#endif
#if __has_builtin(__builtin_amdgcn_rsqf)
__device__ inline float fast_rsq(float x) { return __builtin_amdgcn_rsqf(x); }
#else
__device__ inline float fast_rsq(float x) { return 1.f / sqrtf(x); }
#endif

// ---------- round-robin tournament pairing (8-block LDS-Jacobi kernels only) ----------
__device__ inline void rr_pair(int r, int k, int& p, int& q) {
    int a, b;
    if (k == 0) { a = 31; b = r; }
    else { a = (r + k) % 31; b = (r - k + 62) % 31; }
    p = a < b ? a : b;
    q = a < b ? b : a;
}

template <int NT>
__device__ inline void build_pq(ushort* pq, int tid) {
    for (int e = tid; e < 496; e += NT) {
        int r = e >> 4, kk = e & 15;
        int p, q; rr_pair(r, kk, p, q);
        pq[e] = (ushort)(p | (q << 8));
    }
}

template <int NT>
__device__ inline float bsum(float v, float* scratch, int tid) {
#pragma unroll
    for (int off = 32; off > 0; off >>= 1) v += __shfl_down(v, off);
    if constexpr (NT == 64) {
        return __shfl(v, 0);
    } else {
        if ((tid & 63) == 0) scratch[tid >> 6] = v;
        __syncthreads();
        float r = scratch[0] + scratch[1];
        __syncthreads();
        return r;
    }
}

// ---------- 32x32 LDS helpers ----------
template <int NT>
__device__ inline void g2l(const float* g, float* l, int tid) {
    for (int idx2 = tid; idx2 < 512; idx2 += NT) {
        int i = idx2 >> 4, jp = idx2 & 15;
        *(float2*)&l[i * LDSD + 2 * jp] = *(const float2*)&g[i * 32 + 2 * jp];
    }
}
template <int NT>
__device__ inline void l2g(const float* l, float* g, int tid) {
    for (int idx2 = tid; idx2 < 512; idx2 += NT) {
        int i = idx2 >> 4, jp = idx2 & 15;
        *(float2*)&g[i * 32 + 2 * jp] = *(const float2*)&l[i * LDSD + 2 * jp];
    }
}

// ---------- register-tiled LDS matmuls (64 threads; 8-row x 2-col tile/thread) ----------
// C = A * B.  SAFE with C == B (each thread reads only its own B columns).
__device__ inline void mmb_nn(const float* A, const float* B, float* C, int tid) {
    int j2 = (tid & 15) * 2;
    int i0 = (tid >> 4) * 8;
    float2 ac[8];
#pragma unroll
    for (int r = 0; r < 8; ++r) { ac[r].x = 0.f; ac[r].y = 0.f; }
#pragma unroll
    for (int k = 0; k < 32; k += 2) {
        float2 b0 = *(const float2*)&B[k * LDSD + j2];
        float2 b1 = *(const float2*)&B[(k + 1) * LDSD + j2];
#pragma unroll
        for (int r = 0; r < 8; ++r) {
            float2 a = *(const float2*)&A[(i0 + r) * LDSD + k];
            ac[r].x = fmaf(a.x, b0.x, fmaf(a.y, b1.x, ac[r].x));
            ac[r].y = fmaf(a.x, b0.y, fmaf(a.y, b1.y, ac[r].y));
        }
    }
#pragma unroll
    for (int r = 0; r < 8; ++r) *(float2*)&C[(i0 + r) * LDSD + j2] = ac[r];
}
// C = A * B with C aliasing A: accumulate, block-wide barrier, then store.
__device__ inline void mmb_nn_st(const float* A, const float* B, float* C, int tid) {
    int j2 = (tid & 15) * 2;
    int i0 = (tid >> 4) * 8;
    float2 ac[8];
#pragma unroll
    for (int r = 0; r < 8; ++r) { ac[r].x = 0.f; ac[r].y = 0.f; }
#pragma unroll
    for (int k = 0; k < 32; k += 2) {
        float2 b0 = *(const float2*)&B[k * LDSD + j2];
        float2 b1 = *(const float2*)&B[(k + 1) * LDSD + j2];
#pragma unroll
        for (int r = 0; r < 8; ++r) {
            float2 a = *(const float2*)&A[(i0 + r) * LDSD + k];
            ac[r].x = fmaf(a.x, b0.x, fmaf(a.y, b1.x, ac[r].x));
            ac[r].y = fmaf(a.x, b0.y, fmaf(a.y, b1.y, ac[r].y));
        }
    }
    __syncthreads();   // all threads done reading A and B
#pragma unroll
    for (int r = 0; r < 8; ++r) *(float2*)&C[(i0 + r) * LDSD + j2] = ac[r];
}
// gC(global, stride 32) = A * B^T
__device__ inline void mmb_nt_g(const float* A, const float* B, float* gC, int tid) {
    int j2 = (tid & 15) * 2;
    int i0 = (tid >> 4) * 8;
    float2 ac[8];
#pragma unroll
    for (int r = 0; r < 8; ++r) { ac[r].x = 0.f; ac[r].y = 0.f; }
#pragma unroll
    for (int l = 0; l < 32; l += 2) {
        float2 b0 = *(const float2*)&B[j2 * LDSD + l];
        float2 b1 = *(const float2*)&B[(j2 + 1) * LDSD + l];
#pragma unroll
        for (int r = 0; r < 8; ++r) {
            float2 a = *(const float2*)&A[(i0 + r) * LDSD + l];
            ac[r].x = fmaf(a.x, b0.x, fmaf(a.y, b0.y, ac[r].x));
            ac[r].y = fmaf(a.x, b1.x, fmaf(a.y, b1.y, ac[r].y));
        }
    }
#pragma unroll
    for (int r = 0; r < 8; ++r) *(float2*)&gC[(i0 + r) * 32 + j2] = ac[r];
}

// ---------- register-resident XOR-ordered Jacobi, eigenvalues only, fixed sweeps ----------
// Lane lh holds column lh skewed: m_[r] = M[r^lh][lh]; diag = m_[0].
__device__ inline void rjacobi_fixed(float* m_, int nsweep) {
    for (int sweep = 0; sweep < nsweep; ++sweep) {
#pragma unroll
        for (int mm = 1; mm < 32; ++mm) {
            float app = m_[0];
            float aqq = __shfl_xor(app, mm, 32);
            float apq = m_[mm];
            float apqc = __builtin_copysignf(fmaxf(fabsf(apq), 1e-36f), apq);
            float tau = (aqq - app) * 0.5f * fast_rcp(apqc);
            float den = fabsf(tau) + sqrtf(fmaf(tau, tau, 1.f));
            float t = __builtin_copysignf(fast_rcp(den), tau);
            t = (fabsf(apq) > 1e-36f) ? t : 0.f;
            float cc = fast_rsq(fmaf(t, t, 1.f));
            float ss = t * cc;
            // row rotations: in-lane register pairs; coeffs of row r^lh live in lane lh^r
#pragma unroll
            for (int r = 0; r < 32; ++r) {
                if (r < (r ^ mm)) {
                    const int r2 = r ^ mm;
                    float ci = __shfl_xor(cc, r, 32);
                    float si = __shfl_xor(ss, r, 32);
                    float x = m_[r], y = m_[r2];
                    m_[r]  = ci * x - si * y;
                    m_[r2] = ci * y + si * x;
                }
            }
            // column rotations: prefetch ALL partner values (independent DS burst,
            // no read-after-write hazard), then 32 independent FMAs (pack-friendly)
            float o[32];
#pragma unroll
            for (int u = 0; u < 32; ++u) o[u] = __shfl_xor(m_[u ^ mm], mm, 32);
#pragma unroll
            for (int u = 0; u < 32; ++u) m_[u] = fmaf(cc, m_[u], -ss * o[u]);
        }
    }
}

// ---------- LDS parallel Jacobi (8-block kernels only) ----------
template <int NT, bool WANT_V>
__device__ void jacobi32(float* A, float* Vt, float* csn, const ushort* pq, int tid, int max_sweeps) {
    if (WANT_V) {
        for (int idx = tid; idx < 1024; idx += NT) {
            int i = idx >> 5, j = idx & 31;
            Vt[i * LDSD + j] = (i == j) ? 1.f : 0.f;
        }
    }
    float loc = 0.f;
    for (int idx2 = tid; idx2 < 512; idx2 += NT) {
        int i = idx2 >> 4, jp = idx2 & 15;
        float2 v = *(const float2*)&A[i * LDSD + 2 * jp];
        loc += v.x * v.x + v.y * v.y;
    }
    float fro2 = bsum<NT>(loc, csn + 32, tid);
    float tol2 = fro2 * 1e-9f + 1e-30f;
    __syncthreads();

    for (int sweep = 0; sweep < max_sweeps; ++sweep) {
        for (int r = 0; r < 31; ++r) {
            const ushort* pqr = pq + (r << 4);
            if (tid < 16) {
                int e = pqr[tid], p = e & 31, q = e >> 8;
                float apq = A[p * LDSD + q];
                float c = 1.f, s = 0.f;
                if (fabsf(apq) > 1e-36f) {
                    float app = A[p * LDSD + p], aqq = A[q * LDSD + q];
                    float tau = (aqq - app) / (2.f * apq);
                    float t = (tau >= 0.f ? 1.f : -1.f) / (fabsf(tau) + sqrtf(1.f + tau * tau));
                    c = 1.f / sqrtf(1.f + t * t);
                    s = t * c;
                }
                csn[tid] = c; csn[16 + tid] = s;
            }
            __syncthreads();
            for (int item = tid; item < 256; item += NT) {
                int k = item >> 4, g = item & 15;
                int e = pqr[k], p = e & 31, q = e >> 8;
                float c = csn[k], s = csn[16 + k];
                float2 ap = *(float2*)&A[p * LDSD + 2 * g];
                float2 aq = *(float2*)&A[q * LDSD + 2 * g];
                float2 np, nq;
                np.x = c * ap.x - s * aq.x; np.y = c * ap.y - s * aq.y;
                nq.x = s * ap.x + c * aq.x; nq.y = s * ap.y + c * aq.y;
                *(float2*)&A[p * LDSD + 2 * g] = np;
                *(float2*)&A[q * LDSD + 2 * g] = nq;
            }
            __syncthreads();
            for (int item = tid; item < 512; item += NT) {
                int k = item >> 5, i = item & 31;
                int e = pqr[k], p = e & 31, q = e >> 8;
                float c = csn[k], s = csn[16 + k];
                float ap = A[i * LDSD + p], aq = A[i * LDSD + q];
                A[i * LDSD + p] = c * ap - s * aq;
                A[i * LDSD + q] = s * ap + c * aq;
            }
            if (WANT_V) {
                for (int item = tid; item < 256; item += NT) {
                    int k = item >> 4, g = item & 15;
                    int e = pqr[k], p = e & 31, q = e >> 8;
                    float c = csn[k], s = csn[16 + k];
                    float2 vp = *(float2*)&Vt[p * LDSD + 2 * g];
                    float2 vq = *(float2*)&Vt[q * LDSD + 2 * g];
                    float2 np, nq;
                    np.x = c * vp.x - s * vq.x; np.y = c * vp.y - s * vq.y;
                    nq.x = s * vp.x + c * vq.x; nq.y = s * vp.y + c * vq.y;
                    *(float2*)&Vt[p * LDSD + 2 * g] = np;
                    *(float2*)&Vt[q * LDSD + 2 * g] = nq;
                }
            }
            __syncthreads();
        }
        float l2 = 0.f;
        for (int idx2 = tid; idx2 < 512; idx2 += NT) {
            int i = idx2 >> 4, jp = idx2 & 15;
            float2 v = *(const float2*)&A[i * LDSD + 2 * jp];
            if ((i >> 1) == jp) { if (i & 1) v.y = 0.f; else v.x = 0.f; }
            l2 += v.x * v.x + v.y * v.y;
        }
        l2 = bsum<NT>(l2, csn + 32, tid);
        if (l2 <= tol2) break;
    }
    __syncthreads();
}

// ---------- kernels ----------
__global__ void __launch_bounds__(256) k_count(const int* labels, int B, int* counts) {
    __shared__ int h[NC];
    int tid = threadIdx.x;
    if (tid < NC) h[tid] = 0;
    __syncthreads();
    int loc[NC] = {0, 0, 0, 0, 0, 0, 0, 0};
    for (int b = tid; b < B; b += 256) {
        int lb = labels[b];
#pragma unroll
        for (int c = 0; c < NC; ++c) loc[c] += (lb == c) ? 1 : 0;
    }
#pragma unroll
    for (int c = 0; c < NC; ++c) if (loc[c]) atomicAdd(&h[c], loc[c]);
    __syncthreads();
    if (tid < NC) counts[tid] = h[tid];
}

__global__ void __launch_bounds__(256) k_accum_part(const float* src, const int* labels, int B, float* part) {
    int blk = blockIdx.x, tid = threadIdx.x;
    int chunk = (B + NPART - 1) / NPART;
    int b0 = blk * chunk, b1 = b0 + chunk < B ? b0 + chunk : B;
    float acc[NC][4];
#pragma unroll
    for (int c = 0; c < NC; ++c)
#pragma unroll
        for (int e = 0; e < 4; ++e) acc[c][e] = 0.f;
    for (int b = b0; b < b1; ++b) {
        int lb = labels[b];
        float x[4];
#pragma unroll
        for (int e = 0; e < 4; ++e) x[e] = src[b * 1024 + tid + 256 * e];
#pragma unroll
        for (int c = 0; c < NC; ++c) {
            if (lb == c) {
#pragma unroll
                for (int e = 0; e < 4; ++e) acc[c][e] += x[e];
            }
        }
    }
#pragma unroll
    for (int c = 0; c < NC; ++c)
#pragma unroll
        for (int e = 0; e < 4; ++e) part[(blk * NC + c) * 1024 + tid + 256 * e] = acc[c][e];
}

__global__ void __launch_bounds__(256) k_accum_fin(const float* part, const int* counts, float* dst) {
    int c = blockIdx.x, tid = threadIdx.x;
    float acc[4] = {0.f, 0.f, 0.f, 0.f};
    for (int k = 0; k < NPART; ++k) {
#pragma unroll
        for (int e = 0; e < 4; ++e) acc[e] += part[(k * NC + c) * 1024 + tid + 256 * e];
    }
    float inv = 1.f / (float)counts[c];
#pragma unroll
    for (int e = 0; e < 4; ++e) dst[c * 1024 + tid + 256 * e] = acc[e] * inv;
}

__global__ void __launch_bounds__(64) k_eig_bary0(const float* bary0, float* sqrtm, float* invsqrtm) {
    __shared__ __align__(16) float A[MAT], Vt[MAT], T1[MAT];
    __shared__ float csn[36], evs[32];
    __shared__ ushort pq[496];
    int c = blockIdx.x, tid = threadIdx.x;
    build_pq<64>(pq, tid);
    g2l<64>(bary0 + c * 1024, A, tid);
    __syncthreads();
    jacobi32<64, true>(A, Vt, csn, pq, tid, 8);
    if (tid < 32) evs[tid] = sqrtf(fmaxf(A[tid * LDSD + tid], 0.f));
    __syncthreads();
    for (int idx2 = tid; idx2 < 512; idx2 += 64) {
        int i = idx2 >> 4, jp = idx2 & 15;
        float2 v = *(const float2*)&Vt[i * LDSD + 2 * jp];
        float e = evs[i];
        float2 w; w.x = e * v.x; w.y = e * v.y;
        *(float2*)&T1[i * LDSD + 2 * jp] = w;
    }
    __syncthreads();
    {
        int j2 = (tid & 15) * 2, i0 = (tid >> 4) * 8;
        float ac[8][2];
#pragma unroll
        for (int r = 0; r < 8; ++r) { ac[r][0] = 0.f; ac[r][1] = 0.f; }
        for (int k = 0; k < 32; ++k) {
            float2 b = *(const float2*)&T1[k * LDSD + j2];
#pragma unroll
            for (int r = 0; r < 8; ++r) {
                float a = Vt[k * LDSD + i0 + r];
                ac[r][0] = fmaf(a, b.x, ac[r][0]);
                ac[r][1] = fmaf(a, b.y, ac[r][1]);
            }
        }
#pragma unroll
        for (int r = 0; r < 8; ++r) {
            float2 w; w.x = ac[r][0]; w.y = ac[r][1];
            *(float2*)&sqrtm[c * 1024 + (i0 + r) * 32 + j2] = w;
        }
    }
    if (tid < 32) evs[tid] = 1.f / sqrtf(fmaxf(A[tid * LDSD + tid], 1e-30f));
    __syncthreads();
    for (int idx2 = tid; idx2 < 512; idx2 += 64) {
        int i = idx2 >> 4, jp = idx2 & 15;
        float2 v = *(const float2*)&Vt[i * LDSD + 2 * jp];
        float e = evs[i];
        float2 w; w.x = e * v.x; w.y = e * v.y;
        *(float2*)&T1[i * LDSD + 2 * jp] = w;
    }
    __syncthreads();
    {
        int j2 = (tid & 15) * 2, i0 = (tid >> 4) * 8;
        float ac[8][2];
#pragma unroll
        for (int r = 0; r < 8; ++r) { ac[r][0] = 0.f; ac[r][1] = 0.f; }
        for (int k = 0; k < 32; ++k) {
            float2 b = *(const float2*)&T1[k * LDSD + j2];
#pragma unroll
            for (int r = 0; r < 8; ++r) {
                float a = Vt[k * LDSD + i0 + r];
                ac[r][0] = fmaf(a, b.x, ac[r][0]);
                ac[r][1] = fmaf(a, b.y, ac[r][1]);
            }
        }
#pragma unroll
        for (int r = 0; r < 8; ++r) {
            float2 w; w.x = ac[r][0]; w.y = ac[r][1];
            *(float2*)&invsqrtm[c * 1024 + (i0 + r) * 32 + j2] = w;
        }
    }
}

// tangent: 2 LDS buffers; split-role wave; fixed 3 sweeps
__global__ void __launch_bounds__(64) k_tangent(const float* X, const int* labels, const float* sqrtm,
                                                const float* invsqrtm, float* Tbuf) {
    __shared__ __align__(16) float P[MAT], Q[MAT];
    int b = blockIdx.x, tid = threadIdx.x, half = tid >> 5, lh = tid & 31;
    int lb = labels[b];
    g2l<64>(X + b * 1024, P, tid);
    g2l<64>(invsqrtm + lb * 1024, Q, tid);
    __syncthreads();
    mmb_nn(Q, P, P, tid); __syncthreads();   // P = S·X          (in-place on B)
    mmb_nn(P, Q, Q, tid); __syncthreads();   // Q = (S·X)·S = M  (in-place on B)
    g2l<64>(sqrtm + lb * 1024, P, tid);      // P = sqrtm
    __syncthreads();
    float z_[32];
    if (half == 0) {
#pragma unroll
        for (int r = 0; r < 32; ++r) {
            int i = r ^ lh;
            z_[r] = 0.5f * (Q[i * LDSD + lh] + Q[lh * LDSD + i]);   // symmetrized M
        }
    } else {
#pragma unroll
        for (int r = 0; r < 32; ++r) z_[r] = P[(r ^ lh) * LDSD + lh];  // W0 = sqrtm col lh (skew)
    }
    for (int sweep = 0; sweep < 3; ++sweep) {
#pragma unroll
        for (int mm = 1; mm < 32; ++mm) {
            float app = z_[0];
            float aqq = __shfl_xor(app, mm, 32);
            float apq = z_[mm];
            float apqc = __builtin_copysignf(fmaxf(fabsf(apq), 1e-36f), apq);
            float tau = (aqq - app) * 0.5f * fast_rcp(apqc);
            float den = fabsf(tau) + sqrtf(fmaf(tau, tau, 1.f));
            float t = __builtin_copysignf(fast_rcp(den), tau);
            t = (fabsf(apq) > 1e-36f) ? t : 0.f;
            t = __shfl(t, lh, 64);               // half 1 inherits half 0's t
            float cc = fast_rsq(fmaf(t, t, 1.f));
            float ss = t * cc;
            if (half == 0) {                     // row rotations on M only
#pragma unroll
                for (int r = 0; r < 32; ++r) {
                    if (r < (r ^ mm)) {
                        const int r2 = r ^ mm;
                        float ci = __shfl_xor(cc, r, 32);
                        float si = __shfl_xor(ss, r, 32);
                        float x = z_[r], y = z_[r2];
                        z_[r]  = ci * x - si * y;
                        z_[r2] = ci * y + si * x;
                    }
                }
            }
            // col rotations: M (h0) and W (h1) share the stream; prefetch then update
            float o[32];
#pragma unroll
            for (int u = 0; u < 32; ++u) o[u] = __shfl_xor(z_[u ^ mm], mm, 32);
#pragma unroll
            for (int u = 0; u < 32; ++u) z_[u] = fmaf(cc, z_[u], -ss * o[u]);
        }
    }
    float lam = __shfl(z_[0], lh, 64);
    float ev = logf(fmaxf(lam, EV_EPS));
    __syncthreads();                             // extraction reads of P,Q done
    if (half == 1) {
#pragma unroll
        for (int r = 0; r < 32; ++r) {
            float w = z_[r];
            int i = r ^ lh;
            Q[i * LDSD + lh] = w;                // Q = W = sqrtm·V
            P[i * LDSD + lh] = w * ev;           // P = W·diag(log λ)
        }
    }
    __syncthreads();
    mmb_nt_g(P, Q, Tbuf + b * 1024, tid);        // T = W·diag·W^T
}

__global__ void __launch_bounds__(64) k_update(const float* meanT, const float* sqrtm, const float* invsqrtm,
                                               const float* bary0, float* bary) {
    __shared__ __align__(16) float X1[MAT], S1[MAT], T1[MAT], Vt[MAT];
    __shared__ float csn[36], evs[32];
    __shared__ ushort pq[496];
    int c = blockIdx.x, tid = threadIdx.x;
    build_pq<64>(pq, tid);
    g2l<64>(meanT + c * 1024, X1, tid);
    g2l<64>(invsqrtm + c * 1024, S1, tid);
    __syncthreads();
    mmb_nn(S1, X1, T1, tid); __syncthreads();
    mmb_nn(T1, S1, X1, tid); __syncthreads();
    jacobi32<64, true>(X1, Vt, csn, pq, tid, 8);
    // faithful quirk: clamp eigenvalues to >= 1e-10 BEFORE exp
    if (tid < 32) evs[tid] = expf(fmaxf(X1[tid * LDSD + tid], EV_EPS));
    __syncthreads();
    for (int idx2 = tid; idx2 < 512; idx2 += 64) {
        int i = idx2 >> 4, jp = idx2 & 15;
        float2 v = *(const float2*)&Vt[i * LDSD + 2 * jp];
        float e = evs[i];
        float2 w; w.x = e * v.x; w.y = e * v.y;
        *(float2*)&T1[i * LDSD + 2 * jp] = w;
    }
    __syncthreads();
    {
        int j2 = (tid & 15) * 2, i0 = (tid >> 4) * 8;
        float ac[8][2];
#pragma unroll
        for (int r = 0; r < 8; ++r) { ac[r][0] = 0.f; ac[r][1] = 0.f; }
        for (int k = 0; k < 32; ++k) {
            float2 b = *(const float2*)&T1[k * LDSD + j2];
#pragma unroll
            for (int r = 0; r < 8; ++r) {
                float a = Vt[k * LDSD + i0 + r];
                ac[r][0] = fmaf(a, b.x, ac[r][0]);
                ac[r][1] = fmaf(a, b.y, ac[r][1]);
            }
        }
        __syncthreads();
#pragma unroll
        for (int r = 0; r < 8; ++r) {
            float2 w; w.x = ac[r][0]; w.y = ac[r][1];
            *(float2*)&S1[(i0 + r) * LDSD + j2] = w;
        }
    }
    __syncthreads();
    g2l<64>(sqrtm + c * 1024, Vt, tid);
    __syncthreads();
    mmb_nn(Vt, S1, T1, tid); __syncthreads();
    mmb_nn(T1, Vt, X1, tid); __syncthreads();
    float loc = 0.f;
    for (int idx = tid; idx < 1024; idx += 64) {
        int i = idx >> 5, j = idx & 31;
        float d = X1[i * LDSD + j] - bary0[c * 1024 + idx];
        loc += d * d;
    }
#pragma unroll
    for (int off = 32; off > 0; off >>= 1) loc += __shfl_down(loc, off);
    float err2 = __shfl(loc, 0);
    bool keep0 = (err2 < 1e-8f);  // CONV_TOL^2
    for (int idx = tid; idx < 1024; idx += 64) {
        int i = idx >> 5, j = idx & 31;
        bary[c * 1024 + idx] = keep0 ? bary0[c * 1024 + idx] : X1[i * LDSD + j];
    }
}

__global__ void __launch_bounds__(64) k_cholinv(const float* X, float* WtBuf) {
    __shared__ __align__(16) float A[MAT], W[MAT];
    int b = blockIdx.x, tid = threadIdx.x;
    g2l<64>(X + b * 1024, A, tid);
    __syncthreads();
    if (tid < 32) A[tid * LDSD + tid] += 1e-3f;  // CHOL_EPS
    __syncthreads();
    for (int k = 0; k < 32; ++k) {
        if (tid == 0) A[k * LDSD + k] = sqrtf(A[k * LDSD + k]);
        __syncthreads();
        float invd = 1.f / A[k * LDSD + k];
        if (tid > k && tid < 32) A[tid * LDSD + k] *= invd;
        __syncthreads();
        for (int idx = tid; idx < 1024; idx += 64) {
            int i = idx >> 5, j = idx & 31;
            if (i > k && j > k && j <= i) A[i * LDSD + j] -= A[i * LDSD + k] * A[j * LDSD + k];
        }
        __syncthreads();
    }
    // register forward substitution: lane j computes column j of W = L^{-1}
    if (tid < 32) {
        const int j = tid;
        float w[32];
#pragma unroll
        for (int i = 0; i < 32; ++i) {
            float acc = (i == j) ? 1.f : 0.f;
#pragma unroll
            for (int k = 0; k < 32; ++k) {
                if (k < i) acc = fmaf(-A[i * LDSD + k], w[k], acc);
            }
            float val = acc * fast_rcp(A[i * LDSD + i]);
            w[i] = (i < j) ? 0.f : val;
            W[j * LDSD + i] = w[i];
        }
    }
    __syncthreads();
    l2g<64>(W, WtBuf + b * 1024, tid);   // WtBuf = L^{-T} row-major
}

// pairdist: 2 LDS buffers (in-place matmuls), register Jacobi fixed 3 sweeps
__global__ void __launch_bounds__(64) k_pairdist(const float* WtBuf, const float* bary, float* D) {
    __shared__ __align__(16) float Wl[MAT], Bc[MAT];
    int bid = blockIdx.x;
    int b = bid >> 2, cp = bid & 3;
    int tid = threadIdx.x, half = tid >> 5, lh = tid & 31;
    g2l<64>(WtBuf + b * 1024, Wl, tid);
    float m_[32];
    for (int h = 0; h < 2; ++h) {
        __syncthreads();                      // Wl ready / previous extraction done
        g2l<64>(bary + (2 * cp + h) * 1024, Bc, tid);
        __syncthreads();
        // faithful quirk: M = L^{-T} bary L^{-T}
        mmb_nn(Wl, Bc, Bc, tid);              // Y = Wl·bary  (in-place on B)
        __syncthreads();
        mmb_nn_st(Bc, Wl, Bc, tid);           // M = Y·Wl     (staged store into A-alias)
        __syncthreads();
        if (half == h) {
#pragma unroll
            for (int r = 0; r < 32; ++r) {
                int i = r ^ lh;
                int hi = i > lh ? i : lh, lo = i > lh ? lh : i;  // eigvalsh UPLO='L'
                m_[r] = Bc[hi * LDSD + lo];
            }
        }
    }
    rjacobi_fixed(m_, 3);
    float lg = logf(fmaxf(m_[0], EV_EPS));
    float d2 = lg * lg;
#pragma unroll
    for (int off = 16; off > 0; off >>= 1) d2 += __shfl_xor(d2, off, 32);
    if (lh == 0) D[b * NC + 2 * cp + half] = sqrtf(d2);
}

__global__ void k_loss(const float* out, const int* labels, const float* D, int B, float* res) {
    __shared__ float sI[256], sD[256], sC[256];
    int tid = threadIdx.x;
    float aI = 0.f, aD = 0.f, aC = 0.f;
    for (int b = tid; b < B; b += 256) {
        int lb = labels[b];
        const float* ob = out + b * NC;
        float m = ob[0];
#pragma unroll
        for (int j = 1; j < NC; ++j) m = fmaxf(m, ob[j]);
        float se = 0.f;
#pragma unroll
        for (int j = 0; j < NC; ++j) se += expf(ob[j] - m);
        aC += m + logf(se) - ob[lb];
        const float* db = D + b * NC;
        float s = 0.f;
#pragma unroll
        for (int j = 0; j < NC; ++j) s += db[j];
        aI += db[lb];
        aD += s - db[lb];
    }
    sI[tid] = aI; sD[tid] = aD; sC[tid] = aC;
    __syncthreads();
    for (int off = 128; off > 0; off >>= 1) {
        if (tid < off) { sI[tid] += sI[tid + off]; sD[tid] += sD[tid + off]; sC[tid] += sC[tid + off]; }
        __syncthreads();
    }
    if (tid == 0) {
        float intra = 0.001f * sI[0] / (float)B;
        float disp = sD[0] / (float)(B * (NC - 1));
        float ce = sC[0] / (float)B;
        res[0] = intra - 0.001f * disp + ce;
    }
}

extern "C" void kernel_launch(void* const* d_in, const int* in_sizes, int n_in,
                              void* d_out, int out_size, void* d_ws, size_t ws_size,
                              hipStream_t stream) {
    const float* X = (const float*)d_in[0];
    const float* out = (const float*)d_in[1];
    const int* labels = (const int*)d_in[2];
    int B = in_sizes[2];

    float* ws = (float*)d_ws;
    float* bary0    = ws;                 // 8192
    float* sqrtm    = ws + 8192;          // 8192
    float* invsqrtm = ws + 16384;         // 8192
    float* meanT    = ws + 24576;         // 8192
    float* bary     = ws + 32768;         // 8192
    float* D        = ws + 40960;         // B*8 = 16384
    int*   counts   = (int*)(ws + 57344); // 8
    float* big      = ws + 65536;         // B*1024 floats (partials, then T, then Wt)
    float* part2    = ws + 65536 + (size_t)B * 1024;  // NPART*NC*1024 floats

    k_count<<<1, 256, 0, stream>>>(labels, B, counts);
    k_accum_part<<<NPART, 256, 0, stream>>>(X, labels, B, big);
    k_accum_fin<<<NC, 256, 0, stream>>>(big, counts, bary0);
    k_eig_bary0<<<NC, 64, 0, stream>>>(bary0, sqrtm, invsqrtm);
    k_tangent<<<B, 64, 0, stream>>>(X, labels, sqrtm, invsqrtm, big);
    k_accum_part<<<NPART, 256, 0, stream>>>(big, labels, B, part2);
    k_accum_fin<<<NC, 256, 0, stream>>>(part2, counts, meanT);
    k_update<<<NC, 64, 0, stream>>>(meanT, sqrtm, invsqrtm, bary0, bary);
    k_cholinv<<<B, 64, 0, stream>>>(X, big);
    k_pairdist<<<B * 4, 64, 0, stream>>>(big, bary, D);
    k_loss<<<1, 256, 0, stream>>>(out, labels, D, B, (float*)d_out);
}

// Round 8
// 1406.924 us; speedup vs baseline: 3.2051x; 1.1560x over previous
//
#include <hip/hip_runtime.h>
#include <math.h>

#define NC 8
#define NDIM 32
#define LDSD 34            // stride 34: rows 8B-aligned (float2); col access 2-way bank alias (free)
#define MAT (NDIM * LDSD)  // 1088 floats per LDS matrix
#define EV_EPS 1e-10f
#define NPART 32

#if __has_builtin(__builtin_amdgcn_rcpf)
__device__ inline float fast_rcp(float x) { return __builtin_amdgcn_rcpf(x); }
#else
__device__ inline float fast_rcp(float x) { return 1.f / x; }
#endif
#if __has_builtin(__builtin_amdgcn_rsqf)
__device__ inline float fast_rsq(float x) { return __builtin_amdgcn_rsqf(x); }
#else
__device__ inline float fast_rsq(float x) { return 1.f / sqrtf(x); }
#endif

// ---------- round-robin tournament pairing (8-block LDS-Jacobi kernels only) ----------
__device__ inline void rr_pair(int r, int k, int& p, int& q) {
    int a, b;
    if (k == 0) { a = 31; b = r; }
    else { a = (r + k) % 31; b = (r - k + 62) % 31; }
    p = a < b ? a : b;
    q = a < b ? b : a;
}

template <int NT>
__device__ inline void build_pq(ushort* pq, int tid) {
    for (int e = tid; e < 496; e += NT) {
        int r = e >> 4, kk = e & 15;
        int p, q; rr_pair(r, kk, p, q);
        pq[e] = (ushort)(p | (q << 8));
    }
}

template <int NT>
__device__ inline float bsum(float v, float* scratch, int tid) {
#pragma unroll
    for (int off = 32; off > 0; off >>= 1) v += __shfl_down(v, off);
    if constexpr (NT == 64) {
        return __shfl(v, 0);
    } else {
        if ((tid & 63) == 0) scratch[tid >> 6] = v;
        __syncthreads();
        float r = scratch[0] + scratch[1];
        __syncthreads();
        return r;
    }
}

// ---------- 32x32 LDS helpers ----------
template <int NT>
__device__ inline void g2l(const float* g, float* l, int tid) {
    for (int idx2 = tid; idx2 < 512; idx2 += NT) {
        int i = idx2 >> 4, jp = idx2 & 15;
        *(float2*)&l[i * LDSD + 2 * jp] = *(const float2*)&g[i * 32 + 2 * jp];
    }
}
template <int NT>
__device__ inline void l2g(const float* l, float* g, int tid) {
    for (int idx2 = tid; idx2 < 512; idx2 += NT) {
        int i = idx2 >> 4, jp = idx2 & 15;
        *(float2*)&g[i * 32 + 2 * jp] = *(const float2*)&l[i * LDSD + 2 * jp];
    }
}

// ---------- register-tiled LDS matmuls (64 threads; 8-row x 2-col tile/thread) ----------
// C = A * B.  SAFE with C == B (each thread reads only its own B columns).
__device__ inline void mmb_nn(const float* A, const float* B, float* C, int tid) {
    int j2 = (tid & 15) * 2;
    int i0 = (tid >> 4) * 8;
    float2 ac[8];
#pragma unroll
    for (int r = 0; r < 8; ++r) { ac[r].x = 0.f; ac[r].y = 0.f; }
#pragma unroll
    for (int k = 0; k < 32; k += 2) {
        float2 b0 = *(const float2*)&B[k * LDSD + j2];
        float2 b1 = *(const float2*)&B[(k + 1) * LDSD + j2];
#pragma unroll
        for (int r = 0; r < 8; ++r) {
            float2 a = *(const float2*)&A[(i0 + r) * LDSD + k];
            ac[r].x = fmaf(a.x, b0.x, fmaf(a.y, b1.x, ac[r].x));
            ac[r].y = fmaf(a.x, b0.y, fmaf(a.y, b1.y, ac[r].y));
        }
    }
#pragma unroll
    for (int r = 0; r < 8; ++r) *(float2*)&C[(i0 + r) * LDSD + j2] = ac[r];
}
// C = A * B with C aliasing A: accumulate, block-wide barrier, then store.
__device__ inline void mmb_nn_st(const float* A, const float* B, float* C, int tid) {
    int j2 = (tid & 15) * 2;
    int i0 = (tid >> 4) * 8;
    float2 ac[8];
#pragma unroll
    for (int r = 0; r < 8; ++r) { ac[r].x = 0.f; ac[r].y = 0.f; }
#pragma unroll
    for (int k = 0; k < 32; k += 2) {
        float2 b0 = *(const float2*)&B[k * LDSD + j2];
        float2 b1 = *(const float2*)&B[(k + 1) * LDSD + j2];
#pragma unroll
        for (int r = 0; r < 8; ++r) {
            float2 a = *(const float2*)&A[(i0 + r) * LDSD + k];
            ac[r].x = fmaf(a.x, b0.x, fmaf(a.y, b1.x, ac[r].x));
            ac[r].y = fmaf(a.x, b0.y, fmaf(a.y, b1.y, ac[r].y));
        }
    }
    __syncthreads();   // all threads done reading A and B
#pragma unroll
    for (int r = 0; r < 8; ++r) *(float2*)&C[(i0 + r) * LDSD + j2] = ac[r];
}
// gC(global, stride 32) = A * B^T
__device__ inline void mmb_nt_g(const float* A, const float* B, float* gC, int tid) {
    int j2 = (tid & 15) * 2;
    int i0 = (tid >> 4) * 8;
    float2 ac[8];
#pragma unroll
    for (int r = 0; r < 8; ++r) { ac[r].x = 0.f; ac[r].y = 0.f; }
#pragma unroll
    for (int l = 0; l < 32; l += 2) {
        float2 b0 = *(const float2*)&B[j2 * LDSD + l];
        float2 b1 = *(const float2*)&B[(j2 + 1) * LDSD + l];
#pragma unroll
        for (int r = 0; r < 8; ++r) {
            float2 a = *(const float2*)&A[(i0 + r) * LDSD + l];
            ac[r].x = fmaf(a.x, b0.x, fmaf(a.y, b0.y, ac[r].x));
            ac[r].y = fmaf(a.x, b1.x, fmaf(a.y, b1.y, ac[r].y));
        }
    }
#pragma unroll
    for (int r = 0; r < 8; ++r) *(float2*)&gC[(i0 + r) * 32 + j2] = ac[r];
}

// ---------- register-resident XOR-ordered Jacobi, eigenvalues only, fixed sweeps ----------
// Lane lh holds column lh skewed: m_[r] = M[r^lh][lh]; diag = m_[0].
// Row pass: refetch t only (1 shuffle) and rebuild c,s with rsq (trans pipe).
// Col pass: prefetch all partners (independent DS burst) then independent FMAs.
__device__ inline void rjacobi_fixed(float* m_, int nsweep) {
    for (int sweep = 0; sweep < nsweep; ++sweep) {
#pragma unroll
        for (int mm = 1; mm < 32; ++mm) {
            float app = m_[0];
            float aqq = __shfl_xor(app, mm, 32);
            float apq = m_[mm];
            float apqc = __builtin_copysignf(fmaxf(fabsf(apq), 1e-36f), apq);
            float tau = (aqq - app) * 0.5f * fast_rcp(apqc);
            float den = fabsf(tau) + sqrtf(fmaf(tau, tau, 1.f));
            float t = __builtin_copysignf(fast_rcp(den), tau);
            t = (fabsf(apq) > 1e-36f) ? t : 0.f;
            float cc = fast_rsq(fmaf(t, t, 1.f));
            float ss = t * cc;
#pragma unroll
            for (int r = 0; r < 32; ++r) {
                if (r < (r ^ mm)) {
                    const int r2 = r ^ mm;
                    float ti = __shfl_xor(t, r, 32);
                    float ci = fast_rsq(fmaf(ti, ti, 1.f));
                    float si = ti * ci;
                    float x = m_[r], y = m_[r2];
                    m_[r]  = ci * x - si * y;
                    m_[r2] = ci * y + si * x;
                }
            }
            float o[32];
#pragma unroll
            for (int u = 0; u < 32; ++u) o[u] = __shfl_xor(m_[u ^ mm], mm, 32);
#pragma unroll
            for (int u = 0; u < 32; ++u) m_[u] = fmaf(cc, m_[u], -ss * o[u]);
        }
    }
}

// ---------- LDS parallel Jacobi (8-block kernels only) ----------
template <int NT, bool WANT_V>
__device__ void jacobi32(float* A, float* Vt, float* csn, const ushort* pq, int tid, int max_sweeps) {
    if (WANT_V) {
        for (int idx = tid; idx < 1024; idx += NT) {
            int i = idx >> 5, j = idx & 31;
            Vt[i * LDSD + j] = (i == j) ? 1.f : 0.f;
        }
    }
    float loc = 0.f;
    for (int idx2 = tid; idx2 < 512; idx2 += NT) {
        int i = idx2 >> 4, jp = idx2 & 15;
        float2 v = *(const float2*)&A[i * LDSD + 2 * jp];
        loc += v.x * v.x + v.y * v.y;
    }
    float fro2 = bsum<NT>(loc, csn + 32, tid);
    float tol2 = fro2 * 1e-9f + 1e-30f;
    __syncthreads();

    for (int sweep = 0; sweep < max_sweeps; ++sweep) {
        for (int r = 0; r < 31; ++r) {
            const ushort* pqr = pq + (r << 4);
            if (tid < 16) {
                int e = pqr[tid], p = e & 31, q = e >> 8;
                float apq = A[p * LDSD + q];
                float c = 1.f, s = 0.f;
                if (fabsf(apq) > 1e-36f) {
                    float app = A[p * LDSD + p], aqq = A[q * LDSD + q];
                    float tau = (aqq - app) / (2.f * apq);
                    float t = (tau >= 0.f ? 1.f : -1.f) / (fabsf(tau) + sqrtf(1.f + tau * tau));
                    c = 1.f / sqrtf(1.f + t * t);
                    s = t * c;
                }
                csn[tid] = c; csn[16 + tid] = s;
            }
            __syncthreads();
            for (int item = tid; item < 256; item += NT) {
                int k = item >> 4, g = item & 15;
                int e = pqr[k], p = e & 31, q = e >> 8;
                float c = csn[k], s = csn[16 + k];
                float2 ap = *(float2*)&A[p * LDSD + 2 * g];
                float2 aq = *(float2*)&A[q * LDSD + 2 * g];
                float2 np, nq;
                np.x = c * ap.x - s * aq.x; np.y = c * ap.y - s * aq.y;
                nq.x = s * ap.x + c * aq.x; nq.y = s * ap.y + c * aq.y;
                *(float2*)&A[p * LDSD + 2 * g] = np;
                *(float2*)&A[q * LDSD + 2 * g] = nq;
            }
            __syncthreads();
            for (int item = tid; item < 512; item += NT) {
                int k = item >> 5, i = item & 31;
                int e = pqr[k], p = e & 31, q = e >> 8;
                float c = csn[k], s = csn[16 + k];
                float ap = A[i * LDSD + p], aq = A[i * LDSD + q];
                A[i * LDSD + p] = c * ap - s * aq;
                A[i * LDSD + q] = s * ap + c * aq;
            }
            if (WANT_V) {
                for (int item = tid; item < 256; item += NT) {
                    int k = item >> 4, g = item & 15;
                    int e = pqr[k], p = e & 31, q = e >> 8;
                    float c = csn[k], s = csn[16 + k];
                    float2 vp = *(float2*)&Vt[p * LDSD + 2 * g];
                    float2 vq = *(float2*)&Vt[q * LDSD + 2 * g];
                    float2 np, nq;
                    np.x = c * vp.x - s * vq.x; np.y = c * vp.y - s * vq.y;
                    nq.x = s * vp.x + c * vq.x; nq.y = s * vp.y + c * vq.y;
                    *(float2*)&Vt[p * LDSD + 2 * g] = np;
                    *(float2*)&Vt[q * LDSD + 2 * g] = nq;
                }
            }
            __syncthreads();
        }
        float l2 = 0.f;
        for (int idx2 = tid; idx2 < 512; idx2 += NT) {
            int i = idx2 >> 4, jp = idx2 & 15;
            float2 v = *(const float2*)&A[i * LDSD + 2 * jp];
            if ((i >> 1) == jp) { if (i & 1) v.y = 0.f; else v.x = 0.f; }
            l2 += v.x * v.x + v.y * v.y;
        }
        l2 = bsum<NT>(l2, csn + 32, tid);
        if (l2 <= tol2) break;
    }
    __syncthreads();
}

// ---------- kernels ----------
__global__ void __launch_bounds__(256) k_count(const int* labels, int B, int* counts) {
    __shared__ int h[NC];
    int tid = threadIdx.x;
    if (tid < NC) h[tid] = 0;
    __syncthreads();
    int loc[NC] = {0, 0, 0, 0, 0, 0, 0, 0};
    for (int b = tid; b < B; b += 256) {
        int lb = labels[b];
#pragma unroll
        for (int c = 0; c < NC; ++c) loc[c] += (lb == c) ? 1 : 0;
    }
#pragma unroll
    for (int c = 0; c < NC; ++c) if (loc[c]) atomicAdd(&h[c], loc[c]);
    __syncthreads();
    if (tid < NC) counts[tid] = h[tid];
}

__global__ void __launch_bounds__(256) k_accum_part(const float* src, const int* labels, int B, float* part) {
    int blk = blockIdx.x, tid = threadIdx.x;
    int chunk = (B + NPART - 1) / NPART;
    int b0 = blk * chunk, b1 = b0 + chunk < B ? b0 + chunk : B;
    float acc[NC][4];
#pragma unroll
    for (int c = 0; c < NC; ++c)
#pragma unroll
        for (int e = 0; e < 4; ++e) acc[c][e] = 0.f;
    for (int b = b0; b < b1; ++b) {
        int lb = labels[b];
        float x[4];
#pragma unroll
        for (int e = 0; e < 4; ++e) x[e] = src[b * 1024 + tid + 256 * e];
#pragma unroll
        for (int c = 0; c < NC; ++c) {
            if (lb == c) {
#pragma unroll
                for (int e = 0; e < 4; ++e) acc[c][e] += x[e];
            }
        }
    }
#pragma unroll
    for (int c = 0; c < NC; ++c)
#pragma unroll
        for (int e = 0; e < 4; ++e) part[(blk * NC + c) * 1024 + tid + 256 * e] = acc[c][e];
}

__global__ void __launch_bounds__(256) k_accum_fin(const float* part, const int* counts, float* dst) {
    int c = blockIdx.x, tid = threadIdx.x;
    float acc[4] = {0.f, 0.f, 0.f, 0.f};
    for (int k = 0; k < NPART; ++k) {
#pragma unroll
        for (int e = 0; e < 4; ++e) acc[e] += part[(k * NC + c) * 1024 + tid + 256 * e];
    }
    float inv = 1.f / (float)counts[c];
#pragma unroll
    for (int e = 0; e < 4; ++e) dst[c * 1024 + tid + 256 * e] = acc[e] * inv;
}

__global__ void __launch_bounds__(64) k_eig_bary0(const float* bary0, float* sqrtm, float* invsqrtm) {
    __shared__ __align__(16) float A[MAT], Vt[MAT], T1[MAT];
    __shared__ float csn[36], evs[32];
    __shared__ ushort pq[496];
    int c = blockIdx.x, tid = threadIdx.x;
    build_pq<64>(pq, tid);
    g2l<64>(bary0 + c * 1024, A, tid);
    __syncthreads();
    jacobi32<64, true>(A, Vt, csn, pq, tid, 8);
    if (tid < 32) evs[tid] = sqrtf(fmaxf(A[tid * LDSD + tid], 0.f));
    __syncthreads();
    for (int idx2 = tid; idx2 < 512; idx2 += 64) {
        int i = idx2 >> 4, jp = idx2 & 15;
        float2 v = *(const float2*)&Vt[i * LDSD + 2 * jp];
        float e = evs[i];
        float2 w; w.x = e * v.x; w.y = e * v.y;
        *(float2*)&T1[i * LDSD + 2 * jp] = w;
    }
    __syncthreads();
    {
        int j2 = (tid & 15) * 2, i0 = (tid >> 4) * 8;
        float ac[8][2];
#pragma unroll
        for (int r = 0; r < 8; ++r) { ac[r][0] = 0.f; ac[r][1] = 0.f; }
        for (int k = 0; k < 32; ++k) {
            float2 b = *(const float2*)&T1[k * LDSD + j2];
#pragma unroll
            for (int r = 0; r < 8; ++r) {
                float a = Vt[k * LDSD + i0 + r];
                ac[r][0] = fmaf(a, b.x, ac[r][0]);
                ac[r][1] = fmaf(a, b.y, ac[r][1]);
            }
        }
#pragma unroll
        for (int r = 0; r < 8; ++r) {
            float2 w; w.x = ac[r][0]; w.y = ac[r][1];
            *(float2*)&sqrtm[c * 1024 + (i0 + r) * 32 + j2] = w;
        }
    }
    if (tid < 32) evs[tid] = 1.f / sqrtf(fmaxf(A[tid * LDSD + tid], 1e-30f));
    __syncthreads();
    for (int idx2 = tid; idx2 < 512; idx2 += 64) {
        int i = idx2 >> 4, jp = idx2 & 15;
        float2 v = *(const float2*)&Vt[i * LDSD + 2 * jp];
        float e = evs[i];
        float2 w; w.x = e * v.x; w.y = e * v.y;
        *(float2*)&T1[i * LDSD + 2 * jp] = w;
    }
    __syncthreads();
    {
        int j2 = (tid & 15) * 2, i0 = (tid >> 4) * 8;
        float ac[8][2];
#pragma unroll
        for (int r = 0; r < 8; ++r) { ac[r][0] = 0.f; ac[r][1] = 0.f; }
        for (int k = 0; k < 32; ++k) {
            float2 b = *(const float2*)&T1[k * LDSD + j2];
#pragma unroll
            for (int r = 0; r < 8; ++r) {
                float a = Vt[k * LDSD + i0 + r];
                ac[r][0] = fmaf(a, b.x, ac[r][0]);
                ac[r][1] = fmaf(a, b.y, ac[r][1]);
            }
        }
#pragma unroll
        for (int r = 0; r < 8; ++r) {
            float2 w; w.x = ac[r][0]; w.y = ac[r][1];
            *(float2*)&invsqrtm[c * 1024 + (i0 + r) * 32 + j2] = w;
        }
    }
}

// tangent: 2 LDS buffers; split-role wave; fixed 3 sweeps; t-refetch rows
__global__ void __launch_bounds__(64) k_tangent(const float* X, const int* labels, const float* sqrtm,
                                                const float* invsqrtm, float* Tbuf) {
    __shared__ __align__(16) float P[MAT], Q[MAT];
    int b = blockIdx.x, tid = threadIdx.x, half = tid >> 5, lh = tid & 31;
    int lb = labels[b];
    g2l<64>(X + b * 1024, P, tid);
    g2l<64>(invsqrtm + lb * 1024, Q, tid);
    __syncthreads();
    mmb_nn(Q, P, P, tid); __syncthreads();   // P = S·X          (in-place on B)
    mmb_nn(P, Q, Q, tid); __syncthreads();   // Q = (S·X)·S = M  (in-place on B)
    g2l<64>(sqrtm + lb * 1024, P, tid);      // P = sqrtm
    __syncthreads();
    float z_[32];
    if (half == 0) {
#pragma unroll
        for (int r = 0; r < 32; ++r) {
            int i = r ^ lh;
            z_[r] = 0.5f * (Q[i * LDSD + lh] + Q[lh * LDSD + i]);   // symmetrized M
        }
    } else {
#pragma unroll
        for (int r = 0; r < 32; ++r) z_[r] = P[(r ^ lh) * LDSD + lh];  // W0 = sqrtm col lh (skew)
    }
    for (int sweep = 0; sweep < 3; ++sweep) {
#pragma unroll
        for (int mm = 1; mm < 32; ++mm) {
            float app = z_[0];
            float aqq = __shfl_xor(app, mm, 32);
            float apq = z_[mm];
            float apqc = __builtin_copysignf(fmaxf(fabsf(apq), 1e-36f), apq);
            float tau = (aqq - app) * 0.5f * fast_rcp(apqc);
            float den = fabsf(tau) + sqrtf(fmaf(tau, tau, 1.f));
            float t = __builtin_copysignf(fast_rcp(den), tau);
            t = (fabsf(apq) > 1e-36f) ? t : 0.f;
            t = __shfl(t, lh, 64);               // half 1 inherits half 0's t
            float cc = fast_rsq(fmaf(t, t, 1.f));
            float ss = t * cc;
            if (half == 0) {                     // row rotations on M only (t-refetch)
#pragma unroll
                for (int r = 0; r < 32; ++r) {
                    if (r < (r ^ mm)) {
                        const int r2 = r ^ mm;
                        float ti = __shfl_xor(t, r, 32);
                        float ci = fast_rsq(fmaf(ti, ti, 1.f));
                        float si = ti * ci;
                        float x = z_[r], y = z_[r2];
                        z_[r]  = ci * x - si * y;
                        z_[r2] = ci * y + si * x;
                    }
                }
            }
            // col rotations: M (h0) and W (h1) share the stream; prefetch then update
            float o[32];
#pragma unroll
            for (int u = 0; u < 32; ++u) o[u] = __shfl_xor(z_[u ^ mm], mm, 32);
#pragma unroll
            for (int u = 0; u < 32; ++u) z_[u] = fmaf(cc, z_[u], -ss * o[u]);
        }
    }
    float lam = __shfl(z_[0], lh, 64);
    float ev = logf(fmaxf(lam, EV_EPS));
    __syncthreads();                             // extraction reads of P,Q done
    if (half == 1) {
#pragma unroll
        for (int r = 0; r < 32; ++r) {
            float w = z_[r];
            int i = r ^ lh;
            Q[i * LDSD + lh] = w;                // Q = W = sqrtm·V
            P[i * LDSD + lh] = w * ev;           // P = W·diag(log λ)
        }
    }
    __syncthreads();
    mmb_nt_g(P, Q, Tbuf + b * 1024, tid);        // T = W·diag·W^T
}

__global__ void __launch_bounds__(64) k_update(const float* meanT, const float* sqrtm, const float* invsqrtm,
                                               const float* bary0, float* bary) {
    __shared__ __align__(16) float X1[MAT], S1[MAT], T1[MAT], Vt[MAT];
    __shared__ float csn[36], evs[32];
    __shared__ ushort pq[496];
    int c = blockIdx.x, tid = threadIdx.x;
    build_pq<64>(pq, tid);
    g2l<64>(meanT + c * 1024, X1, tid);
    g2l<64>(invsqrtm + c * 1024, S1, tid);
    __syncthreads();
    mmb_nn(S1, X1, T1, tid); __syncthreads();
    mmb_nn(T1, S1, X1, tid); __syncthreads();
    jacobi32<64, true>(X1, Vt, csn, pq, tid, 8);
    // faithful quirk: clamp eigenvalues to >= 1e-10 BEFORE exp
    if (tid < 32) evs[tid] = expf(fmaxf(X1[tid * LDSD + tid], EV_EPS));
    __syncthreads();
    for (int idx2 = tid; idx2 < 512; idx2 += 64) {
        int i = idx2 >> 4, jp = idx2 & 15;
        float2 v = *(const float2*)&Vt[i * LDSD + 2 * jp];
        float e = evs[i];
        float2 w; w.x = e * v.x; w.y = e * v.y;
        *(float2*)&T1[i * LDSD + 2 * jp] = w;
    }
    __syncthreads();
    {
        int j2 = (tid & 15) * 2, i0 = (tid >> 4) * 8;
        float ac[8][2];
#pragma unroll
        for (int r = 0; r < 8; ++r) { ac[r][0] = 0.f; ac[r][1] = 0.f; }
        for (int k = 0; k < 32; ++k) {
            float2 b = *(const float2*)&T1[k * LDSD + j2];
#pragma unroll
            for (int r = 0; r < 8; ++r) {
                float a = Vt[k * LDSD + i0 + r];
                ac[r][0] = fmaf(a, b.x, ac[r][0]);
                ac[r][1] = fmaf(a, b.y, ac[r][1]);
            }
        }
        __syncthreads();
#pragma unroll
        for (int r = 0; r < 8; ++r) {
            float2 w; w.x = ac[r][0]; w.y = ac[r][1];
            *(float2*)&S1[(i0 + r) * LDSD + j2] = w;
        }
    }
    __syncthreads();
    g2l<64>(sqrtm + c * 1024, Vt, tid);
    __syncthreads();
    mmb_nn(Vt, S1, T1, tid); __syncthreads();
    mmb_nn(T1, Vt, X1, tid); __syncthreads();
    float loc = 0.f;
    for (int idx = tid; idx < 1024; idx += 64) {
        int i = idx >> 5, j = idx & 31;
        float d = X1[i * LDSD + j] - bary0[c * 1024 + idx];
        loc += d * d;
    }
#pragma unroll
    for (int off = 32; off > 0; off >>= 1) loc += __shfl_down(loc, off);
    float err2 = __shfl(loc, 0);
    bool keep0 = (err2 < 1e-8f);  // CONV_TOL^2
    for (int idx = tid; idx < 1024; idx += 64) {
        int i = idx >> 5, j = idx & 31;
        bary[c * 1024 + idx] = keep0 ? bary0[c * 1024 + idx] : X1[i * LDSD + j];
    }
}

__global__ void __launch_bounds__(64) k_cholinv(const float* X, float* WtBuf) {
    __shared__ __align__(16) float A[MAT], W[MAT];
    int b = blockIdx.x, tid = threadIdx.x;
    g2l<64>(X + b * 1024, A, tid);
    __syncthreads();
    if (tid < 32) A[tid * LDSD + tid] += 1e-3f;  // CHOL_EPS
    __syncthreads();
    for (int k = 0; k < 32; ++k) {
        if (tid == 0) A[k * LDSD + k] = sqrtf(A[k * LDSD + k]);
        __syncthreads();
        float invd = 1.f / A[k * LDSD + k];
        if (tid > k && tid < 32) A[tid * LDSD + k] *= invd;
        __syncthreads();
        for (int idx = tid; idx < 1024; idx += 64) {
            int i = idx >> 5, j = idx & 31;
            if (i > k && j > k && j <= i) A[i * LDSD + j] -= A[i * LDSD + k] * A[j * LDSD + k];
        }
        __syncthreads();
    }
    // register forward substitution: lane j computes column j of W = L^{-1}
    if (tid < 32) {
        const int j = tid;
        float w[32];
#pragma unroll
        for (int i = 0; i < 32; ++i) {
            float acc = (i == j) ? 1.f : 0.f;
#pragma unroll
            for (int k = 0; k < 32; ++k) {
                if (k < i) acc = fmaf(-A[i * LDSD + k], w[k], acc);
            }
            float val = acc * fast_rcp(A[i * LDSD + i]);
            w[i] = (i < j) ? 0.f : val;
            W[j * LDSD + i] = w[i];
        }
    }
    __syncthreads();
    l2g<64>(W, WtBuf + b * 1024, tid);   // WtBuf = L^{-T} row-major
}

// pairdist: 2 LDS buffers (in-place matmuls), register Jacobi fixed 2 sweeps
__global__ void __launch_bounds__(64) k_pairdist(const float* WtBuf, const float* bary, float* D) {
    __shared__ __align__(16) float Wl[MAT], Bc[MAT];
    int bid = blockIdx.x;
    int b = bid >> 2, cp = bid & 3;
    int tid = threadIdx.x, half = tid >> 5, lh = tid & 31;
    g2l<64>(WtBuf + b * 1024, Wl, tid);
    float m_[32];
    for (int h = 0; h < 2; ++h) {
        __syncthreads();                      // Wl ready / previous extraction done
        g2l<64>(bary + (2 * cp + h) * 1024, Bc, tid);
        __syncthreads();
        // faithful quirk: M = L^{-T} bary L^{-T}
        mmb_nn(Wl, Bc, Bc, tid);              // Y = Wl·bary  (in-place on B)
        __syncthreads();
        mmb_nn_st(Bc, Wl, Bc, tid);           // M = Y·Wl     (staged store into A-alias)
        __syncthreads();
        if (half == h) {
#pragma unroll
            for (int r = 0; r < 32; ++r) {
                int i = r ^ lh;
                int hi = i > lh ? i : lh, lo = i > lh ? lh : i;  // eigvalsh UPLO='L'
                m_[r] = Bc[hi * LDSD + lo];
            }
        }
    }
    rjacobi_fixed(m_, 2);
    float lg = logf(fmaxf(m_[0], EV_EPS));
    float d2 = lg * lg;
#pragma unroll
    for (int off = 16; off > 0; off >>= 1) d2 += __shfl_xor(d2, off, 32);
    if (lh == 0) D[b * NC + 2 * cp + half] = sqrtf(d2);
}

__global__ void k_loss(const float* out, const int* labels, const float* D, int B, float* res) {
    __shared__ float sI[256], sD[256], sC[256];
    int tid = threadIdx.x;
    float aI = 0.f, aD = 0.f, aC = 0.f;
    for (int b = tid; b < B; b += 256) {
        int lb = labels[b];
        const float* ob = out + b * NC;
        float m = ob[0];
#pragma unroll
        for (int j = 1; j < NC; ++j) m = fmaxf(m, ob[j]);
        float se = 0.f;
#pragma unroll
        for (int j = 0; j < NC; ++j) se += expf(ob[j] - m);
        aC += m + logf(se) - ob[lb];
        const float* db = D + b * NC;
        float s = 0.f;
#pragma unroll
        for (int j = 0; j < NC; ++j) s += db[j];
        aI += db[lb];
        aD += s - db[lb];
    }
    sI[tid] = aI; sD[tid] = aD; sC[tid] = aC;
    __syncthreads();
    for (int off = 128; off > 0; off >>= 1) {
        if (tid < off) { sI[tid] += sI[tid + off]; sD[tid] += sD[tid + off]; sC[tid] += sC[tid + off]; }
        __syncthreads();
    }
    if (tid == 0) {
        float intra = 0.001f * sI[0] / (float)B;
        float disp = sD[0] / (float)(B * (NC - 1));
        float ce = sC[0] / (float)B;
        res[0] = intra - 0.001f * disp + ce;
    }
}

extern "C" void kernel_launch(void* const* d_in, const int* in_sizes, int n_in,
                              void* d_out, int out_size, void* d_ws, size_t ws_size,
                              hipStream_t stream) {
    const float* X = (const float*)d_in[0];
    const float* out = (const float*)d_in[1];
    const int* labels = (const int*)d_in[2];
    int B = in_sizes[2];

    float* ws = (float*)d_ws;
    float* bary0    = ws;                 // 8192
    float* sqrtm    = ws + 8192;          // 8192
    float* invsqrtm = ws + 16384;         // 8192
    float* meanT    = ws + 24576;         // 8192
    float* bary     = ws + 32768;         // 8192
    float* D        = ws + 40960;         // B*8 = 16384
    int*   counts   = (int*)(ws + 57344); // 8
    float* big      = ws + 65536;         // B*1024 floats (partials, then T, then Wt)
    float* part2    = ws + 65536 + (size_t)B * 1024;  // NPART*NC*1024 floats

    k_count<<<1, 256, 0, stream>>>(labels, B, counts);
    k_accum_part<<<NPART, 256, 0, stream>>>(X, labels, B, big);
    k_accum_fin<<<NC, 256, 0, stream>>>(big, counts, bary0);
    k_eig_bary0<<<NC, 64, 0, stream>>>(bary0, sqrtm, invsqrtm);
    k_tangent<<<B, 64, 0, stream>>>(X, labels, sqrtm, invsqrtm, big);
    k_accum_part<<<NPART, 256, 0, stream>>>(big, labels, B, part2);
    k_accum_fin<<<NC, 256, 0, stream>>>(part2, counts, meanT);
    k_update<<<NC, 64, 0, stream>>>(meanT, sqrtm, invsqrtm, bary0, bary);
    k_cholinv<<<B, 64, 0, stream>>>(X, big);
    k_pairdist<<<B * 4, 64, 0, stream>>>(big, bary, D);
    k_loss<<<1, 256, 0, stream>>>(out, labels, D, B, (float*)d_out);
}

// Round 9
// 1277.327 us; speedup vs baseline: 3.5303x; 1.1015x over previous
//
#include <hip/hip_runtime.h>
#include <math.h>

#define NC 8
#define NDIM 32
#define LDSD 34            // stride 34: rows 8B-aligned (float2); col access 2-way bank alias (free)
#define MAT (NDIM * LDSD)  // 1088 floats per LDS matrix
#define EV_EPS 1e-10f
#define NPART 32

#if __has_builtin(__builtin_amdgcn_rcpf)
__device__ inline float fast_rcp(float x) { return __builtin_amdgcn_rcpf(x); }
#else
__device__ inline float fast_rcp(float x) { return 1.f / x; }
#endif
#if __has_builtin(__builtin_amdgcn_rsqf)
__device__ inline float fast_rsq(float x) { return __builtin_amdgcn_rsqf(x); }
#else
__device__ inline float fast_rsq(float x) { return 1.f / sqrtf(x); }
#endif

// ---------- 32x32 LDS helpers ----------
template <int NT>
__device__ inline void g2l(const float* g, float* l, int tid) {
    for (int idx2 = tid; idx2 < 512; idx2 += NT) {
        int i = idx2 >> 4, jp = idx2 & 15;
        *(float2*)&l[i * LDSD + 2 * jp] = *(const float2*)&g[i * 32 + 2 * jp];
    }
}
template <int NT>
__device__ inline void l2g(const float* l, float* g, int tid) {
    for (int idx2 = tid; idx2 < 512; idx2 += NT) {
        int i = idx2 >> 4, jp = idx2 & 15;
        *(float2*)&g[i * 32 + 2 * jp] = *(const float2*)&l[i * LDSD + 2 * jp];
    }
}

// ---------- register-tiled LDS matmuls (64 threads; 8-row x 2-col tile/thread) ----------
// C = A * B.  SAFE with C == B (each thread reads only its own B columns).
__device__ inline void mmb_nn(const float* A, const float* B, float* C, int tid) {
    int j2 = (tid & 15) * 2;
    int i0 = (tid >> 4) * 8;
    float2 ac[8];
#pragma unroll
    for (int r = 0; r < 8; ++r) { ac[r].x = 0.f; ac[r].y = 0.f; }
#pragma unroll
    for (int k = 0; k < 32; k += 2) {
        float2 b0 = *(const float2*)&B[k * LDSD + j2];
        float2 b1 = *(const float2*)&B[(k + 1) * LDSD + j2];
#pragma unroll
        for (int r = 0; r < 8; ++r) {
            float2 a = *(const float2*)&A[(i0 + r) * LDSD + k];
            ac[r].x = fmaf(a.x, b0.x, fmaf(a.y, b1.x, ac[r].x));
            ac[r].y = fmaf(a.x, b0.y, fmaf(a.y, b1.y, ac[r].y));
        }
    }
#pragma unroll
    for (int r = 0; r < 8; ++r) *(float2*)&C[(i0 + r) * LDSD + j2] = ac[r];
}
// C = A * B with C aliasing A: accumulate, block-wide barrier, then store.
__device__ inline void mmb_nn_st(const float* A, const float* B, float* C, int tid) {
    int j2 = (tid & 15) * 2;
    int i0 = (tid >> 4) * 8;
    float2 ac[8];
#pragma unroll
    for (int r = 0; r < 8; ++r) { ac[r].x = 0.f; ac[r].y = 0.f; }
#pragma unroll
    for (int k = 0; k < 32; k += 2) {
        float2 b0 = *(const float2*)&B[k * LDSD + j2];
        float2 b1 = *(const float2*)&B[(k + 1) * LDSD + j2];
#pragma unroll
        for (int r = 0; r < 8; ++r) {
            float2 a = *(const float2*)&A[(i0 + r) * LDSD + k];
            ac[r].x = fmaf(a.x, b0.x, fmaf(a.y, b1.x, ac[r].x));
            ac[r].y = fmaf(a.x, b0.y, fmaf(a.y, b1.y, ac[r].y));
        }
    }
    __syncthreads();   // all threads done reading A and B
#pragma unroll
    for (int r = 0; r < 8; ++r) *(float2*)&C[(i0 + r) * LDSD + j2] = ac[r];
}
// gC(global, stride 32) = A * B^T
__device__ inline void mmb_nt_g(const float* A, const float* B, float* gC, int tid) {
    int j2 = (tid & 15) * 2;
    int i0 = (tid >> 4) * 8;
    float2 ac[8];
#pragma unroll
    for (int r = 0; r < 8; ++r) { ac[r].x = 0.f; ac[r].y = 0.f; }
#pragma unroll
    for (int l = 0; l < 32; l += 2) {
        float2 b0 = *(const float2*)&B[j2 * LDSD + l];
        float2 b1 = *(const float2*)&B[(j2 + 1) * LDSD + l];
#pragma unroll
        for (int r = 0; r < 8; ++r) {
            float2 a = *(const float2*)&A[(i0 + r) * LDSD + l];
            ac[r].x = fmaf(a.x, b0.x, fmaf(a.y, b0.y, ac[r].x));
            ac[r].y = fmaf(a.x, b1.x, fmaf(a.y, b1.y, ac[r].y));
        }
    }
#pragma unroll
    for (int r = 0; r < 8; ++r) *(float2*)&gC[(i0 + r) * 32 + j2] = ac[r];
}

// ---------- register-resident XOR-ordered Jacobi, eigenvalues only, fixed sweeps ----------
// Lane lh holds column lh skewed: m_[r] = M[r^lh][lh]; diag = m_[0].
__device__ inline void rjacobi_fixed(float* m_, int nsweep) {
    for (int sweep = 0; sweep < nsweep; ++sweep) {
#pragma unroll
        for (int mm = 1; mm < 32; ++mm) {
            float app = m_[0];
            float aqq = __shfl_xor(app, mm, 32);
            float apq = m_[mm];
            float apqc = __builtin_copysignf(fmaxf(fabsf(apq), 1e-36f), apq);
            float tau = (aqq - app) * 0.5f * fast_rcp(apqc);
            float den = fabsf(tau) + sqrtf(fmaf(tau, tau, 1.f));
            float t = __builtin_copysignf(fast_rcp(den), tau);
            t = (fabsf(apq) > 1e-36f) ? t : 0.f;
            float cc = fast_rsq(fmaf(t, t, 1.f));
            float ss = t * cc;
#pragma unroll
            for (int r = 0; r < 32; ++r) {
                if (r < (r ^ mm)) {
                    const int r2 = r ^ mm;
                    float ti = __shfl_xor(t, r, 32);
                    float ci = fast_rsq(fmaf(ti, ti, 1.f));
                    float si = ti * ci;
                    float x = m_[r], y = m_[r2];
                    m_[r]  = ci * x - si * y;
                    m_[r2] = ci * y + si * x;
                }
            }
            float o[32];
#pragma unroll
            for (int u = 0; u < 32; ++u) o[u] = __shfl_xor(m_[u ^ mm], mm, 32);
#pragma unroll
            for (int u = 0; u < 32; ++u) m_[u] = fmaf(cc, m_[u], -ss * o[u]);
        }
    }
}

// ---------- split-role register Jacobi: half 0 solves M, half 1 accumulates W·V ----------
// half 0: z_ = symmetrized M (skew).  half 1: z_ = W0 column lh (skew); receives
// only the column-rotation stream -> ends as W0·V.
template <int NSWEEP>
__device__ inline void rjacobi_split(float* z_, int half, int lh) {
    for (int sweep = 0; sweep < NSWEEP; ++sweep) {
#pragma unroll
        for (int mm = 1; mm < 32; ++mm) {
            float app = z_[0];
            float aqq = __shfl_xor(app, mm, 32);
            float apq = z_[mm];
            float apqc = __builtin_copysignf(fmaxf(fabsf(apq), 1e-36f), apq);
            float tau = (aqq - app) * 0.5f * fast_rcp(apqc);
            float den = fabsf(tau) + sqrtf(fmaf(tau, tau, 1.f));
            float t = __builtin_copysignf(fast_rcp(den), tau);
            t = (fabsf(apq) > 1e-36f) ? t : 0.f;
            t = __shfl(t, lh, 64);               // half 1 inherits half 0's t
            float cc = fast_rsq(fmaf(t, t, 1.f));
            float ss = t * cc;
            if (half == 0) {                     // row rotations on M only (t-refetch)
#pragma unroll
                for (int r = 0; r < 32; ++r) {
                    if (r < (r ^ mm)) {
                        const int r2 = r ^ mm;
                        float ti = __shfl_xor(t, r, 32);
                        float ci = fast_rsq(fmaf(ti, ti, 1.f));
                        float si = ti * ci;
                        float x = z_[r], y = z_[r2];
                        z_[r]  = ci * x - si * y;
                        z_[r2] = ci * y + si * x;
                    }
                }
            }
            // col rotations: shared stream; prefetch then independent FMAs
            float o[32];
#pragma unroll
            for (int u = 0; u < 32; ++u) o[u] = __shfl_xor(z_[u ^ mm], mm, 32);
#pragma unroll
            for (int u = 0; u < 32; ++u) z_[u] = fmaf(cc, z_[u], -ss * o[u]);
        }
    }
}

// ---------- kernels ----------
__global__ void __launch_bounds__(256) k_accum_part(const float* src, const int* labels, int B, float* part) {
    int blk = blockIdx.x, tid = threadIdx.x;
    int chunk = (B + NPART - 1) / NPART;
    int b0 = blk * chunk, b1 = b0 + chunk < B ? b0 + chunk : B;
    float acc[NC][4];
#pragma unroll
    for (int c = 0; c < NC; ++c)
#pragma unroll
        for (int e = 0; e < 4; ++e) acc[c][e] = 0.f;
    for (int b = b0; b < b1; ++b) {
        int lb = labels[b];
        float x[4];
#pragma unroll
        for (int e = 0; e < 4; ++e) x[e] = src[b * 1024 + tid + 256 * e];
#pragma unroll
        for (int c = 0; c < NC; ++c) {
            if (lb == c) {
#pragma unroll
                for (int e = 0; e < 4; ++e) acc[c][e] += x[e];
            }
        }
    }
#pragma unroll
    for (int c = 0; c < NC; ++c)
#pragma unroll
        for (int e = 0; e < 4; ++e) part[(blk * NC + c) * 1024 + tid + 256 * e] = acc[c][e];
}

// reduce NPART partials, divide by class count (counted inline from labels)
__global__ void __launch_bounds__(256) k_accum_fin(const float* part, const int* labels, int B, float* dst) {
    __shared__ int sc[4];
    int c = blockIdx.x, tid = threadIdx.x;
    int cnt = 0;
    for (int b = tid; b < B; b += 256) cnt += (labels[b] == c) ? 1 : 0;
#pragma unroll
    for (int off = 32; off > 0; off >>= 1) cnt += __shfl_down(cnt, off);
    if ((tid & 63) == 0) sc[tid >> 6] = cnt;
    __syncthreads();
    int total = sc[0] + sc[1] + sc[2] + sc[3];
    float acc[4] = {0.f, 0.f, 0.f, 0.f};
    for (int k = 0; k < NPART; ++k) {
#pragma unroll
        for (int e = 0; e < 4; ++e) acc[e] += part[(k * NC + c) * 1024 + tid + 256 * e];
    }
    float inv = 1.f / (float)total;
#pragma unroll
    for (int e = 0; e < 4; ++e) dst[c * 1024 + tid + 256 * e] = acc[e] * inv;
}

// sqrtm/invsqrtm of bary0 via split-role register Jacobi (W0 = I -> half 1 holds V)
__global__ void __launch_bounds__(64) k_eig_bary0(const float* bary0, float* sqrtm, float* invsqrtm) {
    __shared__ __align__(16) float P[MAT], Q[MAT];
    int c = blockIdx.x, tid = threadIdx.x, half = tid >> 5, lh = tid & 31;
    g2l<64>(bary0 + c * 1024, P, tid);
    __syncthreads();
    float z_[32];
    if (half == 0) {
#pragma unroll
        for (int r = 0; r < 32; ++r) {
            int i = r ^ lh;
            z_[r] = 0.5f * (P[i * LDSD + lh] + P[lh * LDSD + i]);
        }
    } else {
#pragma unroll
        for (int r = 0; r < 32; ++r) z_[r] = (r == 0) ? 1.f : 0.f;   // V0 = I col
    }
    rjacobi_split<5>(z_, half, lh);
    float lam = __shfl(z_[0], lh, 64);
    float esq = sqrtf(fmaxf(lam, 0.f));
    float eisq = fast_rsq(fmaxf(lam, 1e-30f));
    __syncthreads();                             // done reading P
    if (half == 1) {
#pragma unroll
        for (int r = 0; r < 32; ++r) {
            int i = r ^ lh;
            Q[i * LDSD + lh] = z_[r];            // Q = V
            P[i * LDSD + lh] = z_[r] * esq;      // P = V·diag(sqrt λ)
        }
    }
    __syncthreads();
    mmb_nt_g(P, Q, sqrtm + c * 1024, tid);       // sqrtm = V diag V^T
    __syncthreads();
    if (half == 1) {
#pragma unroll
        for (int r = 0; r < 32; ++r) P[(r ^ lh) * LDSD + lh] = z_[r] * eisq;
    }
    __syncthreads();
    mmb_nt_g(P, Q, invsqrtm + c * 1024, tid);    // invsqrtm = V diag^-1 V^T
}

// tangent: 2 LDS buffers; split-role wave (W0 = sqrtm); fixed 2 sweeps
__global__ void __launch_bounds__(64) k_tangent(const float* X, const int* labels, const float* sqrtm,
                                                const float* invsqrtm, float* Tbuf) {
    __shared__ __align__(16) float P[MAT], Q[MAT];
    int b = blockIdx.x, tid = threadIdx.x, half = tid >> 5, lh = tid & 31;
    int lb = labels[b];
    g2l<64>(X + b * 1024, P, tid);
    g2l<64>(invsqrtm + lb * 1024, Q, tid);
    __syncthreads();
    mmb_nn(Q, P, P, tid); __syncthreads();   // P = S·X          (in-place on B)
    mmb_nn(P, Q, Q, tid); __syncthreads();   // Q = (S·X)·S = M  (in-place on B)
    g2l<64>(sqrtm + lb * 1024, P, tid);      // P = sqrtm
    __syncthreads();
    float z_[32];
    if (half == 0) {
#pragma unroll
        for (int r = 0; r < 32; ++r) {
            int i = r ^ lh;
            z_[r] = 0.5f * (Q[i * LDSD + lh] + Q[lh * LDSD + i]);   // symmetrized M
        }
    } else {
#pragma unroll
        for (int r = 0; r < 32; ++r) z_[r] = P[(r ^ lh) * LDSD + lh];  // W0 = sqrtm col (skew)
    }
    rjacobi_split<2>(z_, half, lh);
    float lam = __shfl(z_[0], lh, 64);
    float ev = logf(fmaxf(lam, EV_EPS));
    __syncthreads();                             // extraction reads of P,Q done
    if (half == 1) {
#pragma unroll
        for (int r = 0; r < 32; ++r) {
            float w = z_[r];
            int i = r ^ lh;
            Q[i * LDSD + lh] = w;                // Q = W = sqrtm·V
            P[i * LDSD + lh] = w * ev;           // P = W·diag(log λ)
        }
    }
    __syncthreads();
    mmb_nt_g(P, Q, Tbuf + b * 1024, tid);        // T = W·diag·W^T
}

// exp-map update via split-role register Jacobi (W0 = sqrtm), fused err+select
__global__ void __launch_bounds__(64) k_update(const float* meanT, const float* sqrtm, const float* invsqrtm,
                                               const float* bary0, float* bary) {
    __shared__ __align__(16) float P[MAT], Q[MAT];
    int c = blockIdx.x, tid = threadIdx.x, half = tid >> 5, lh = tid & 31;
    g2l<64>(meanT + c * 1024, P, tid);
    g2l<64>(invsqrtm + c * 1024, Q, tid);
    __syncthreads();
    mmb_nn(Q, P, P, tid); __syncthreads();   // P = S·meanT
    mmb_nn(P, Q, Q, tid); __syncthreads();   // Q = N
    g2l<64>(sqrtm + c * 1024, P, tid);
    __syncthreads();
    float z_[32];
    if (half == 0) {
#pragma unroll
        for (int r = 0; r < 32; ++r) {
            int i = r ^ lh;
            z_[r] = 0.5f * (Q[i * LDSD + lh] + Q[lh * LDSD + i]);
        }
    } else {
#pragma unroll
        for (int r = 0; r < 32; ++r) z_[r] = P[(r ^ lh) * LDSD + lh];  // W0 = sqrtm col
    }
    rjacobi_split<5>(z_, half, lh);
    float lam = __shfl(z_[0], lh, 64);
    // faithful quirk: clamp eigenvalues to >= 1e-10 BEFORE exp
    float ev = expf(fmaxf(lam, EV_EPS));
    __syncthreads();
    if (half == 1) {
#pragma unroll
        for (int r = 0; r < 32; ++r) {
            float w = z_[r];
            int i = r ^ lh;
            Q[i * LDSD + lh] = w;                // Q = W
            P[i * LDSD + lh] = w * ev;           // P = W·diag(exp λ)
        }
    }
    __syncthreads();
    // newbary tile = P·Q^T per thread; err vs bary0; select; write
    int j2 = (tid & 15) * 2, i0 = (tid >> 4) * 8;
    float2 ac[8];
#pragma unroll
    for (int r = 0; r < 8; ++r) { ac[r].x = 0.f; ac[r].y = 0.f; }
#pragma unroll
    for (int l = 0; l < 32; l += 2) {
        float2 b0 = *(const float2*)&Q[j2 * LDSD + l];
        float2 b1 = *(const float2*)&Q[(j2 + 1) * LDSD + l];
#pragma unroll
        for (int r = 0; r < 8; ++r) {
            float2 a = *(const float2*)&P[(i0 + r) * LDSD + l];
            ac[r].x = fmaf(a.x, b0.x, fmaf(a.y, b0.y, ac[r].x));
            ac[r].y = fmaf(a.x, b1.x, fmaf(a.y, b1.y, ac[r].y));
        }
    }
    float2 bv[8];
    float loc = 0.f;
#pragma unroll
    for (int r = 0; r < 8; ++r) {
        bv[r] = *(const float2*)&bary0[c * 1024 + (i0 + r) * 32 + j2];
        float dx = ac[r].x - bv[r].x, dy = ac[r].y - bv[r].y;
        loc += dx * dx + dy * dy;
    }
#pragma unroll
    for (int off = 32; off > 0; off >>= 1) loc += __shfl_down(loc, off);
    float err2 = __shfl(loc, 0);
    bool keep0 = (err2 < 1e-8f);  // CONV_TOL^2
#pragma unroll
    for (int r = 0; r < 8; ++r) {
        float2 w = keep0 ? bv[r] : ac[r];
        *(float2*)&bary[c * 1024 + (i0 + r) * 32 + j2] = w;
    }
}

__global__ void __launch_bounds__(64) k_cholinv(const float* X, float* WtBuf) {
    __shared__ __align__(16) float A[MAT], W[MAT];
    int b = blockIdx.x, tid = threadIdx.x;
    g2l<64>(X + b * 1024, A, tid);
    __syncthreads();
    if (tid < 32) A[tid * LDSD + tid] += 1e-3f;  // CHOL_EPS
    __syncthreads();
    for (int k = 0; k < 32; ++k) {
        if (tid == 0) A[k * LDSD + k] = sqrtf(A[k * LDSD + k]);
        __syncthreads();
        float invd = 1.f / A[k * LDSD + k];
        if (tid > k && tid < 32) A[tid * LDSD + k] *= invd;
        __syncthreads();
        for (int idx = tid; idx < 1024; idx += 64) {
            int i = idx >> 5, j = idx & 31;
            if (i > k && j > k && j <= i) A[i * LDSD + j] -= A[i * LDSD + k] * A[j * LDSD + k];
        }
        __syncthreads();
    }
    // register forward substitution: lane j computes column j of W = L^{-1}
    if (tid < 32) {
        const int j = tid;
        float w[32];
#pragma unroll
        for (int i = 0; i < 32; ++i) {
            float acc = (i == j) ? 1.f : 0.f;
#pragma unroll
            for (int k = 0; k < 32; ++k) {
                if (k < i) acc = fmaf(-A[i * LDSD + k], w[k], acc);
            }
            float val = acc * fast_rcp(A[i * LDSD + i]);
            w[i] = (i < j) ? 0.f : val;
            W[j * LDSD + i] = w[i];
        }
    }
    __syncthreads();
    l2g<64>(W, WtBuf + b * 1024, tid);   // WtBuf = L^{-T} row-major
}

// pairdist: 2 LDS buffers (in-place matmuls), register Jacobi fixed 2 sweeps
__global__ void __launch_bounds__(64) k_pairdist(const float* WtBuf, const float* bary, float* D) {
    __shared__ __align__(16) float Wl[MAT], Bc[MAT];
    int bid = blockIdx.x;
    int b = bid >> 2, cp = bid & 3;
    int tid = threadIdx.x, half = tid >> 5, lh = tid & 31;
    g2l<64>(WtBuf + b * 1024, Wl, tid);
    float m_[32];
    for (int h = 0; h < 2; ++h) {
        __syncthreads();                      // Wl ready / previous extraction done
        g2l<64>(bary + (2 * cp + h) * 1024, Bc, tid);
        __syncthreads();
        // faithful quirk: M = L^{-T} bary L^{-T}
        mmb_nn(Wl, Bc, Bc, tid);              // Y = Wl·bary  (in-place on B)
        __syncthreads();
        mmb_nn_st(Bc, Wl, Bc, tid);           // M = Y·Wl     (staged store into A-alias)
        __syncthreads();
        if (half == h) {
#pragma unroll
            for (int r = 0; r < 32; ++r) {
                int i = r ^ lh;
                int hi = i > lh ? i : lh, lo = i > lh ? lh : i;  // eigvalsh UPLO='L'
                m_[r] = Bc[hi * LDSD + lo];
            }
        }
    }
    rjacobi_fixed(m_, 2);
    float lg = logf(fmaxf(m_[0], EV_EPS));
    float d2 = lg * lg;
#pragma unroll
    for (int off = 16; off > 0; off >>= 1) d2 += __shfl_xor(d2, off, 32);
    if (lh == 0) D[b * NC + 2 * cp + half] = sqrtf(d2);
}

__global__ void k_loss(const float* out, const int* labels, const float* D, int B, float* res) {
    __shared__ float sI[256], sD[256], sC[256];
    int tid = threadIdx.x;
    float aI = 0.f, aD = 0.f, aC = 0.f;
    for (int b = tid; b < B; b += 256) {
        int lb = labels[b];
        const float* ob = out + b * NC;
        float m = ob[0];
#pragma unroll
        for (int j = 1; j < NC; ++j) m = fmaxf(m, ob[j]);
        float se = 0.f;
#pragma unroll
        for (int j = 0; j < NC; ++j) se += expf(ob[j] - m);
        aC += m + logf(se) - ob[lb];
        const float* db = D + b * NC;
        float s = 0.f;
#pragma unroll
        for (int j = 0; j < NC; ++j) s += db[j];
        aI += db[lb];
        aD += s - db[lb];
    }
    sI[tid] = aI; sD[tid] = aD; sC[tid] = aC;
    __syncthreads();
    for (int off = 128; off > 0; off >>= 1) {
        if (tid < off) { sI[tid] += sI[tid + off]; sD[tid] += sD[tid + off]; sC[tid] += sC[tid + off]; }
        __syncthreads();
    }
    if (tid == 0) {
        float intra = 0.001f * sI[0] / (float)B;
        float disp = sD[0] / (float)(B * (NC - 1));
        float ce = sC[0] / (float)B;
        res[0] = intra - 0.001f * disp + ce;
    }
}

extern "C" void kernel_launch(void* const* d_in, const int* in_sizes, int n_in,
                              void* d_out, int out_size, void* d_ws, size_t ws_size,
                              hipStream_t stream) {
    const float* X = (const float*)d_in[0];
    const float* out = (const float*)d_in[1];
    const int* labels = (const int*)d_in[2];
    int B = in_sizes[2];

    float* ws = (float*)d_ws;
    float* bary0    = ws;                 // 8192
    float* sqrtm    = ws + 8192;          // 8192
    float* invsqrtm = ws + 16384;         // 8192
    float* meanT    = ws + 24576;         // 8192
    float* bary     = ws + 32768;         // 8192
    float* D        = ws + 40960;         // B*8 = 16384
    float* big      = ws + 65536;         // B*1024 floats (partials, then T, then Wt)
    float* part2    = ws + 65536 + (size_t)B * 1024;  // NPART*NC*1024 floats

    k_accum_part<<<NPART, 256, 0, stream>>>(X, labels, B, big);
    k_accum_fin<<<NC, 256, 0, stream>>>(big, labels, B, bary0);
    k_eig_bary0<<<NC, 64, 0, stream>>>(bary0, sqrtm, invsqrtm);
    k_tangent<<<B, 64, 0, stream>>>(X, labels, sqrtm, invsqrtm, big);
    k_accum_part<<<NPART, 256, 0, stream>>>(big, labels, B, part2);
    k_accum_fin<<<NC, 256, 0, stream>>>(part2, labels, B, meanT);
    k_update<<<NC, 64, 0, stream>>>(meanT, sqrtm, invsqrtm, bary0, bary);
    k_cholinv<<<B, 64, 0, stream>>>(X, big);
    k_pairdist<<<B * 4, 64, 0, stream>>>(big, bary, D);
    k_loss<<<1, 256, 0, stream>>>(out, labels, D, B, (float*)d_out);
}

// Round 10
// 1197.960 us; speedup vs baseline: 3.7641x; 1.0663x over previous
//
#include <hip/hip_runtime.h>
#include <math.h>

#define NC 8
#define NDIM 32
#define LDSD 34            // stride 34: rows 8B-aligned (float2); col access 2-way bank alias (free)
#define MAT (NDIM * LDSD)  // 1088 floats per LDS matrix
#define EV_EPS 1e-10f
#define NPART 64

#if __has_builtin(__builtin_amdgcn_rcpf)
__device__ inline float fast_rcp(float x) { return __builtin_amdgcn_rcpf(x); }
#else
__device__ inline float fast_rcp(float x) { return 1.f / x; }
#endif
#if __has_builtin(__builtin_amdgcn_rsqf)
__device__ inline float fast_rsq(float x) { return __builtin_amdgcn_rsqf(x); }
#else
__device__ inline float fast_rsq(float x) { return 1.f / sqrtf(x); }
#endif

// ---------- 32x32 LDS helpers (T = participating threads, t = 0..T-1) ----------
template <int NT>
__device__ inline void g2l(const float* g, float* l, int t) {
    for (int idx2 = t; idx2 < 512; idx2 += NT) {
        int i = idx2 >> 4, jp = idx2 & 15;
        *(float2*)&l[i * LDSD + 2 * jp] = *(const float2*)&g[i * 32 + 2 * jp];
    }
}

// ---------- register-tiled LDS matmuls (one wave; 8-row x 2-col tile/thread; t = lane 0..63) ----------
// C = A * B.  SAFE with C == B (per-lane B-column ownership; LDS ops in-order within a wave).
__device__ inline void mmb_nn(const float* A, const float* B, float* C, int t) {
    int j2 = (t & 15) * 2;
    int i0 = (t >> 4) * 8;
    float2 ac[8];
#pragma unroll
    for (int r = 0; r < 8; ++r) { ac[r].x = 0.f; ac[r].y = 0.f; }
#pragma unroll
    for (int k = 0; k < 32; k += 2) {
        float2 b0 = *(const float2*)&B[k * LDSD + j2];
        float2 b1 = *(const float2*)&B[(k + 1) * LDSD + j2];
#pragma unroll
        for (int r = 0; r < 8; ++r) {
            float2 a = *(const float2*)&A[(i0 + r) * LDSD + k];
            ac[r].x = fmaf(a.x, b0.x, fmaf(a.y, b1.x, ac[r].x));
            ac[r].y = fmaf(a.x, b0.y, fmaf(a.y, b1.y, ac[r].y));
        }
    }
#pragma unroll
    for (int r = 0; r < 8; ++r) *(float2*)&C[(i0 + r) * LDSD + j2] = ac[r];
}
// C = A * B with C aliasing A: accumulate, BLOCK barrier, then store (call from all threads).
__device__ inline void mmb_nn_st(const float* A, const float* B, float* C, int t) {
    int j2 = (t & 15) * 2;
    int i0 = (t >> 4) * 8;
    float2 ac[8];
#pragma unroll
    for (int r = 0; r < 8; ++r) { ac[r].x = 0.f; ac[r].y = 0.f; }
#pragma unroll
    for (int k = 0; k < 32; k += 2) {
        float2 b0 = *(const float2*)&B[k * LDSD + j2];
        float2 b1 = *(const float2*)&B[(k + 1) * LDSD + j2];
#pragma unroll
        for (int r = 0; r < 8; ++r) {
            float2 a = *(const float2*)&A[(i0 + r) * LDSD + k];
            ac[r].x = fmaf(a.x, b0.x, fmaf(a.y, b1.x, ac[r].x));
            ac[r].y = fmaf(a.x, b0.y, fmaf(a.y, b1.y, ac[r].y));
        }
    }
    __syncthreads();   // all threads done reading A and B
#pragma unroll
    for (int r = 0; r < 8; ++r) *(float2*)&C[(i0 + r) * LDSD + j2] = ac[r];
}
// gC(global, stride 32) = A * B^T
__device__ inline void mmb_nt_g(const float* A, const float* B, float* gC, int t) {
    int j2 = (t & 15) * 2;
    int i0 = (t >> 4) * 8;
    float2 ac[8];
#pragma unroll
    for (int r = 0; r < 8; ++r) { ac[r].x = 0.f; ac[r].y = 0.f; }
#pragma unroll
    for (int l = 0; l < 32; l += 2) {
        float2 b0 = *(const float2*)&B[j2 * LDSD + l];
        float2 b1 = *(const float2*)&B[(j2 + 1) * LDSD + l];
#pragma unroll
        for (int r = 0; r < 8; ++r) {
            float2 a = *(const float2*)&A[(i0 + r) * LDSD + l];
            ac[r].x = fmaf(a.x, b0.x, fmaf(a.y, b0.y, ac[r].x));
            ac[r].y = fmaf(a.x, b1.x, fmaf(a.y, b1.y, ac[r].y));
        }
    }
#pragma unroll
    for (int r = 0; r < 8; ++r) *(float2*)&gC[(i0 + r) * 32 + j2] = ac[r];
}

// ---------- register-resident XOR-ordered Jacobi, eigenvalues only, fixed sweeps ----------
// Lane lh holds column lh skewed: m_[r] = M[r^lh][lh]; diag = m_[0].
__device__ inline void rjacobi_fixed(float* m_, int nsweep) {
    for (int sweep = 0; sweep < nsweep; ++sweep) {
#pragma unroll
        for (int mm = 1; mm < 32; ++mm) {
            float app = m_[0];
            float aqq = __shfl_xor(app, mm, 32);
            float apq = m_[mm];
            float apqc = __builtin_copysignf(fmaxf(fabsf(apq), 1e-36f), apq);
            float tau = (aqq - app) * 0.5f * fast_rcp(apqc);
            float den = fabsf(tau) + sqrtf(fmaf(tau, tau, 1.f));
            float t = __builtin_copysignf(fast_rcp(den), tau);
            t = (fabsf(apq) > 1e-36f) ? t : 0.f;
            float cc = fast_rsq(fmaf(t, t, 1.f));
            float ss = t * cc;
#pragma unroll
            for (int r = 0; r < 32; ++r) {
                if (r < (r ^ mm)) {
                    const int r2 = r ^ mm;
                    float ti = __shfl_xor(t, r, 32);
                    float ci = fast_rsq(fmaf(ti, ti, 1.f));
                    float si = ti * ci;
                    float x = m_[r], y = m_[r2];
                    m_[r]  = ci * x - si * y;
                    m_[r2] = ci * y + si * x;
                }
            }
            float o[32];
#pragma unroll
            for (int u = 0; u < 32; ++u) o[u] = __shfl_xor(m_[u ^ mm], mm, 32);
#pragma unroll
            for (int u = 0; u < 32; ++u) m_[u] = fmaf(cc, m_[u], -ss * o[u]);
        }
    }
}

// ---------- split-role register Jacobi: half 0 solves M, half 1 accumulates W·V ----------
template <int NSWEEP>
__device__ inline void rjacobi_split(float* z_, int half, int lh) {
    for (int sweep = 0; sweep < NSWEEP; ++sweep) {
#pragma unroll
        for (int mm = 1; mm < 32; ++mm) {
            float app = z_[0];
            float aqq = __shfl_xor(app, mm, 32);
            float apq = z_[mm];
            float apqc = __builtin_copysignf(fmaxf(fabsf(apq), 1e-36f), apq);
            float tau = (aqq - app) * 0.5f * fast_rcp(apqc);
            float den = fabsf(tau) + sqrtf(fmaf(tau, tau, 1.f));
            float t = __builtin_copysignf(fast_rcp(den), tau);
            t = (fabsf(apq) > 1e-36f) ? t : 0.f;
            t = __shfl(t, lh, 64);               // half 1 inherits half 0's t (wave-local)
            float cc = fast_rsq(fmaf(t, t, 1.f));
            float ss = t * cc;
            if (half == 0) {                     // row rotations on M only (t-refetch)
#pragma unroll
                for (int r = 0; r < 32; ++r) {
                    if (r < (r ^ mm)) {
                        const int r2 = r ^ mm;
                        float ti = __shfl_xor(t, r, 32);
                        float ci = fast_rsq(fmaf(ti, ti, 1.f));
                        float si = ti * ci;
                        float x = z_[r], y = z_[r2];
                        z_[r]  = ci * x - si * y;
                        z_[r2] = ci * y + si * x;
                    }
                }
            }
            float o[32];
#pragma unroll
            for (int u = 0; u < 32; ++u) o[u] = __shfl_xor(z_[u ^ mm], mm, 32);
#pragma unroll
            for (int u = 0; u < 32; ++u) z_[u] = fmaf(cc, z_[u], -ss * o[u]);
        }
    }
}

// ---------- kernels ----------
__global__ void __launch_bounds__(256) k_accum_part(const float* src, const int* labels, int B, float* part) {
    int blk = blockIdx.x, tid = threadIdx.x;
    int chunk = (B + NPART - 1) / NPART;
    int b0 = blk * chunk, b1 = b0 + chunk < B ? b0 + chunk : B;
    float acc[NC][4];
#pragma unroll
    for (int c = 0; c < NC; ++c)
#pragma unroll
        for (int e = 0; e < 4; ++e) acc[c][e] = 0.f;
    for (int b = b0; b < b1; ++b) {
        int lb = labels[b];
        float x[4];
#pragma unroll
        for (int e = 0; e < 4; ++e) x[e] = src[b * 1024 + tid + 256 * e];
#pragma unroll
        for (int c = 0; c < NC; ++c) {
            if (lb == c) {
#pragma unroll
                for (int e = 0; e < 4; ++e) acc[c][e] += x[e];
            }
        }
    }
#pragma unroll
    for (int c = 0; c < NC; ++c)
#pragma unroll
        for (int e = 0; e < 4; ++e) part[(blk * NC + c) * 1024 + tid + 256 * e] = acc[c][e];
}

// reduce NPART partials, divide by class count (counted inline from labels)
__global__ void __launch_bounds__(256) k_accum_fin(const float* part, const int* labels, int B, float* dst) {
    __shared__ int sc[4];
    int c = blockIdx.x, tid = threadIdx.x;
    int cnt = 0;
    for (int b = tid; b < B; b += 256) cnt += (labels[b] == c) ? 1 : 0;
#pragma unroll
    for (int off = 32; off > 0; off >>= 1) cnt += __shfl_down(cnt, off);
    if ((tid & 63) == 0) sc[tid >> 6] = cnt;
    __syncthreads();
    int total = sc[0] + sc[1] + sc[2] + sc[3];
    float acc[4] = {0.f, 0.f, 0.f, 0.f};
    for (int k = 0; k < NPART; ++k) {
#pragma unroll
        for (int e = 0; e < 4; ++e) acc[e] += part[(k * NC + c) * 1024 + tid + 256 * e];
    }
    float inv = 1.f / (float)total;
#pragma unroll
    for (int e = 0; e < 4; ++e) dst[c * 1024 + tid + 256 * e] = acc[e] * inv;
}

// sqrtm/invsqrtm of bary0 via split-role register Jacobi (W0 = I -> half 1 holds V)
__global__ void __launch_bounds__(64) k_eig_bary0(const float* bary0, float* sqrtm, float* invsqrtm) {
    __shared__ __align__(16) float P[MAT], Q[MAT];
    int c = blockIdx.x, tid = threadIdx.x, half = tid >> 5, lh = tid & 31;
    g2l<64>(bary0 + c * 1024, P, tid);
    __syncthreads();
    float z_[32];
    if (half == 0) {
#pragma unroll
        for (int r = 0; r < 32; ++r) {
            int i = r ^ lh;
            z_[r] = 0.5f * (P[i * LDSD + lh] + P[lh * LDSD + i]);
        }
    } else {
#pragma unroll
        for (int r = 0; r < 32; ++r) z_[r] = (r == 0) ? 1.f : 0.f;   // V0 = I col
    }
    rjacobi_split<5>(z_, half, lh);
    float lam = __shfl(z_[0], lh, 64);
    float esq = sqrtf(fmaxf(lam, 0.f));
    float eisq = fast_rsq(fmaxf(lam, 1e-30f));
    __syncthreads();                             // done reading P
    if (half == 1) {
#pragma unroll
        for (int r = 0; r < 32; ++r) {
            int i = r ^ lh;
            Q[i * LDSD + lh] = z_[r];            // Q = V
            P[i * LDSD + lh] = z_[r] * esq;      // P = V·diag(sqrt λ)
        }
    }
    __syncthreads();
    mmb_nt_g(P, Q, sqrtm + c * 1024, tid);       // sqrtm = V diag V^T
    __syncthreads();
    if (half == 1) {
#pragma unroll
        for (int r = 0; r < 32; ++r) P[(r ^ lh) * LDSD + lh] = z_[r] * eisq;
    }
    __syncthreads();
    mmb_nt_g(P, Q, invsqrtm + c * 1024, tid);    // invsqrtm = V diag^-1 V^T
}

// tangent: 4 samples per 256-thread block (per-wave P,Q); split-role wave; 2 sweeps
__global__ void __launch_bounds__(256) k_tangent(const float* X, const int* labels, const float* sqrtm,
                                                 const float* invsqrtm, float* Tbuf) {
    __shared__ __align__(16) float P[4][MAT], Q[4][MAT];   // 34816 B
    int tid = threadIdx.x, wv = tid >> 6, t64 = tid & 63;
    int half = (t64) >> 5, lh = tid & 31;
    int b = blockIdx.x * 4 + wv;
    int lb = labels[b];
    float* Pw = P[wv];
    float* Qw = Q[wv];
    g2l<64>(X + b * 1024, Pw, t64);
    g2l<64>(invsqrtm + lb * 1024, Qw, t64);
    __syncthreads();
    mmb_nn(Qw, Pw, Pw, t64); __syncthreads();   // P = S·X
    mmb_nn(Pw, Qw, Qw, t64); __syncthreads();   // Q = (S·X)·S = M
    g2l<64>(sqrtm + lb * 1024, Pw, t64);        // P = sqrtm
    __syncthreads();
    float z_[32];
    if (half == 0) {
#pragma unroll
        for (int r = 0; r < 32; ++r) {
            int i = r ^ lh;
            z_[r] = 0.5f * (Qw[i * LDSD + lh] + Qw[lh * LDSD + i]);   // symmetrized M
        }
    } else {
#pragma unroll
        for (int r = 0; r < 32; ++r) z_[r] = Pw[(r ^ lh) * LDSD + lh];  // W0 = sqrtm col (skew)
    }
    rjacobi_split<2>(z_, half, lh);
    float lam = __shfl(z_[0], lh, 64);          // wave-local broadcast of half-0 eigenvalue
    float ev = logf(fmaxf(lam, EV_EPS));
    __syncthreads();                             // extraction reads of P,Q done
    if (half == 1) {
#pragma unroll
        for (int r = 0; r < 32; ++r) {
            float w = z_[r];
            int i = r ^ lh;
            Qw[i * LDSD + lh] = w;               // Q = W = sqrtm·V
            Pw[i * LDSD + lh] = w * ev;          // P = W·diag(log λ)
        }
    }
    __syncthreads();
    mmb_nt_g(Pw, Qw, Tbuf + b * 1024, t64);      // T = W·diag·W^T
}

// exp-map update via split-role register Jacobi (W0 = sqrtm), fused err+select
__global__ void __launch_bounds__(64) k_update(const float* meanT, const float* sqrtm, const float* invsqrtm,
                                               const float* bary0, float* bary) {
    __shared__ __align__(16) float P[MAT], Q[MAT];
    int c = blockIdx.x, tid = threadIdx.x, half = tid >> 5, lh = tid & 31;
    g2l<64>(meanT + c * 1024, P, tid);
    g2l<64>(invsqrtm + c * 1024, Q, tid);
    __syncthreads();
    mmb_nn(Q, P, P, tid); __syncthreads();   // P = S·meanT
    mmb_nn(P, Q, Q, tid); __syncthreads();   // Q = N
    g2l<64>(sqrtm + c * 1024, P, tid);
    __syncthreads();
    float z_[32];
    if (half == 0) {
#pragma unroll
        for (int r = 0; r < 32; ++r) {
            int i = r ^ lh;
            z_[r] = 0.5f * (Q[i * LDSD + lh] + Q[lh * LDSD + i]);
        }
    } else {
#pragma unroll
        for (int r = 0; r < 32; ++r) z_[r] = P[(r ^ lh) * LDSD + lh];  // W0 = sqrtm col
    }
    rjacobi_split<5>(z_, half, lh);
    float lam = __shfl(z_[0], lh, 64);
    // faithful quirk: clamp eigenvalues to >= 1e-10 BEFORE exp
    float ev = expf(fmaxf(lam, EV_EPS));
    __syncthreads();
    if (half == 1) {
#pragma unroll
        for (int r = 0; r < 32; ++r) {
            float w = z_[r];
            int i = r ^ lh;
            Q[i * LDSD + lh] = w;                // Q = W
            P[i * LDSD + lh] = w * ev;           // P = W·diag(exp λ)
        }
    }
    __syncthreads();
    // newbary tile = P·Q^T per thread; err vs bary0; select; write
    int j2 = (tid & 15) * 2, i0 = (tid >> 4) * 8;
    float2 ac[8];
#pragma unroll
    for (int r = 0; r < 8; ++r) { ac[r].x = 0.f; ac[r].y = 0.f; }
#pragma unroll
    for (int l = 0; l < 32; l += 2) {
        float2 b0 = *(const float2*)&Q[j2 * LDSD + l];
        float2 b1 = *(const float2*)&Q[(j2 + 1) * LDSD + l];
#pragma unroll
        for (int r = 0; r < 8; ++r) {
            float2 a = *(const float2*)&P[(i0 + r) * LDSD + l];
            ac[r].x = fmaf(a.x, b0.x, fmaf(a.y, b0.y, ac[r].x));
            ac[r].y = fmaf(a.x, b1.x, fmaf(a.y, b1.y, ac[r].y));
        }
    }
    float2 bv[8];
    float loc = 0.f;
#pragma unroll
    for (int r = 0; r < 8; ++r) {
        bv[r] = *(const float2*)&bary0[c * 1024 + (i0 + r) * 32 + j2];
        float dx = ac[r].x - bv[r].x, dy = ac[r].y - bv[r].y;
        loc += dx * dx + dy * dy;
    }
#pragma unroll
    for (int off = 32; off > 0; off >>= 1) loc += __shfl_down(loc, off);
    float err2 = __shfl(loc, 0);
    bool keep0 = (err2 < 1e-8f);  // CONV_TOL^2
#pragma unroll
    for (int r = 0; r < 8; ++r) {
        float2 w = keep0 ? bv[r] : ac[r];
        *(float2*)&bary[c * 1024 + (i0 + r) * 32 + j2] = w;
    }
}

// pairdist with FUSED Cholesky+inverse: one block per sample b (256 threads, 4 waves).
// Block computes Wt = L^{-T} once in LDS, then wave wv handles classes {2wv, 2wv+1}.
__global__ void __launch_bounds__(256) k_pairdist(const float* X, const float* bary, float* D) {
    __shared__ __align__(16) float WA[MAT];        // X -> L -> Wt
    __shared__ __align__(16) float BC[4][MAT];     // per-wave class buffer
    int tid = threadIdx.x, wv = tid >> 6, t64 = tid & 63;
    int half = t64 >> 5, lh = tid & 31;
    int b = blockIdx.x;
    g2l<256>(X + b * 1024, WA, tid);
    __syncthreads();
    if (tid < 32) WA[tid * LDSD + tid] += 1e-3f;   // CHOL_EPS
    __syncthreads();
    // right-looking Cholesky (lower triangle), 256 threads on trailing updates
    for (int k = 0; k < 32; ++k) {
        if (tid == 0) WA[k * LDSD + k] = sqrtf(WA[k * LDSD + k]);
        __syncthreads();
        float invd = fast_rcp(WA[k * LDSD + k]);
        if (tid > k && tid < 32) WA[tid * LDSD + k] *= invd;
        __syncthreads();
        for (int idx = tid; idx < 1024; idx += 256) {
            int i = idx >> 5, j = idx & 31;
            if (i > k && j > k && j <= i) WA[i * LDSD + j] -= WA[i * LDSD + k] * WA[j * LDSD + k];
        }
        __syncthreads();
    }
    // forward substitution: lane j (wave 0) computes column j of W = L^{-1} into registers,
    // THEN writes row j of Wt = L^{-T} (reads-then-writes; LDS in-order within the wave)
    if (tid < 32) {
        const int j = tid;
        float w[32];
#pragma unroll
        for (int i = 0; i < 32; ++i) {
            float acc = (i == j) ? 1.f : 0.f;
#pragma unroll
            for (int k = 0; k < 32; ++k) {
                if (k < i) acc = fmaf(-WA[i * LDSD + k], w[k], acc);
            }
            float val = acc * fast_rcp(WA[i * LDSD + i]);
            w[i] = (i < j) ? 0.f : val;
        }
#pragma unroll
        for (int i = 0; i < 32; ++i) WA[j * LDSD + i] = w[i];   // Wt row j
    }
    __syncthreads();
    // per-wave: two classes through M = Wt·bary·Wt
    float* Bw = BC[wv];
    float m_[32];
    for (int h = 0; h < 2; ++h) {
        int c = 2 * wv + h;
        g2l<64>(bary + c * 1024, Bw, t64);
        __syncthreads();
        mmb_nn(WA, Bw, Bw, t64);              // Y = Wt·bary  (in-place on B)
        __syncthreads();
        mmb_nn_st(Bw, WA, Bw, t64);           // M = Y·Wt     (staged store into A-alias)
        __syncthreads();
        if (half == h) {
#pragma unroll
            for (int r = 0; r < 32; ++r) {
                int i = r ^ lh;
                int hi = i > lh ? i : lh, lo = i > lh ? lh : i;  // eigvalsh UPLO='L'
                m_[r] = Bw[hi * LDSD + lo];
            }
        }
        __syncthreads();                      // extraction done before next h overwrites Bw
    }
    rjacobi_fixed(m_, 2);
    float lg = logf(fmaxf(m_[0], EV_EPS));
    float d2 = lg * lg;
#pragma unroll
    for (int off = 16; off > 0; off >>= 1) d2 += __shfl_xor(d2, off, 32);
    if (lh == 0) D[b * NC + 2 * wv + half] = sqrtf(d2);
}

__global__ void k_loss(const float* out, const int* labels, const float* D, int B, float* res) {
    __shared__ float sI[256], sD[256], sC[256];
    int tid = threadIdx.x;
    float aI = 0.f, aD = 0.f, aC = 0.f;
    for (int b = tid; b < B; b += 256) {
        int lb = labels[b];
        const float* ob = out + b * NC;
        float m = ob[0];
#pragma unroll
        for (int j = 1; j < NC; ++j) m = fmaxf(m, ob[j]);
        float se = 0.f;
#pragma unroll
        for (int j = 0; j < NC; ++j) se += expf(ob[j] - m);
        aC += m + logf(se) - ob[lb];
        const float* db = D + b * NC;
        float s = 0.f;
#pragma unroll
        for (int j = 0; j < NC; ++j) s += db[j];
        aI += db[lb];
        aD += s - db[lb];
    }
    sI[tid] = aI; sD[tid] = aD; sC[tid] = aC;
    __syncthreads();
    for (int off = 128; off > 0; off >>= 1) {
        if (tid < off) { sI[tid] += sI[tid + off]; sD[tid] += sD[tid + off]; sC[tid] += sC[tid + off]; }
        __syncthreads();
    }
    if (tid == 0) {
        float intra = 0.001f * sI[0] / (float)B;
        float disp = sD[0] / (float)(B * (NC - 1));
        float ce = sC[0] / (float)B;
        res[0] = intra - 0.001f * disp + ce;
    }
}

extern "C" void kernel_launch(void* const* d_in, const int* in_sizes, int n_in,
                              void* d_out, int out_size, void* d_ws, size_t ws_size,
                              hipStream_t stream) {
    const float* X = (const float*)d_in[0];
    const float* out = (const float*)d_in[1];
    const int* labels = (const int*)d_in[2];
    int B = in_sizes[2];

    float* ws = (float*)d_ws;
    float* bary0    = ws;                 // 8192
    float* sqrtm    = ws + 8192;          // 8192
    float* invsqrtm = ws + 16384;         // 8192
    float* meanT    = ws + 24576;         // 8192
    float* bary     = ws + 32768;         // 8192
    float* D        = ws + 40960;         // B*8 = 16384
    float* big      = ws + 65536;         // B*1024 floats (partials, then T)
    float* part2    = ws + 65536 + (size_t)B * 1024;  // NPART*NC*1024 floats

    k_accum_part<<<NPART, 256, 0, stream>>>(X, labels, B, big);
    k_accum_fin<<<NC, 256, 0, stream>>>(big, labels, B, bary0);
    k_eig_bary0<<<NC, 64, 0, stream>>>(bary0, sqrtm, invsqrtm);
    k_tangent<<<B / 4, 256, 0, stream>>>(X, labels, sqrtm, invsqrtm, big);
    k_accum_part<<<NPART, 256, 0, stream>>>(big, labels, B, part2);
    k_accum_fin<<<NC, 256, 0, stream>>>(part2, labels, B, meanT);
    k_update<<<NC, 64, 0, stream>>>(meanT, sqrtm, invsqrtm, bary0, bary);
    k_pairdist<<<B, 256, 0, stream>>>(X, bary, D);
    k_loss<<<1, 256, 0, stream>>>(out, labels, D, B, (float*)d_out);
}